// Round 1
// baseline (1776.127 us; speedup 1.0000x reference)
//
#include <hip/hip_runtime.h>
#include <hip/hip_bf16.h>

typedef __hip_bfloat16 bf16;
typedef __attribute__((ext_vector_type(8))) short bf16x8;
typedef __attribute__((ext_vector_type(4))) float f32x4;

#define NL 4
#define NH 12
#define C 768
#define T 1024
#define NB 2
#define BTOK 2048
#define V 50257
#define DH 64

// ---------------- block reductions (256 threads = 4 waves) ----------------
__device__ __forceinline__ float block_sum(float v, float* red) {
#pragma unroll
  for (int off = 32; off; off >>= 1) v += __shfl_down(v, off);
  int lane = threadIdx.x & 63, wid = threadIdx.x >> 6;
  __syncthreads();
  if (lane == 0) red[wid] = v;
  __syncthreads();
  return red[0] + red[1] + red[2] + red[3];
}

__device__ __forceinline__ float block_max(float v, float* red) {
#pragma unroll
  for (int off = 32; off; off >>= 1) v = fmaxf(v, __shfl_down(v, off));
  int lane = threadIdx.x & 63, wid = threadIdx.x >> 6;
  __syncthreads();
  if (lane == 0) red[wid] = v;
  __syncthreads();
  return fmaxf(fmaxf(red[0], red[1]), fmaxf(red[2], red[3]));
}

// ---------------- embedding ----------------
__global__ __launch_bounds__(256) void k_embed(const int* __restrict__ idx,
    const float* __restrict__ wte, const float* __restrict__ wpe,
    float* __restrict__ x) {
  long i = (long)blockIdx.x * 256 + threadIdx.x;  // over BTOK*C (exact)
  int bt = (int)(i / C), c = (int)(i % C);
  int t = bt & (T - 1);
  x[i] = wte[(long)idx[bt] * C + c] + wpe[(long)t * C + c];
}

// ---------------- fp32 -> bf16 transposed weight convert ----------------
__global__ __launch_bounds__(256) void k_transpose_bf16(const float* __restrict__ W,
    bf16* __restrict__ Wt, int K, int N) {
  __shared__ float tile[32][33];
  long zoff = (long)blockIdx.z * K * N;
  W += zoff;
  Wt += zoff;
  int n0 = blockIdx.x * 32, k0 = blockIdx.y * 32;
  int tx = threadIdx.x, ty = threadIdx.y;
#pragma unroll
  for (int i = 0; i < 4; i++) {
    int k = k0 + ty + i * 8, n = n0 + tx;
    if (k < K && n < N) tile[ty + i * 8][tx] = W[(long)k * N + n];
  }
  __syncthreads();
#pragma unroll
  for (int i = 0; i < 4; i++) {
    int n = n0 + ty + i * 8, k = k0 + tx;
    if (n < N && k < K) Wt[(long)n * K + k] = __float2bfloat16(tile[tx][ty + i * 8]);
  }
}

// ---------------- layernorm: fp32 in -> bf16 out ----------------
__global__ __launch_bounds__(256) void k_layernorm(const float* __restrict__ x,
    const float* __restrict__ w, const float* __restrict__ b, bf16* __restrict__ out) {
  __shared__ float red[4];
  long row = blockIdx.x;
  const float* xr = x + row * C;
  int t = threadIdx.x;
  float v0 = xr[t], v1 = xr[t + 256], v2 = xr[t + 512];
  float s = block_sum(v0 + v1 + v2, red);
  float mu = s * (1.0f / C);
  float d0 = v0 - mu, d1 = v1 - mu, d2 = v2 - mu;
  float vs = block_sum(d0 * d0 + d1 * d1 + d2 * d2, red);
  float inv = rsqrtf(vs * (1.0f / C) + 1e-5f);
  bf16* orow = out + row * C;
  orow[t]       = __float2bfloat16(d0 * inv * w[t]       + b[t]);
  orow[t + 256] = __float2bfloat16(d1 * inv * w[t + 256] + b[t + 256]);
  orow[t + 512] = __float2bfloat16(d2 * inv * w[t + 512] + b[t + 512]);
}

// ---------------- row softmax over masked fp32 scores, bf16 out in place ----
__global__ __launch_bounds__(256) void k_softmax(float* S) {
  __shared__ float red[4];
  long row = blockIdx.x;  // NB*NH*T rows of length T
  float* sr = S + row * T;
  bf16* pr = reinterpret_cast<bf16*>(S) + row * (2 * T);  // same bytes, bf16 row
  int t = threadIdx.x;
  float v[4];
#pragma unroll
  for (int j = 0; j < 4; j++) v[j] = sr[t + j * 256];
  float mx = fmaxf(fmaxf(v[0], v[1]), fmaxf(v[2], v[3]));
  float m = block_max(mx, red);
  float e[4], sum = 0.f;
#pragma unroll
  for (int j = 0; j < 4; j++) { e[j] = __expf(v[j] - m); sum += e[j]; }
  float tot = block_sum(sum, red);
  float inv = 1.0f / tot;
#pragma unroll
  for (int j = 0; j < 4; j++) pr[t + j * 256] = __float2bfloat16(e[j] * inv);
}

// ---------------- qkv fp32 [BTOK,3C] -> q,k [bh,T,DH] bf16 ; v -> [bh,DH,T] ----
__global__ __launch_bounds__(256) void k_repack_qkv(const float* __restrict__ qkv,
    bf16* __restrict__ q, bf16* __restrict__ k, bf16* __restrict__ vt) {
  long i = (long)blockIdx.x * 256 + threadIdx.x;  // BTOK*3C (exact)
  float val = qkv[i];
  int bt = (int)(i / (3 * C)), n = (int)(i % (3 * C));
  int which = n / C, r = n % C;
  int h = r >> 6, d = r & 63;
  int b = bt >> 10, t = bt & 1023;
  int bh = b * NH + h;
  bf16 bv = __float2bfloat16(val);
  if (which == 0)      q[((long)bh * T + t) * DH + d] = bv;
  else if (which == 1) k[((long)bh * T + t) * DH + d] = bv;
  else                 vt[((long)bh * DH + d) * T + t] = bv;
}

// ---------------- y [b,h,t,d] fp32 -> yb [b*T+t, C] bf16 ----------------
__global__ __launch_bounds__(256) void k_repack_y(const float* __restrict__ y,
    bf16* __restrict__ yb) {
  long i = (long)blockIdx.x * 256 + threadIdx.x;  // BTOK*C (exact)
  int d = (int)(i & 63);
  int t = (int)((i >> 6) & 1023);
  int bh = (int)(i >> 16);
  int h = bh % NH, b = bh / NH;
  yb[((long)(b * T + t)) * C + h * DH + d] = __float2bfloat16(y[i]);
}

// ---------------- NT GEMM: C[M,N] = A[M,K] * Bt[N,K]^T (+epilogue) ----------
// EPI 0: fp32 out (+bias if non-null)
// EPI 2: bf16 out, gelu(acc+bias)
// EPI 3: fp32 out, acc+bias+R (residual)
// EPI 4: fp32 out, acc*scale with causal mask (col>row -> -1e30)
#define BM 128
#define BN 128
#define BK 32

template <int EPI>
__global__ __launch_bounds__(256) void k_gemm(const bf16* __restrict__ A,
    const bf16* __restrict__ B, const float* __restrict__ bias,
    void* __restrict__ Cv, const float* __restrict__ R,
    int M, int N, int K, int lda, int ldb, int ldc,
    long sA, long sB, long sC, float scale) {
  __shared__ __align__(16) bf16 As[BM][BK + 16];
  __shared__ __align__(16) bf16 Bs[BN][BK + 16];
  int z = blockIdx.z;
  A += (long)z * sA;
  B += (long)z * sB;
  long coff = (long)z * sC;
  int m0 = blockIdx.y * BM, n0 = blockIdx.x * BN;
  int tid = threadIdx.x;
  int lane = tid & 63, wid = tid >> 6;
  int wr = wid >> 1, wc = wid & 1;
  int srow = tid >> 2, scol = (tid & 3) * 8;
  f32x4 acc[4][4] = {};
  for (int k0 = 0; k0 < K; k0 += BK) {
#pragma unroll
    for (int p = 0; p < 2; p++) {
      int row = srow + p * 64;
      uint4 av = *reinterpret_cast<const uint4*>(A + (long)(m0 + row) * lda + k0 + scol);
      *reinterpret_cast<uint4*>(&As[row][scol]) = av;
      uint4 bv = make_uint4(0u, 0u, 0u, 0u);
      if (n0 + row < N)
        bv = *reinterpret_cast<const uint4*>(B + (long)(n0 + row) * ldb + k0 + scol);
      *reinterpret_cast<uint4*>(&Bs[row][scol]) = bv;
    }
    __syncthreads();
    int koff = (lane >> 4) * 8, l15 = lane & 15;
    bf16x8 af[4], bfr[4];
#pragma unroll
    for (int i = 0; i < 4; i++)
      af[i] = *reinterpret_cast<const bf16x8*>(&As[wr * 64 + i * 16 + l15][koff]);
#pragma unroll
    for (int i = 0; i < 4; i++)
      bfr[i] = *reinterpret_cast<const bf16x8*>(&Bs[wc * 64 + i * 16 + l15][koff]);
#pragma unroll
    for (int i = 0; i < 4; i++)
#pragma unroll
      for (int j = 0; j < 4; j++)
        acc[i][j] = __builtin_amdgcn_mfma_f32_16x16x32_bf16(af[i], bfr[j], acc[i][j], 0, 0, 0);
    __syncthreads();
  }
  int l15 = lane & 15, l4 = lane >> 4;
#pragma unroll
  for (int j = 0; j < 4; j++) {
    int gn = n0 + wc * 64 + j * 16 + l15;
    if (gn >= N) continue;
    float bv = (bias != nullptr) ? bias[gn] : 0.0f;
#pragma unroll
    for (int i = 0; i < 4; i++) {
#pragma unroll
      for (int rr = 0; rr < 4; rr++) {
        int gm = m0 + wr * 64 + i * 16 + l4 * 4 + rr;
        long off = coff + (long)gm * ldc + gn;
        float v = acc[i][j][rr] + bv;
        if constexpr (EPI == 0) {
          ((float*)Cv)[off] = v;
        } else if constexpr (EPI == 2) {
          float u = 0.7978845608028654f * (v + 0.044715f * v * v * v);
          u = fminf(fmaxf(u, -15.f), 15.f);
          float e2 = __expf(2.f * u);
          float th = (e2 - 1.f) / (e2 + 1.f);
          ((bf16*)Cv)[off] = __float2bfloat16(0.5f * v * (1.f + th));
        } else if constexpr (EPI == 3) {
          ((float*)Cv)[off] = v + R[off];
        } else if constexpr (EPI == 4) {
          float s = acc[i][j][rr] * scale;
          if (gn > gm) s = -1e30f;
          ((float*)Cv)[off] = s;
        }
      }
    }
  }
}

extern "C" void kernel_launch(void* const* d_in, const int* in_sizes, int n_in,
                              void* d_out, int out_size, void* d_ws, size_t ws_size,
                              hipStream_t stream) {
  const int*   idx    = (const int*)d_in[0];
  const float* wte    = (const float*)d_in[1];
  const float* wpe    = (const float*)d_in[2];
  const float* ln1_w  = (const float*)d_in[3];
  const float* ln1_b  = (const float*)d_in[4];
  const float* qkv_w  = (const float*)d_in[5];
  const float* qkv_b  = (const float*)d_in[6];
  const float* proj_w = (const float*)d_in[7];
  const float* proj_b = (const float*)d_in[8];
  const float* ln2_w  = (const float*)d_in[9];
  const float* ln2_b  = (const float*)d_in[10];
  const float* fc_w   = (const float*)d_in[11];
  const float* fc_b   = (const float*)d_in[12];
  const float* fc2_w  = (const float*)d_in[13];
  const float* fc2_b  = (const float*)d_in[14];
  const float* lnf_w  = (const float*)d_in[15];
  const float* lnf_b  = (const float*)d_in[16];
  const float* head_w = (const float*)d_in[17];
  (void)in_sizes; (void)n_in; (void)out_size; (void)ws_size;

  char* base = (char*)d_ws;
  size_t off = 0;
  auto alloc = [&](size_t bytes) -> void* {
    void* p = base + off;
    off = (off + bytes + 255) & ~(size_t)255;
    return p;
  };
  bf16* wt_qkv  = (bf16*)alloc((size_t)NL * 3 * C * C * 2);
  bf16* wt_proj = (bf16*)alloc((size_t)NL * C * C * 2);
  bf16* wt_fc   = (bf16*)alloc((size_t)NL * 4 * C * C * 2);
  bf16* wt_fc2  = (bf16*)alloc((size_t)NL * 4 * C * C * 2);
  bf16* wt_head = (bf16*)alloc((size_t)V * C * 2);
  float* x      = (float*)alloc((size_t)BTOK * C * 4);
  bf16*  xb     = (bf16*)alloc((size_t)BTOK * C * 2);
  float* qkvbuf = (float*)alloc((size_t)BTOK * 3 * C * 4);
  bf16*  qb     = (bf16*)alloc((size_t)NB * NH * T * DH * 2);
  bf16*  kb     = (bf16*)alloc((size_t)NB * NH * T * DH * 2);
  bf16*  vtb    = (bf16*)alloc((size_t)NB * NH * T * DH * 2);
  float* ybuf   = (float*)alloc((size_t)NB * NH * T * DH * 4);
  bf16*  yb     = (bf16*)alloc((size_t)BTOK * C * 2);
  bf16*  mbuf   = (bf16*)alloc((size_t)BTOK * 4 * C * 2);

  // scores scratch lives in d_out (100.7 MB < 411 MB); head GEMM overwrites last.
  float* S = (float*)d_out;

  dim3 tb(32, 8);
  k_transpose_bf16<<<dim3(72, 24, NL), tb, 0, stream>>>(qkv_w, wt_qkv, C, 3 * C);
  k_transpose_bf16<<<dim3(24, 24, NL), tb, 0, stream>>>(proj_w, wt_proj, C, C);
  k_transpose_bf16<<<dim3(96, 24, NL), tb, 0, stream>>>(fc_w, wt_fc, C, 4 * C);
  k_transpose_bf16<<<dim3(24, 96, NL), tb, 0, stream>>>(fc2_w, wt_fc2, 4 * C, C);
  k_transpose_bf16<<<dim3((V + 31) / 32, 24, 1), tb, 0, stream>>>(head_w, wt_head, C, V);

  k_embed<<<BTOK * C / 256, 256, 0, stream>>>(idx, wte, wpe, x);

  for (int l = 0; l < NL; l++) {
    k_layernorm<<<BTOK, 256, 0, stream>>>(x, ln1_w + l * C, ln1_b + l * C, xb);
    k_gemm<0><<<dim3(18, 16, 1), 256, 0, stream>>>(xb, wt_qkv + (long)l * 3 * C * C,
        qkv_b + l * 3 * C, qkvbuf, nullptr, BTOK, 3 * C, C, C, C, 3 * C, 0, 0, 0, 0.f);
    k_repack_qkv<<<BTOK * 3 * C / 256, 256, 0, stream>>>(qkvbuf, qb, kb, vtb);
    k_gemm<4><<<dim3(8, 8, NB * NH), 256, 0, stream>>>(qb, kb, nullptr, S, nullptr,
        T, T, DH, DH, DH, T, (long)T * DH, (long)T * DH, (long)T * T, 0.125f);
    k_softmax<<<NB * NH * T, 256, 0, stream>>>(S);
    k_gemm<0><<<dim3(1, 8, NB * NH), 256, 0, stream>>>((const bf16*)S, vtb, nullptr,
        ybuf, nullptr, T, DH, T, 2 * T, T, DH, (long)T * 2 * T, (long)DH * T,
        (long)T * DH, 0.f);
    k_repack_y<<<BTOK * C / 256, 256, 0, stream>>>(ybuf, yb);
    k_gemm<3><<<dim3(6, 16, 1), 256, 0, stream>>>(yb, wt_proj + (long)l * C * C,
        proj_b + l * C, x, x, BTOK, C, C, C, C, C, 0, 0, 0, 0.f);
    k_layernorm<<<BTOK, 256, 0, stream>>>(x, ln2_w + l * C, ln2_b + l * C, xb);
    k_gemm<2><<<dim3(24, 16, 1), 256, 0, stream>>>(xb, wt_fc + (long)l * 4 * C * C,
        fc_b + l * 4 * C, mbuf, nullptr, BTOK, 4 * C, C, C, C, 4 * C, 0, 0, 0, 0.f);
    k_gemm<3><<<dim3(6, 16, 1), 256, 0, stream>>>(mbuf, wt_fc2 + (long)l * 4 * C * C,
        fc2_b + l * C, x, x, BTOK, C, 4 * C, 4 * C, 4 * C, C, 0, 0, 0, 0.f);
  }
  k_layernorm<<<BTOK, 256, 0, stream>>>(x, lnf_w, lnf_b, xb);
  k_gemm<0><<<dim3((V + BN - 1) / BN, 16, 1), 256, 0, stream>>>(xb, wt_head, nullptr,
      (float*)d_out, nullptr, BTOK, V, C, C, C, V, 0, 0, 0, 0.f);
}

// Round 2
// 1429.990 us; speedup vs baseline: 1.2421x; 1.2421x over previous
//
#include <hip/hip_runtime.h>
#include <hip/hip_bf16.h>

typedef __hip_bfloat16 bf16;
typedef __attribute__((ext_vector_type(8))) short bf16x8;
typedef __attribute__((ext_vector_type(4))) float f32x4;

#define NL 4
#define NH 12
#define C 768
#define T 1024
#define NB 2
#define BTOK 2048
#define V 50257
#define DH 64

__device__ __forceinline__ void gload16(const void* g, void* l) {
  __builtin_amdgcn_global_load_lds(
      (const __attribute__((address_space(1))) void*)g,
      (__attribute__((address_space(3))) void*)l, 16, 0, 0);
}

// ---------------- block reductions (256 threads = 4 waves) ----------------
__device__ __forceinline__ float block_sum(float v, float* red) {
#pragma unroll
  for (int off = 32; off; off >>= 1) v += __shfl_down(v, off);
  int lane = threadIdx.x & 63, wid = threadIdx.x >> 6;
  __syncthreads();
  if (lane == 0) red[wid] = v;
  __syncthreads();
  return red[0] + red[1] + red[2] + red[3];
}

// ---------------- embedding ----------------
__global__ __launch_bounds__(256) void k_embed(const int* __restrict__ idx,
    const float* __restrict__ wte, const float* __restrict__ wpe,
    float* __restrict__ x) {
  long i = (long)blockIdx.x * 256 + threadIdx.x;  // over BTOK*C (exact)
  int bt = (int)(i / C), c = (int)(i % C);
  int t = bt & (T - 1);
  x[i] = wte[(long)idx[bt] * C + c] + wpe[(long)t * C + c];
}

// ---------------- fp32 -> bf16 transposed weight convert ----------------
__global__ __launch_bounds__(256) void k_transpose_bf16(const float* __restrict__ W,
    bf16* __restrict__ Wt, int K, int N) {
  __shared__ float tile[32][33];
  long zoff = (long)blockIdx.z * K * N;
  W += zoff;
  Wt += zoff;
  int n0 = blockIdx.x * 32, k0 = blockIdx.y * 32;
  int tx = threadIdx.x, ty = threadIdx.y;
#pragma unroll
  for (int i = 0; i < 4; i++) {
    int k = k0 + ty + i * 8, n = n0 + tx;
    if (k < K && n < N) tile[ty + i * 8][tx] = W[(long)k * N + n];
  }
  __syncthreads();
#pragma unroll
  for (int i = 0; i < 4; i++) {
    int n = n0 + ty + i * 8, k = k0 + tx;
    if (n < N && k < K) Wt[(long)n * K + k] = __float2bfloat16(tile[tx][ty + i * 8]);
  }
}

// ---------------- layernorm: fp32 in -> bf16 out ----------------
__global__ __launch_bounds__(256) void k_layernorm(const float* __restrict__ x,
    const float* __restrict__ w, const float* __restrict__ b, bf16* __restrict__ out) {
  __shared__ float red[4];
  long row = blockIdx.x;
  const float* xr = x + row * C;
  int t = threadIdx.x;
  float v0 = xr[t], v1 = xr[t + 256], v2 = xr[t + 512];
  float s = block_sum(v0 + v1 + v2, red);
  float mu = s * (1.0f / C);
  float d0 = v0 - mu, d1 = v1 - mu, d2 = v2 - mu;
  float vs = block_sum(d0 * d0 + d1 * d1 + d2 * d2, red);
  float inv = rsqrtf(vs * (1.0f / C) + 1e-5f);
  bf16* orow = out + row * C;
  orow[t]       = __float2bfloat16(d0 * inv * w[t]       + b[t]);
  orow[t + 256] = __float2bfloat16(d1 * inv * w[t + 256] + b[t + 256]);
  orow[t + 512] = __float2bfloat16(d2 * inv * w[t + 512] + b[t + 512]);
}

// ---------------- qkv fp32 [BTOK,3C] -> q,k [bh,T,DH] bf16 ; v -> [bh,DH,T] ----
// q is pre-scaled by 1/sqrt(DH)
__global__ __launch_bounds__(256) void k_repack_qkv(const float* __restrict__ qkv,
    bf16* __restrict__ q, bf16* __restrict__ k, bf16* __restrict__ vt) {
  long i = (long)blockIdx.x * 256 + threadIdx.x;  // BTOK*3C (exact)
  float val = qkv[i];
  int bt = (int)(i / (3 * C)), n = (int)(i % (3 * C));
  int which = n / C, r = n % C;
  int h = r >> 6, d = r & 63;
  int b = bt >> 10, t = bt & 1023;
  int bh = b * NH + h;
  if (which == 0)      q[((long)bh * T + t) * DH + d] = __float2bfloat16(val * 0.125f);
  else if (which == 1) k[((long)bh * T + t) * DH + d] = __float2bfloat16(val);
  else                 vt[((long)bh * DH + d) * T + t] = __float2bfloat16(val);
}

// ---------------- fused causal flash attention ----------------
// grid (T/64, NB*NH); 4 waves/block, wave w owns q rows [qt*64+w*16, +16)
// writes y straight into residual-layout bf16 [BTOK][C]
__global__ __launch_bounds__(256) void k_attn(const bf16* __restrict__ q,
    const bf16* __restrict__ k, const bf16* __restrict__ vt,
    bf16* __restrict__ yb) {
  __shared__ __align__(16) bf16 Pl[4][16][72];  // per-wave P tile, +8 pad
  int qt = blockIdx.x, bh = blockIdx.y;
  int b = bh / NH, h = bh % NH;
  int tid = threadIdx.x, w = tid >> 6, lane = tid & 63;
  int l15 = lane & 15, hi = lane >> 4;
  const bf16* qbase = q + (long)bh * T * DH;
  const bf16* kbase = k + (long)bh * T * DH;
  const bf16* vbase = vt + (long)bh * DH * T;

  int qrow = qt * 64 + w * 16 + l15;  // softmax-layout q (col of S^T)
  bf16x8 qf0 = *(const bf16x8*)(qbase + (long)qrow * DH + hi * 8);
  bf16x8 qf1 = *(const bf16x8*)(qbase + (long)qrow * DH + 32 + hi * 8);

  f32x4 accy[4] = {};               // y: row q=hi*4+rr, col d=j*16+l15
  float m_run = -1e30f, l_run = 0.f;

  int nkt = qt + 1;
  for (int kt = 0; kt < nkt; kt++) {
    int kv0 = kt * 64;
    // S^T = mfma(K, Q): out col(l15)=q, row(hi*4+rr)=kv within 16-block kvi
    f32x4 accs[4] = {};
#pragma unroll
    for (int kvi = 0; kvi < 4; kvi++) {
      const bf16* kr = kbase + (long)(kv0 + kvi * 16 + l15) * DH + hi * 8;
      bf16x8 kf0 = *(const bf16x8*)kr;
      bf16x8 kf1 = *(const bf16x8*)(kr + 32);
      accs[kvi] = __builtin_amdgcn_mfma_f32_16x16x32_bf16(kf0, qf0, accs[kvi], 0, 0, 0);
      accs[kvi] = __builtin_amdgcn_mfma_f32_16x16x32_bf16(kf1, qf1, accs[kvi], 0, 0, 0);
    }
    bool diag = (kt == qt);
    float p[4][4];
    float tmax = -1e30f;
#pragma unroll
    for (int kvi = 0; kvi < 4; kvi++)
#pragma unroll
      for (int rr = 0; rr < 4; rr++) {
        float s = accs[kvi][rr];
        if (diag && (kvi * 16 + hi * 4 + rr > w * 16 + l15)) s = -1e30f;
        p[kvi][rr] = s;
        tmax = fmaxf(tmax, s);
      }
    tmax = fmaxf(tmax, __shfl_xor(tmax, 16));
    tmax = fmaxf(tmax, __shfl_xor(tmax, 32));
    float m_new = fmaxf(m_run, tmax);
    float scl = __expf(m_run - m_new);
    float psum = 0.f;
#pragma unroll
    for (int kvi = 0; kvi < 4; kvi++)
#pragma unroll
      for (int rr = 0; rr < 4; rr++) {
        float e = __expf(p[kvi][rr] - m_new);
        p[kvi][rr] = e;
        psum += e;
      }
    psum += __shfl_xor(psum, 16);
    psum += __shfl_xor(psum, 32);
    l_run = l_run * scl + psum;
    m_run = m_new;
    // rescale y-acc (rows are q=hi*4+rr -> fetch scl from lane q_local)
#pragma unroll
    for (int rr = 0; rr < 4; rr++) {
      float sy = __shfl(scl, hi * 4 + rr);
#pragma unroll
      for (int j = 0; j < 4; j++) accy[j][rr] *= sy;
    }
    // P -> LDS (bf16), row = q(l15), col = kv
#pragma unroll
    for (int kvi = 0; kvi < 4; kvi++) {
      union { bf16 hh[2]; unsigned u; } pk0, pk1;
      pk0.hh[0] = __float2bfloat16(p[kvi][0]);
      pk0.hh[1] = __float2bfloat16(p[kvi][1]);
      pk1.hh[0] = __float2bfloat16(p[kvi][2]);
      pk1.hh[1] = __float2bfloat16(p[kvi][3]);
      *(unsigned*)&Pl[w][l15][kvi * 16 + hi * 4]     = pk0.u;
      *(unsigned*)&Pl[w][l15][kvi * 16 + hi * 4 + 2] = pk1.u;
    }
    __syncthreads();
    // PV: A=P (row=q=l15, k=kv), B=V^T (row=d, k=kv)
#pragma unroll
    for (int c = 0; c < 2; c++) {
      bf16x8 pf = *(const bf16x8*)&Pl[w][l15][c * 32 + hi * 8];
#pragma unroll
      for (int j = 0; j < 4; j++) {
        const bf16* vr = vbase + (long)(j * 16 + l15) * T + kv0 + c * 32 + hi * 8;
        bf16x8 vf = *(const bf16x8*)vr;
        accy[j] = __builtin_amdgcn_mfma_f32_16x16x32_bf16(pf, vf, accy[j], 0, 0, 0);
      }
    }
    __syncthreads();
  }
  float inv = 1.0f / l_run;  // valid at lanes with l15 == q_local (all hi groups)
#pragma unroll
  for (int rr = 0; rr < 4; rr++) {
    float li = __shfl(inv, hi * 4 + rr);
    int qg = qt * 64 + w * 16 + hi * 4 + rr;
#pragma unroll
    for (int j = 0; j < 4; j++)
      yb[((long)(b * T + qg)) * C + h * DH + j * 16 + l15] =
          __float2bfloat16(accy[j][rr] * li);
  }
}

// ---------------- NT GEMM (m97-style global_load_lds staging) ----------
// C[M,N] = A[M,K] * Bt[N,K]^T (+epilogue)
// EPI 0: fp32 out (+bias if non-null)
// EPI 2: bf16 out, gelu(acc+bias)
// EPI 3: fp32 out, acc+bias+R (residual)
#define BK 32

template <int EPI>
__global__ __launch_bounds__(256) void k_gemm(const bf16* __restrict__ A,
    const bf16* __restrict__ B, const float* __restrict__ bias,
    void* __restrict__ Cv, const float* __restrict__ R,
    int M, int N, int K, int lda, int ldb, int ldc) {
  __shared__ __align__(16) bf16 As[128][BK];
  __shared__ __align__(16) bf16 Bs[128][BK];
  int m0 = blockIdx.y * 128, n0 = blockIdx.x * 128;
  int tid = threadIdx.x;
  int lane = tid & 63, wid = tid >> 6;
  int wr = wid >> 1, wc = wid & 1;
  int l15 = lane & 15, hi = lane >> 4;
  int srow = lane >> 2;            // 0..15 within 16-row chunk
  int scol = (lane & 3) * 8;       // element col for 16B chunk
  f32x4 acc[4][4] = {};
  const bf16* Ag0 = A + (long)(m0 + wid * 32 + srow) * lda + scol;
  const bf16* Bg0 = B + (long)(n0 + wid * 32 + srow) * ldb + scol;
  for (int k0 = 0; k0 < K; k0 += BK) {
    gload16(Ag0 + k0, &As[wid * 32][0]);
    gload16(Ag0 + k0 + 16 * lda, &As[wid * 32 + 16][0]);
    gload16(Bg0 + k0, &Bs[wid * 32][0]);
    gload16(Bg0 + k0 + 16 * ldb, &Bs[wid * 32 + 16][0]);
    __syncthreads();
    bf16x8 af[4], bfr[4];
#pragma unroll
    for (int i = 0; i < 4; i++)
      af[i] = *(const bf16x8*)&As[wr * 64 + i * 16 + l15][hi * 8];
#pragma unroll
    for (int i = 0; i < 4; i++)
      bfr[i] = *(const bf16x8*)&Bs[wc * 64 + i * 16 + l15][hi * 8];
#pragma unroll
    for (int i = 0; i < 4; i++)
#pragma unroll
      for (int j = 0; j < 4; j++)
        acc[i][j] = __builtin_amdgcn_mfma_f32_16x16x32_bf16(af[i], bfr[j], acc[i][j], 0, 0, 0);
    __syncthreads();
  }
#pragma unroll
  for (int j = 0; j < 4; j++) {
    int gn = n0 + wc * 64 + j * 16 + l15;
    if (gn >= N) continue;
    float bv = (bias != nullptr) ? bias[gn] : 0.0f;
#pragma unroll
    for (int i = 0; i < 4; i++) {
#pragma unroll
      for (int rr = 0; rr < 4; rr++) {
        int gm = m0 + wr * 64 + i * 16 + hi * 4 + rr;
        long off = (long)gm * ldc + gn;
        float v = acc[i][j][rr] + bv;
        if constexpr (EPI == 0) {
          ((float*)Cv)[off] = v;
        } else if constexpr (EPI == 2) {
          float u = 0.7978845608028654f * (v + 0.044715f * v * v * v);
          u = fminf(fmaxf(u, -15.f), 15.f);
          float e2 = __expf(2.f * u);
          float th = (e2 - 1.f) / (e2 + 1.f);
          ((bf16*)Cv)[off] = __float2bfloat16(0.5f * v * (1.f + th));
        } else if constexpr (EPI == 3) {
          ((float*)Cv)[off] = v + R[off];
        }
      }
    }
  }
}

extern "C" void kernel_launch(void* const* d_in, const int* in_sizes, int n_in,
                              void* d_out, int out_size, void* d_ws, size_t ws_size,
                              hipStream_t stream) {
  const int*   idx    = (const int*)d_in[0];
  const float* wte    = (const float*)d_in[1];
  const float* wpe    = (const float*)d_in[2];
  const float* ln1_w  = (const float*)d_in[3];
  const float* ln1_b  = (const float*)d_in[4];
  const float* qkv_w  = (const float*)d_in[5];
  const float* qkv_b  = (const float*)d_in[6];
  const float* proj_w = (const float*)d_in[7];
  const float* proj_b = (const float*)d_in[8];
  const float* ln2_w  = (const float*)d_in[9];
  const float* ln2_b  = (const float*)d_in[10];
  const float* fc_w   = (const float*)d_in[11];
  const float* fc_b   = (const float*)d_in[12];
  const float* fc2_w  = (const float*)d_in[13];
  const float* fc2_b  = (const float*)d_in[14];
  const float* lnf_w  = (const float*)d_in[15];
  const float* lnf_b  = (const float*)d_in[16];
  const float* head_w = (const float*)d_in[17];
  (void)in_sizes; (void)n_in; (void)out_size; (void)ws_size;

  char* base = (char*)d_ws;
  size_t off = 0;
  auto alloc = [&](size_t bytes) -> void* {
    void* p = base + off;
    off = (off + bytes + 255) & ~(size_t)255;
    return p;
  };
  bf16* wt_qkv  = (bf16*)alloc((size_t)NL * 3 * C * C * 2);
  bf16* wt_proj = (bf16*)alloc((size_t)NL * C * C * 2);
  bf16* wt_fc   = (bf16*)alloc((size_t)NL * 4 * C * C * 2);
  bf16* wt_fc2  = (bf16*)alloc((size_t)NL * 4 * C * C * 2);
  bf16* wt_head = (bf16*)alloc((size_t)V * C * 2);
  float* x      = (float*)alloc((size_t)BTOK * C * 4);   // also absorbs head OOB reads
  bf16*  xb     = (bf16*)alloc((size_t)BTOK * C * 2);
  float* qkvbuf = (float*)alloc((size_t)BTOK * 3 * C * 4);
  bf16*  qb     = (bf16*)alloc((size_t)NB * NH * T * DH * 2);
  bf16*  kb     = (bf16*)alloc((size_t)NB * NH * T * DH * 2);
  bf16*  vtb    = (bf16*)alloc((size_t)NB * NH * T * DH * 2);
  bf16*  yb     = (bf16*)alloc((size_t)BTOK * C * 2);
  bf16*  mbuf   = (bf16*)alloc((size_t)BTOK * 4 * C * 2);

  dim3 tb(32, 8);
  k_transpose_bf16<<<dim3(72, 24, NL), tb, 0, stream>>>(qkv_w, wt_qkv, C, 3 * C);
  k_transpose_bf16<<<dim3(24, 24, NL), tb, 0, stream>>>(proj_w, wt_proj, C, C);
  k_transpose_bf16<<<dim3(96, 24, NL), tb, 0, stream>>>(fc_w, wt_fc, C, 4 * C);
  k_transpose_bf16<<<dim3(24, 96, NL), tb, 0, stream>>>(fc2_w, wt_fc2, 4 * C, C);
  k_transpose_bf16<<<dim3((V + 31) / 32, 24, 1), tb, 0, stream>>>(head_w, wt_head, C, V);

  k_embed<<<BTOK * C / 256, 256, 0, stream>>>(idx, wte, wpe, x);

  for (int l = 0; l < NL; l++) {
    k_layernorm<<<BTOK, 256, 0, stream>>>(x, ln1_w + l * C, ln1_b + l * C, xb);
    k_gemm<0><<<dim3(18, 16), 256, 0, stream>>>(xb, wt_qkv + (long)l * 3 * C * C,
        qkv_b + l * 3 * C, qkvbuf, nullptr, BTOK, 3 * C, C, C, C, 3 * C);
    k_repack_qkv<<<BTOK * 3 * C / 256, 256, 0, stream>>>(qkvbuf, qb, kb, vtb);
    k_attn<<<dim3(T / 64, NB * NH), 256, 0, stream>>>(qb, kb, vtb, yb);
    k_gemm<3><<<dim3(6, 16), 256, 0, stream>>>(yb, wt_proj + (long)l * C * C,
        proj_b + l * C, x, x, BTOK, C, C, C, C, C);
    k_layernorm<<<BTOK, 256, 0, stream>>>(x, ln2_w + l * C, ln2_b + l * C, xb);
    k_gemm<2><<<dim3(24, 16), 256, 0, stream>>>(xb, wt_fc + (long)l * 4 * C * C,
        fc_b + l * 4 * C, mbuf, nullptr, BTOK, 4 * C, C, C, C, 4 * C);
    k_gemm<3><<<dim3(6, 16), 256, 0, stream>>>(mbuf, wt_fc2 + (long)l * 4 * C * C,
        fc2_b + l * C, x, x, BTOK, C, 4 * C, 4 * C, 4 * C, C);
  }
  k_layernorm<<<BTOK, 256, 0, stream>>>(x, lnf_w, lnf_b, xb);
  k_gemm<0><<<dim3((V + 127) / 128, 16), 256, 0, stream>>>(xb, wt_head, nullptr,
      (float*)d_out, nullptr, BTOK, V, C, C, C, V);
}

// Round 3
// 1373.357 us; speedup vs baseline: 1.2933x; 1.0412x over previous
//
#include <hip/hip_runtime.h>
#include <hip/hip_bf16.h>

typedef __hip_bfloat16 bf16;
typedef __attribute__((ext_vector_type(8))) short bf16x8;
typedef __attribute__((ext_vector_type(4))) float f32x4;

#define NL 4
#define NH 12
#define C 768
#define T 1024
#define NB 2
#define BTOK 2048
#define V 50257
#define DH 64

__device__ __forceinline__ void gload16(const void* g, void* l) {
  __builtin_amdgcn_global_load_lds(
      (const __attribute__((address_space(1))) void*)g,
      (__attribute__((address_space(3))) void*)l, 16, 0, 0);
}

// ---------------- block reductions (256 threads = 4 waves) ----------------
__device__ __forceinline__ float block_sum(float v, float* red) {
#pragma unroll
  for (int off = 32; off; off >>= 1) v += __shfl_down(v, off);
  int lane = threadIdx.x & 63, wid = threadIdx.x >> 6;
  __syncthreads();
  if (lane == 0) red[wid] = v;
  __syncthreads();
  return red[0] + red[1] + red[2] + red[3];
}

// ---------------- embedding ----------------
__global__ __launch_bounds__(256) void k_embed(const int* __restrict__ idx,
    const float* __restrict__ wte, const float* __restrict__ wpe,
    float* __restrict__ x) {
  long i = (long)blockIdx.x * 256 + threadIdx.x;  // over BTOK*C (exact)
  int bt = (int)(i / C), c = (int)(i % C);
  int t = bt & (T - 1);
  x[i] = wte[(long)idx[bt] * C + c] + wpe[(long)t * C + c];
}

// ---------------- fp32 -> bf16 transposed weight convert ----------------
__global__ __launch_bounds__(256) void k_transpose_bf16(const float* __restrict__ W,
    bf16* __restrict__ Wt, int K, int N) {
  __shared__ float tile[32][33];
  long zoff = (long)blockIdx.z * K * N;
  W += zoff;
  Wt += zoff;
  int n0 = blockIdx.x * 32, k0 = blockIdx.y * 32;
  int tx = threadIdx.x, ty = threadIdx.y;
#pragma unroll
  for (int i = 0; i < 4; i++) {
    int k = k0 + ty + i * 8, n = n0 + tx;
    if (k < K && n < N) tile[ty + i * 8][tx] = W[(long)k * N + n];
  }
  __syncthreads();
#pragma unroll
  for (int i = 0; i < 4; i++) {
    int n = n0 + ty + i * 8, k = k0 + tx;
    if (n < N && k < K) Wt[(long)n * K + k] = __float2bfloat16(tile[tx][ty + i * 8]);
  }
}

// ---------------- layernorm: fp32 in -> bf16 out ----------------
__global__ __launch_bounds__(256) void k_layernorm(const float* __restrict__ x,
    const float* __restrict__ w, const float* __restrict__ b, bf16* __restrict__ out) {
  __shared__ float red[4];
  long row = blockIdx.x;
  const float* xr = x + row * C;
  int t = threadIdx.x;
  float v0 = xr[t], v1 = xr[t + 256], v2 = xr[t + 512];
  float s = block_sum(v0 + v1 + v2, red);
  float mu = s * (1.0f / C);
  float d0 = v0 - mu, d1 = v1 - mu, d2 = v2 - mu;
  float vs = block_sum(d0 * d0 + d1 * d1 + d2 * d2, red);
  float inv = rsqrtf(vs * (1.0f / C) + 1e-5f);
  bf16* orow = out + row * C;
  orow[t]       = __float2bfloat16(d0 * inv * w[t]       + b[t]);
  orow[t + 256] = __float2bfloat16(d1 * inv * w[t + 256] + b[t + 256]);
  orow[t + 512] = __float2bfloat16(d2 * inv * w[t + 512] + b[t + 512]);
}

// ---------------- fused causal flash attention ----------------
// grid (T/64, NB*NH); 4 waves/block, wave w owns q rows [qt*64+w*16, +16)
// writes y straight into residual-layout bf16 [BTOK][C]
__global__ __launch_bounds__(256) void k_attn(const bf16* __restrict__ q,
    const bf16* __restrict__ k, const bf16* __restrict__ vt,
    bf16* __restrict__ yb) {
  __shared__ __align__(16) bf16 Pl[4][16][72];  // per-wave P tile, +8 pad
  int qt = blockIdx.x, bh = blockIdx.y;
  int b = bh / NH, h = bh % NH;
  int tid = threadIdx.x, w = tid >> 6, lane = tid & 63;
  int l15 = lane & 15, hi = lane >> 4;
  const bf16* qbase = q + (long)bh * T * DH;
  const bf16* kbase = k + (long)bh * T * DH;
  const bf16* vbase = vt + (long)bh * DH * T;

  int qrow = qt * 64 + w * 16 + l15;  // softmax-layout q (col of S^T)
  bf16x8 qf0 = *(const bf16x8*)(qbase + (long)qrow * DH + hi * 8);
  bf16x8 qf1 = *(const bf16x8*)(qbase + (long)qrow * DH + 32 + hi * 8);

  f32x4 accy[4] = {};               // y: row q=hi*4+rr, col d=j*16+l15
  float m_run = -1e30f, l_run = 0.f;

  int nkt = qt + 1;
  for (int kt = 0; kt < nkt; kt++) {
    int kv0 = kt * 64;
    // S^T = mfma(K, Q): out col(l15)=q, row(hi*4+rr)=kv within 16-block kvi
    f32x4 accs[4] = {};
#pragma unroll
    for (int kvi = 0; kvi < 4; kvi++) {
      const bf16* kr = kbase + (long)(kv0 + kvi * 16 + l15) * DH + hi * 8;
      bf16x8 kf0 = *(const bf16x8*)kr;
      bf16x8 kf1 = *(const bf16x8*)(kr + 32);
      accs[kvi] = __builtin_amdgcn_mfma_f32_16x16x32_bf16(kf0, qf0, accs[kvi], 0, 0, 0);
      accs[kvi] = __builtin_amdgcn_mfma_f32_16x16x32_bf16(kf1, qf1, accs[kvi], 0, 0, 0);
    }
    bool diag = (kt == qt);
    float p[4][4];
    float tmax = -1e30f;
#pragma unroll
    for (int kvi = 0; kvi < 4; kvi++)
#pragma unroll
      for (int rr = 0; rr < 4; rr++) {
        float s = accs[kvi][rr];
        if (diag && (kvi * 16 + hi * 4 + rr > w * 16 + l15)) s = -1e30f;
        p[kvi][rr] = s;
        tmax = fmaxf(tmax, s);
      }
    tmax = fmaxf(tmax, __shfl_xor(tmax, 16));
    tmax = fmaxf(tmax, __shfl_xor(tmax, 32));
    float m_new = fmaxf(m_run, tmax);
    float scl = __expf(m_run - m_new);
    float psum = 0.f;
#pragma unroll
    for (int kvi = 0; kvi < 4; kvi++)
#pragma unroll
      for (int rr = 0; rr < 4; rr++) {
        float e = __expf(p[kvi][rr] - m_new);
        p[kvi][rr] = e;
        psum += e;
      }
    psum += __shfl_xor(psum, 16);
    psum += __shfl_xor(psum, 32);
    l_run = l_run * scl + psum;
    m_run = m_new;
    // rescale y-acc (rows are q=hi*4+rr -> fetch scl from lane q_local)
#pragma unroll
    for (int rr = 0; rr < 4; rr++) {
      float sy = __shfl(scl, hi * 4 + rr);
#pragma unroll
      for (int j = 0; j < 4; j++) accy[j][rr] *= sy;
    }
    // P -> LDS (bf16), row = q(l15), col = kv
#pragma unroll
    for (int kvi = 0; kvi < 4; kvi++) {
      union { bf16 hh[2]; unsigned u; } pk0, pk1;
      pk0.hh[0] = __float2bfloat16(p[kvi][0]);
      pk0.hh[1] = __float2bfloat16(p[kvi][1]);
      pk1.hh[0] = __float2bfloat16(p[kvi][2]);
      pk1.hh[1] = __float2bfloat16(p[kvi][3]);
      *(unsigned*)&Pl[w][l15][kvi * 16 + hi * 4]     = pk0.u;
      *(unsigned*)&Pl[w][l15][kvi * 16 + hi * 4 + 2] = pk1.u;
    }
    __syncthreads();
    // PV: A=P (row=q=l15, k=kv), B=V^T (row=d, k=kv)
#pragma unroll
    for (int c = 0; c < 2; c++) {
      bf16x8 pf = *(const bf16x8*)&Pl[w][l15][c * 32 + hi * 8];
#pragma unroll
      for (int j = 0; j < 4; j++) {
        const bf16* vr = vbase + (long)(j * 16 + l15) * T + kv0 + c * 32 + hi * 8;
        bf16x8 vf = *(const bf16x8*)vr;
        accy[j] = __builtin_amdgcn_mfma_f32_16x16x32_bf16(pf, vf, accy[j], 0, 0, 0);
      }
    }
    __syncthreads();
  }
  float inv = 1.0f / l_run;  // valid at lanes with l15 == q_local (all hi groups)
#pragma unroll
  for (int rr = 0; rr < 4; rr++) {
    float li = __shfl(inv, hi * 4 + rr);
    int qg = qt * 64 + w * 16 + hi * 4 + rr;
#pragma unroll
    for (int j = 0; j < 4; j++)
      yb[((long)(b * T + qg)) * C + h * DH + j * 16 + l15] =
          __float2bfloat16(accy[j][rr] * li);
  }
}

// ---------------- NT GEMM (m97-style global_load_lds staging) ----------
// C[M,N] = A[M,K] * Bt[N,K]^T (+epilogue)
// EPI 0: fp32 out (+bias if non-null)
// EPI 2: bf16 out, gelu(acc+bias)
// EPI 5: qkv split-repack: Cv=q (scaled 0.125), Cv2=k, Cv3=vt
// SWAPXY: blockIdx.x = M-tile (M-fast dispatch for B-panel L2 reuse)
#define BK 32

template <int EPI, bool SWAPXY>
__global__ __launch_bounds__(256) void k_gemm(const bf16* __restrict__ A,
    const bf16* __restrict__ B, const float* __restrict__ bias,
    void* __restrict__ Cv, int M, int N, int K, int lda, int ldb, int ldc,
    void* __restrict__ Cv2, void* __restrict__ Cv3) {
  __shared__ __align__(16) bf16 As[128][BK];
  __shared__ __align__(16) bf16 Bs[128][BK];
  int m0 = (SWAPXY ? blockIdx.x : blockIdx.y) * 128;
  int n0 = (SWAPXY ? blockIdx.y : blockIdx.x) * 128;
  int tid = threadIdx.x;
  int lane = tid & 63, wid = tid >> 6;
  int wr = wid >> 1, wc = wid & 1;
  int l15 = lane & 15, hi = lane >> 4;
  int srow = lane >> 2;            // 0..15 within 16-row chunk
  int scol = (lane & 3) * 8;       // element col for 16B chunk
  f32x4 acc[4][4] = {};
  const bf16* Ag0 = A + (long)(m0 + wid * 32 + srow) * lda + scol;
  const bf16* Bg0 = B + (long)(n0 + wid * 32 + srow) * ldb + scol;
  for (int k0 = 0; k0 < K; k0 += BK) {
    gload16(Ag0 + k0, &As[wid * 32][0]);
    gload16(Ag0 + k0 + 16 * lda, &As[wid * 32 + 16][0]);
    gload16(Bg0 + k0, &Bs[wid * 32][0]);
    gload16(Bg0 + k0 + 16 * ldb, &Bs[wid * 32 + 16][0]);
    __syncthreads();
    bf16x8 af[4], bfr[4];
#pragma unroll
    for (int i = 0; i < 4; i++)
      af[i] = *(const bf16x8*)&As[wr * 64 + i * 16 + l15][hi * 8];
#pragma unroll
    for (int i = 0; i < 4; i++)
      bfr[i] = *(const bf16x8*)&Bs[wc * 64 + i * 16 + l15][hi * 8];
#pragma unroll
    for (int i = 0; i < 4; i++)
#pragma unroll
      for (int j = 0; j < 4; j++)
        acc[i][j] = __builtin_amdgcn_mfma_f32_16x16x32_bf16(af[i], bfr[j], acc[i][j], 0, 0, 0);
    __syncthreads();
  }
#pragma unroll
  for (int j = 0; j < 4; j++) {
    int gn = n0 + wc * 64 + j * 16 + l15;
    if (gn >= N) continue;
    float bv = (bias != nullptr) ? bias[gn] : 0.0f;
#pragma unroll
    for (int i = 0; i < 4; i++) {
#pragma unroll
      for (int rr = 0; rr < 4; rr++) {
        int gm = m0 + wr * 64 + i * 16 + hi * 4 + rr;
        float v = acc[i][j][rr] + bv;
        if constexpr (EPI == 0) {
          ((float*)Cv)[(long)gm * ldc + gn] = v;
        } else if constexpr (EPI == 2) {
          float u = 0.7978845608028654f * (v + 0.044715f * v * v * v);
          u = fminf(fmaxf(u, -15.f), 15.f);
          float e2 = __expf(2.f * u);
          float th = (e2 - 1.f) / (e2 + 1.f);
          ((bf16*)Cv)[(long)gm * ldc + gn] = __float2bfloat16(0.5f * v * (1.f + th));
        } else if constexpr (EPI == 5) {
          int gb = gm >> 10, gt = gm & 1023;
          int which = gn / C;
          int r = gn - which * C;
          int h = r >> 6, d = r & 63;
          long bh = (long)(gb * NH + h);
          if (which == 0)
            ((bf16*)Cv)[(bh * T + gt) * DH + d] = __float2bfloat16(v * 0.125f);
          else if (which == 1)
            ((bf16*)Cv2)[(bh * T + gt) * DH + d] = __float2bfloat16(v);
          else
            ((bf16*)Cv3)[(bh * DH + d) * T + gt] = __float2bfloat16(v);
        }
      }
    }
  }
}

// ---------------- small-N GEMM: BM=64, BN=128, residual epilogue ----------
// x[M,N] = A[M,K]*Bt[N,K]^T + bias + x   (in-place residual, fp32 out)
__global__ __launch_bounds__(256) void k_gemm_s(const bf16* __restrict__ A,
    const bf16* __restrict__ B, const float* __restrict__ bias,
    float* __restrict__ Cx, int M, int N, int K, int lda, int ldb, int ldc) {
  __shared__ __align__(16) bf16 As[64][BK];
  __shared__ __align__(16) bf16 Bs[128][BK];
  int m0 = blockIdx.x * 64, n0 = blockIdx.y * 128;
  int tid = threadIdx.x;
  int lane = tid & 63, w = tid >> 6;
  int l15 = lane & 15, hi = lane >> 4;
  int srow = lane >> 2, scol = (lane & 3) * 8;
  f32x4 acc[4][2] = {};
  const bf16* Ag0 = A + (long)(m0 + w * 16 + srow) * lda + scol;
  const bf16* Bg0 = B + (long)(n0 + w * 32 + srow) * ldb + scol;
  for (int k0 = 0; k0 < K; k0 += BK) {
    gload16(Ag0 + k0, &As[w * 16][0]);
    gload16(Bg0 + k0, &Bs[w * 32][0]);
    gload16(Bg0 + k0 + 16 * ldb, &Bs[w * 32 + 16][0]);
    __syncthreads();
    bf16x8 af[4], bfr[2];
#pragma unroll
    for (int i = 0; i < 4; i++)
      af[i] = *(const bf16x8*)&As[i * 16 + l15][hi * 8];
#pragma unroll
    for (int j = 0; j < 2; j++)
      bfr[j] = *(const bf16x8*)&Bs[w * 32 + j * 16 + l15][hi * 8];
#pragma unroll
    for (int i = 0; i < 4; i++)
#pragma unroll
      for (int j = 0; j < 2; j++)
        acc[i][j] = __builtin_amdgcn_mfma_f32_16x16x32_bf16(af[i], bfr[j], acc[i][j], 0, 0, 0);
    __syncthreads();
  }
#pragma unroll
  for (int j = 0; j < 2; j++) {
    int gn = n0 + w * 32 + j * 16 + l15;
    float bv = bias[gn];
#pragma unroll
    for (int i = 0; i < 4; i++)
#pragma unroll
      for (int rr = 0; rr < 4; rr++) {
        int gm = m0 + i * 16 + hi * 4 + rr;
        long off = (long)gm * ldc + gn;
        Cx[off] = acc[i][j][rr] + bv + Cx[off];
      }
  }
}

extern "C" void kernel_launch(void* const* d_in, const int* in_sizes, int n_in,
                              void* d_out, int out_size, void* d_ws, size_t ws_size,
                              hipStream_t stream) {
  const int*   idx    = (const int*)d_in[0];
  const float* wte    = (const float*)d_in[1];
  const float* wpe    = (const float*)d_in[2];
  const float* ln1_w  = (const float*)d_in[3];
  const float* ln1_b  = (const float*)d_in[4];
  const float* qkv_w  = (const float*)d_in[5];
  const float* qkv_b  = (const float*)d_in[6];
  const float* proj_w = (const float*)d_in[7];
  const float* proj_b = (const float*)d_in[8];
  const float* ln2_w  = (const float*)d_in[9];
  const float* ln2_b  = (const float*)d_in[10];
  const float* fc_w   = (const float*)d_in[11];
  const float* fc_b   = (const float*)d_in[12];
  const float* fc2_w  = (const float*)d_in[13];
  const float* fc2_b  = (const float*)d_in[14];
  const float* lnf_w  = (const float*)d_in[15];
  const float* lnf_b  = (const float*)d_in[16];
  const float* head_w = (const float*)d_in[17];
  (void)in_sizes; (void)n_in; (void)out_size; (void)ws_size;

  char* base = (char*)d_ws;
  size_t off = 0;
  auto alloc = [&](size_t bytes) -> void* {
    void* p = base + off;
    off = (off + bytes + 255) & ~(size_t)255;
    return p;
  };
  bf16* wt_qkv  = (bf16*)alloc((size_t)NL * 3 * C * C * 2);
  bf16* wt_proj = (bf16*)alloc((size_t)NL * C * C * 2);
  bf16* wt_fc   = (bf16*)alloc((size_t)NL * 4 * C * C * 2);
  bf16* wt_fc2  = (bf16*)alloc((size_t)NL * 4 * C * C * 2);
  bf16* wt_head = (bf16*)alloc((size_t)V * C * 2);
  float* x      = (float*)alloc((size_t)BTOK * C * 4);   // absorbs head OOB reads
  bf16*  xb     = (bf16*)alloc((size_t)BTOK * C * 2);
  bf16*  qb     = (bf16*)alloc((size_t)NB * NH * T * DH * 2);
  bf16*  kb     = (bf16*)alloc((size_t)NB * NH * T * DH * 2);
  bf16*  vtb    = (bf16*)alloc((size_t)NB * NH * T * DH * 2);
  bf16*  yb     = (bf16*)alloc((size_t)BTOK * C * 2);
  bf16*  mbuf   = (bf16*)alloc((size_t)BTOK * 4 * C * 2);

  dim3 tb(32, 8);
  k_transpose_bf16<<<dim3(72, 24, NL), tb, 0, stream>>>(qkv_w, wt_qkv, C, 3 * C);
  k_transpose_bf16<<<dim3(24, 24, NL), tb, 0, stream>>>(proj_w, wt_proj, C, C);
  k_transpose_bf16<<<dim3(96, 24, NL), tb, 0, stream>>>(fc_w, wt_fc, C, 4 * C);
  k_transpose_bf16<<<dim3(24, 96, NL), tb, 0, stream>>>(fc2_w, wt_fc2, 4 * C, C);
  k_transpose_bf16<<<dim3((V + 31) / 32, 24, 1), tb, 0, stream>>>(head_w, wt_head, C, V);

  k_embed<<<BTOK * C / 256, 256, 0, stream>>>(idx, wte, wpe, x);

  for (int l = 0; l < NL; l++) {
    k_layernorm<<<BTOK, 256, 0, stream>>>(x, ln1_w + l * C, ln1_b + l * C, xb);
    k_gemm<5, true><<<dim3(16, 18), 256, 0, stream>>>(xb, wt_qkv + (long)l * 3 * C * C,
        qkv_b + l * 3 * C, qb, BTOK, 3 * C, C, C, C, 0, kb, vtb);
    k_attn<<<dim3(T / 64, NB * NH), 256, 0, stream>>>(qb, kb, vtb, yb);
    k_gemm_s<<<dim3(32, 6), 256, 0, stream>>>(yb, wt_proj + (long)l * C * C,
        proj_b + l * C, x, BTOK, C, C, C, C, C);
    k_layernorm<<<BTOK, 256, 0, stream>>>(x, ln2_w + l * C, ln2_b + l * C, xb);
    k_gemm<2, true><<<dim3(16, 24), 256, 0, stream>>>(xb, wt_fc + (long)l * 4 * C * C,
        fc_b + l * 4 * C, mbuf, BTOK, 4 * C, C, C, C, 4 * C, nullptr, nullptr);
    k_gemm_s<<<dim3(32, 6), 256, 0, stream>>>(mbuf, wt_fc2 + (long)l * 4 * C * C,
        fc2_b + l * C, x, BTOK, C, 4 * C, 4 * C, 4 * C, C);
  }
  k_layernorm<<<BTOK, 256, 0, stream>>>(x, lnf_w, lnf_b, xb);
  k_gemm<0, true><<<dim3(16, (V + 127) / 128), 256, 0, stream>>>(xb, wt_head, nullptr,
      (float*)d_out, BTOK, V, C, C, C, V, nullptr, nullptr);
}

// Round 4
// 1360.085 us; speedup vs baseline: 1.3059x; 1.0098x over previous
//
#include <hip/hip_runtime.h>
#include <hip/hip_bf16.h>

typedef __hip_bfloat16 bf16;
typedef __attribute__((ext_vector_type(8))) short bf16x8;
typedef __attribute__((ext_vector_type(4))) float f32x4;
typedef __attribute__((ext_vector_type(4), aligned(4))) float f32x4u;  // unaligned-safe

#define NL 4
#define NH 12
#define C 768
#define T 1024
#define NB 2
#define BTOK 2048
#define V 50257
#define DH 64

__device__ __forceinline__ void gload16(const void* g, void* l) {
  __builtin_amdgcn_global_load_lds(
      (const __attribute__((address_space(1))) void*)g,
      (__attribute__((address_space(3))) void*)l, 16, 0, 0);
}

// ---------------- block reductions (256 threads = 4 waves) ----------------
__device__ __forceinline__ float block_sum(float v, float* red) {
#pragma unroll
  for (int off = 32; off; off >>= 1) v += __shfl_down(v, off);
  int lane = threadIdx.x & 63, wid = threadIdx.x >> 6;
  __syncthreads();
  if (lane == 0) red[wid] = v;
  __syncthreads();
  return red[0] + red[1] + red[2] + red[3];
}

// ---------------- embedding ----------------
__global__ __launch_bounds__(256) void k_embed(const int* __restrict__ idx,
    const float* __restrict__ wte, const float* __restrict__ wpe,
    float* __restrict__ x) {
  long i = (long)blockIdx.x * 256 + threadIdx.x;  // over BTOK*C (exact)
  int bt = (int)(i / C), c = (int)(i % C);
  int t = bt & (T - 1);
  x[i] = wte[(long)idx[bt] * C + c] + wpe[(long)t * C + c];
}

// ---------------- fp32 -> bf16 transposed weight convert ----------------
__global__ __launch_bounds__(256) void k_transpose_bf16(const float* __restrict__ W,
    bf16* __restrict__ Wt, int K, int N) {
  __shared__ float tile[32][33];
  long zoff = (long)blockIdx.z * K * N;
  W += zoff;
  Wt += zoff;
  int n0 = blockIdx.x * 32, k0 = blockIdx.y * 32;
  int tx = threadIdx.x, ty = threadIdx.y;
#pragma unroll
  for (int i = 0; i < 4; i++) {
    int k = k0 + ty + i * 8, n = n0 + tx;
    if (k < K && n < N) tile[ty + i * 8][tx] = W[(long)k * N + n];
  }
  __syncthreads();
#pragma unroll
  for (int i = 0; i < 4; i++) {
    int n = n0 + ty + i * 8, k = k0 + tx;
    if (n < N && k < K) Wt[(long)n * K + k] = __float2bfloat16(tile[tx][ty + i * 8]);
  }
}

// ---------------- layernorm: fp32 in -> bf16 out ----------------
__global__ __launch_bounds__(256) void k_layernorm(const float* __restrict__ x,
    const float* __restrict__ w, const float* __restrict__ b, bf16* __restrict__ out) {
  __shared__ float red[4];
  long row = blockIdx.x;
  const float* xr = x + row * C;
  int t = threadIdx.x;
  float v0 = xr[t], v1 = xr[t + 256], v2 = xr[t + 512];
  float s = block_sum(v0 + v1 + v2, red);
  float mu = s * (1.0f / C);
  float d0 = v0 - mu, d1 = v1 - mu, d2 = v2 - mu;
  float vs = block_sum(d0 * d0 + d1 * d1 + d2 * d2, red);
  float inv = rsqrtf(vs * (1.0f / C) + 1e-5f);
  bf16* orow = out + row * C;
  orow[t]       = __float2bfloat16(d0 * inv * w[t]       + b[t]);
  orow[t + 256] = __float2bfloat16(d1 * inv * w[t + 256] + b[t + 256]);
  orow[t + 512] = __float2bfloat16(d2 * inv * w[t + 512] + b[t + 512]);
}

// ---------------- fused causal flash attention ----------------
// grid (T/64, NB*NH); 4 waves/block, wave w owns q rows [qt*64+w*16, +16)
// Pl is strictly per-wave -> NO block barriers needed (same-wave lgkmcnt only)
__global__ __launch_bounds__(256) void k_attn(const bf16* __restrict__ q,
    const bf16* __restrict__ k, const bf16* __restrict__ vt,
    bf16* __restrict__ yb) {
  __shared__ __align__(16) bf16 Pl[4][16][72];  // per-wave P tile, +8 pad
  int qt = blockIdx.x, bh = blockIdx.y;
  int b = bh / NH, h = bh % NH;
  int tid = threadIdx.x, w = tid >> 6, lane = tid & 63;
  int l15 = lane & 15, hi = lane >> 4;
  const bf16* qbase = q + (long)bh * T * DH;
  const bf16* kbase = k + (long)bh * T * DH;
  const bf16* vbase = vt + (long)bh * DH * T;

  int qrow = qt * 64 + w * 16 + l15;  // softmax-layout q (col of S^T)
  bf16x8 qf0 = *(const bf16x8*)(qbase + (long)qrow * DH + hi * 8);
  bf16x8 qf1 = *(const bf16x8*)(qbase + (long)qrow * DH + 32 + hi * 8);

  f32x4 accy[4] = {};               // y: row q=hi*4+rr, col d=j*16+l15
  float m_run = -1e30f, l_run = 0.f;

  int nkt = qt + 1;
  for (int kt = 0; kt < nkt; kt++) {
    int kv0 = kt * 64;
    // S^T = mfma(K, Q): out col(l15)=q, row(hi*4+rr)=kv within 16-block kvi
    f32x4 accs[4] = {};
#pragma unroll
    for (int kvi = 0; kvi < 4; kvi++) {
      const bf16* kr = kbase + (long)(kv0 + kvi * 16 + l15) * DH + hi * 8;
      bf16x8 kf0 = *(const bf16x8*)kr;
      bf16x8 kf1 = *(const bf16x8*)(kr + 32);
      accs[kvi] = __builtin_amdgcn_mfma_f32_16x16x32_bf16(kf0, qf0, accs[kvi], 0, 0, 0);
      accs[kvi] = __builtin_amdgcn_mfma_f32_16x16x32_bf16(kf1, qf1, accs[kvi], 0, 0, 0);
    }
    bool diag = (kt == qt);
    float p[4][4];
    float tmax = -1e30f;
#pragma unroll
    for (int kvi = 0; kvi < 4; kvi++)
#pragma unroll
      for (int rr = 0; rr < 4; rr++) {
        float s = accs[kvi][rr];
        if (diag && (kvi * 16 + hi * 4 + rr > w * 16 + l15)) s = -1e30f;
        p[kvi][rr] = s;
        tmax = fmaxf(tmax, s);
      }
    tmax = fmaxf(tmax, __shfl_xor(tmax, 16));
    tmax = fmaxf(tmax, __shfl_xor(tmax, 32));
    float m_new = fmaxf(m_run, tmax);
    float scl = __expf(m_run - m_new);
    float psum = 0.f;
#pragma unroll
    for (int kvi = 0; kvi < 4; kvi++)
#pragma unroll
      for (int rr = 0; rr < 4; rr++) {
        float e = __expf(p[kvi][rr] - m_new);
        p[kvi][rr] = e;
        psum += e;
      }
    psum += __shfl_xor(psum, 16);
    psum += __shfl_xor(psum, 32);
    l_run = l_run * scl + psum;
    m_run = m_new;
#pragma unroll
    for (int rr = 0; rr < 4; rr++) {
      float sy = __shfl(scl, hi * 4 + rr);
#pragma unroll
      for (int j = 0; j < 4; j++) accy[j][rr] *= sy;
    }
    // P -> LDS (bf16), row = q(l15), col = kv  (per-wave buffer)
#pragma unroll
    for (int kvi = 0; kvi < 4; kvi++) {
      union { bf16 hh[2]; unsigned u; } pk0, pk1;
      pk0.hh[0] = __float2bfloat16(p[kvi][0]);
      pk0.hh[1] = __float2bfloat16(p[kvi][1]);
      pk1.hh[0] = __float2bfloat16(p[kvi][2]);
      pk1.hh[1] = __float2bfloat16(p[kvi][3]);
      *(unsigned*)&Pl[w][l15][kvi * 16 + hi * 4]     = pk0.u;
      *(unsigned*)&Pl[w][l15][kvi * 16 + hi * 4 + 2] = pk1.u;
    }
    // PV: A=P (row=q=l15, k=kv), B=V^T (row=d, k=kv)
#pragma unroll
    for (int c = 0; c < 2; c++) {
      bf16x8 pf = *(const bf16x8*)&Pl[w][l15][c * 32 + hi * 8];
#pragma unroll
      for (int j = 0; j < 4; j++) {
        const bf16* vr = vbase + (long)(j * 16 + l15) * T + kv0 + c * 32 + hi * 8;
        bf16x8 vf = *(const bf16x8*)vr;
        accy[j] = __builtin_amdgcn_mfma_f32_16x16x32_bf16(pf, vf, accy[j], 0, 0, 0);
      }
    }
  }
  float inv = 1.0f / l_run;
#pragma unroll
  for (int rr = 0; rr < 4; rr++) {
    float li = __shfl(inv, hi * 4 + rr);
    int qg = qt * 64 + w * 16 + hi * 4 + rr;
#pragma unroll
    for (int j = 0; j < 4; j++)
      yb[((long)(b * T + qg)) * C + h * DH + j * 16 + l15] =
          __float2bfloat16(accy[j][rr] * li);
  }
}

// ---------------- NT GEMM: BK=64, T2 XOR-swizzled LDS, T1 XCD swizzle ------
// C[M,N] = A[M,K] * Bt[N,K]^T (+epilogue)
// EPI 0: fp32 out (+bias), LDS-transposed float4 stores
// EPI 2: bf16 out, gelu(acc+bias)
// EPI 5: qkv split-repack: Cv=q (scaled 0.125), Cv2=k, Cv3=vt
// requires: grid.x*grid.y % 8 == 0, M%128==0, K%64==0
#define BK 64

template <int EPI, bool SWAPXY>
__global__ __launch_bounds__(256) void k_gemm(const bf16* __restrict__ A,
    const bf16* __restrict__ B, const float* __restrict__ bias,
    void* __restrict__ Cv, int M, int N, int K, int lda, int ldb, int ldc,
    void* __restrict__ Cv2, void* __restrict__ Cv3) {
  __shared__ __align__(16) bf16 smem[2][128][BK];  // 32 KiB; A=smem[0], B=smem[1]
  // T1: bijective XCD-chunked swizzle (nwg % 8 == 0 by construction)
  int nwg = gridDim.x * gridDim.y;
  int hw = blockIdx.y * gridDim.x + blockIdx.x;
  int logical = (hw & 7) * (nwg >> 3) + (hw >> 3);
  int bx = logical % gridDim.x, by = logical / gridDim.x;
  int m0 = (SWAPXY ? bx : by) * 128;
  int n0 = (SWAPXY ? by : bx) * 128;
  int tid = threadIdx.x;
  int lane = tid & 63, wid = tid >> 6;
  int wr = wid >> 1, wc = wid & 1;
  int l15 = lane & 15, hi = lane >> 4;
  // staging: issue q covers rows [wid*32+q*8, +8); lane -> row+chunk
  int srow_i = lane >> 3;          // row within 8-row issue
  int scc = lane & 7;              // LDS 16B-chunk within 128B row
  int scol = ((scc ^ srow_i) << 3);  // T2 pre-swizzled source col (elements)
  f32x4 acc[4][4] = {};
  const bf16* Ag = A + (long)(m0 + srow_i) * lda + scol;
  const bf16* Bg = B + (long)(n0 + srow_i) * ldb + scol;
  int x7 = l15 & 7;
  for (int k0 = 0; k0 < K; k0 += BK) {
#pragma unroll
    for (int qi = 0; qi < 4; qi++) {
      int R0 = wid * 32 + qi * 8;
      gload16(Ag + (long)R0 * lda + k0, &smem[0][R0][0]);
      gload16(Bg + (long)R0 * ldb + k0, &smem[1][R0][0]);
    }
    __syncthreads();
#pragma unroll
    for (int kk = 0; kk < 2; kk++) {
      int cofs = ((kk * 4 + hi) ^ x7) << 3;  // T2 swizzled read col (elements)
      bf16x8 af[4], bfr[4];
#pragma unroll
      for (int i = 0; i < 4; i++)
        af[i] = *(const bf16x8*)&smem[0][wr * 64 + i * 16 + l15][cofs];
#pragma unroll
      for (int j = 0; j < 4; j++)
        bfr[j] = *(const bf16x8*)&smem[1][wc * 64 + j * 16 + l15][cofs];
#pragma unroll
      for (int i = 0; i < 4; i++)
#pragma unroll
        for (int j = 0; j < 4; j++)
          acc[i][j] = __builtin_amdgcn_mfma_f32_16x16x32_bf16(af[i], bfr[j], acc[i][j], 0, 0, 0);
    }
    __syncthreads();
  }
  if constexpr (EPI == 0) {
    // LDS-transposed epilogue: contiguous 16B stores per lane
    float* Ct = (float*)&smem[0][0][0];  // 32 x 128 fp32 = 16 KiB
#pragma unroll
    for (int i = 0; i < 4; i++) {
#pragma unroll
      for (int j = 0; j < 4; j++) {
        int lc = wc * 64 + j * 16 + l15;
#pragma unroll
        for (int rr = 0; rr < 4; rr++)
          Ct[(wr * 16 + hi * 4 + rr) * 128 + lc] = acc[i][j][rr];
      }
      __syncthreads();
#pragma unroll
      for (int s = 0; s < 4; s++) {
        int idxq = tid + s * 256;          // 0..1023
        int lr = idxq >> 5;                // 0..31
        int c4 = (idxq & 31) * 4;          // 0..124
        int gm = m0 + (lr >> 4) * 64 + i * 16 + (lr & 15);
        int gn = n0 + c4;
        f32x4 vv = *(const f32x4*)&Ct[lr * 128 + c4];
        if (bias != nullptr) {
#pragma unroll
          for (int e = 0; e < 4; e++) vv[e] += bias[gn + e];
        }
        float* dst = (float*)Cv + (long)gm * ldc + gn;
        if (gn + 3 < N) {
          *(f32x4u*)dst = vv;
        } else {
#pragma unroll
          for (int e = 0; e < 4; e++)
            if (gn + e < N) dst[e] = vv[e];
        }
      }
      __syncthreads();
    }
  } else {
#pragma unroll
    for (int j = 0; j < 4; j++) {
      int gn = n0 + wc * 64 + j * 16 + l15;
      if (gn >= N) continue;
      float bv = (bias != nullptr) ? bias[gn] : 0.0f;
#pragma unroll
      for (int i = 0; i < 4; i++) {
#pragma unroll
        for (int rr = 0; rr < 4; rr++) {
          int gm = m0 + wr * 64 + i * 16 + hi * 4 + rr;
          float v = acc[i][j][rr] + bv;
          if constexpr (EPI == 2) {
            float u = 0.7978845608028654f * (v + 0.044715f * v * v * v);
            u = fminf(fmaxf(u, -15.f), 15.f);
            float e2 = __expf(2.f * u);
            float th = (e2 - 1.f) / (e2 + 1.f);
            ((bf16*)Cv)[(long)gm * ldc + gn] = __float2bfloat16(0.5f * v * (1.f + th));
          } else if constexpr (EPI == 5) {
            int gb = gm >> 10, gt = gm & 1023;
            int which = gn / C;
            int r = gn - which * C;
            int h = r >> 6, d = r & 63;
            long bh = (long)(gb * NH + h);
            if (which == 0)
              ((bf16*)Cv)[(bh * T + gt) * DH + d] = __float2bfloat16(v * 0.125f);
            else if (which == 1)
              ((bf16*)Cv2)[(bh * T + gt) * DH + d] = __float2bfloat16(v);
            else
              ((bf16*)Cv3)[(bh * DH + d) * T + gt] = __float2bfloat16(v);
          }
        }
      }
    }
  }
}

// ---------------- small-N GEMM: BM=64, BN=128, residual epilogue ----------
#define SBK 32
__global__ __launch_bounds__(256) void k_gemm_s(const bf16* __restrict__ A,
    const bf16* __restrict__ B, const float* __restrict__ bias,
    float* __restrict__ Cx, int M, int N, int K, int lda, int ldb, int ldc) {
  __shared__ __align__(16) bf16 As[64][SBK];
  __shared__ __align__(16) bf16 Bs[128][SBK];
  int m0 = blockIdx.x * 64, n0 = blockIdx.y * 128;
  int tid = threadIdx.x;
  int lane = tid & 63, w = tid >> 6;
  int l15 = lane & 15, hi = lane >> 4;
  int srow = lane >> 2, scol = (lane & 3) * 8;
  f32x4 acc[4][2] = {};
  const bf16* Ag0 = A + (long)(m0 + w * 16 + srow) * lda + scol;
  const bf16* Bg0 = B + (long)(n0 + w * 32 + srow) * ldb + scol;
  for (int k0 = 0; k0 < K; k0 += SBK) {
    gload16(Ag0 + k0, &As[w * 16][0]);
    gload16(Bg0 + k0, &Bs[w * 32][0]);
    gload16(Bg0 + k0 + 16 * ldb, &Bs[w * 32 + 16][0]);
    __syncthreads();
    bf16x8 af[4], bfr[2];
#pragma unroll
    for (int i = 0; i < 4; i++)
      af[i] = *(const bf16x8*)&As[i * 16 + l15][hi * 8];
#pragma unroll
    for (int j = 0; j < 2; j++)
      bfr[j] = *(const bf16x8*)&Bs[w * 32 + j * 16 + l15][hi * 8];
#pragma unroll
    for (int i = 0; i < 4; i++)
#pragma unroll
      for (int j = 0; j < 2; j++)
        acc[i][j] = __builtin_amdgcn_mfma_f32_16x16x32_bf16(af[i], bfr[j], acc[i][j], 0, 0, 0);
    __syncthreads();
  }
#pragma unroll
  for (int j = 0; j < 2; j++) {
    int gn = n0 + w * 32 + j * 16 + l15;
    float bv = bias[gn];
#pragma unroll
    for (int i = 0; i < 4; i++)
#pragma unroll
      for (int rr = 0; rr < 4; rr++) {
        int gm = m0 + i * 16 + hi * 4 + rr;
        long off = (long)gm * ldc + gn;
        Cx[off] = acc[i][j][rr] + bv + Cx[off];
      }
  }
}

extern "C" void kernel_launch(void* const* d_in, const int* in_sizes, int n_in,
                              void* d_out, int out_size, void* d_ws, size_t ws_size,
                              hipStream_t stream) {
  const int*   idx    = (const int*)d_in[0];
  const float* wte    = (const float*)d_in[1];
  const float* wpe    = (const float*)d_in[2];
  const float* ln1_w  = (const float*)d_in[3];
  const float* ln1_b  = (const float*)d_in[4];
  const float* qkv_w  = (const float*)d_in[5];
  const float* qkv_b  = (const float*)d_in[6];
  const float* proj_w = (const float*)d_in[7];
  const float* proj_b = (const float*)d_in[8];
  const float* ln2_w  = (const float*)d_in[9];
  const float* ln2_b  = (const float*)d_in[10];
  const float* fc_w   = (const float*)d_in[11];
  const float* fc_b   = (const float*)d_in[12];
  const float* fc2_w  = (const float*)d_in[13];
  const float* fc2_b  = (const float*)d_in[14];
  const float* lnf_w  = (const float*)d_in[15];
  const float* lnf_b  = (const float*)d_in[16];
  const float* head_w = (const float*)d_in[17];
  (void)in_sizes; (void)n_in; (void)out_size; (void)ws_size;

  char* base = (char*)d_ws;
  size_t off = 0;
  auto alloc = [&](size_t bytes) -> void* {
    void* p = base + off;
    off = (off + bytes + 255) & ~(size_t)255;
    return p;
  };
  bf16* wt_qkv  = (bf16*)alloc((size_t)NL * 3 * C * C * 2);
  bf16* wt_proj = (bf16*)alloc((size_t)NL * C * C * 2);
  bf16* wt_fc   = (bf16*)alloc((size_t)NL * 4 * C * C * 2);
  bf16* wt_fc2  = (bf16*)alloc((size_t)NL * 4 * C * C * 2);
  bf16* wt_head = (bf16*)alloc((size_t)V * C * 2);
  float* x      = (float*)alloc((size_t)BTOK * C * 4);   // absorbs head OOB reads
  bf16*  xb     = (bf16*)alloc((size_t)BTOK * C * 2);
  bf16*  qb     = (bf16*)alloc((size_t)NB * NH * T * DH * 2);
  bf16*  kb     = (bf16*)alloc((size_t)NB * NH * T * DH * 2);
  bf16*  vtb    = (bf16*)alloc((size_t)NB * NH * T * DH * 2);
  bf16*  yb     = (bf16*)alloc((size_t)BTOK * C * 2);
  bf16*  mbuf   = (bf16*)alloc((size_t)BTOK * 4 * C * 2);

  dim3 tb(32, 8);
  k_transpose_bf16<<<dim3(72, 24, NL), tb, 0, stream>>>(qkv_w, wt_qkv, C, 3 * C);
  k_transpose_bf16<<<dim3(24, 24, NL), tb, 0, stream>>>(proj_w, wt_proj, C, C);
  k_transpose_bf16<<<dim3(96, 24, NL), tb, 0, stream>>>(fc_w, wt_fc, C, 4 * C);
  k_transpose_bf16<<<dim3(24, 96, NL), tb, 0, stream>>>(fc2_w, wt_fc2, 4 * C, C);
  k_transpose_bf16<<<dim3((V + 31) / 32, 24, 1), tb, 0, stream>>>(head_w, wt_head, C, V);

  k_embed<<<BTOK * C / 256, 256, 0, stream>>>(idx, wte, wpe, x);

  for (int l = 0; l < NL; l++) {
    k_layernorm<<<BTOK, 256, 0, stream>>>(x, ln1_w + l * C, ln1_b + l * C, xb);
    k_gemm<5, true><<<dim3(16, 18), 256, 0, stream>>>(xb, wt_qkv + (long)l * 3 * C * C,
        qkv_b + l * 3 * C, qb, BTOK, 3 * C, C, C, C, 0, kb, vtb);
    k_attn<<<dim3(T / 64, NB * NH), 256, 0, stream>>>(qb, kb, vtb, yb);
    k_gemm_s<<<dim3(32, 6), 256, 0, stream>>>(yb, wt_proj + (long)l * C * C,
        proj_b + l * C, x, BTOK, C, C, C, C, C);
    k_layernorm<<<BTOK, 256, 0, stream>>>(x, ln2_w + l * C, ln2_b + l * C, xb);
    k_gemm<2, true><<<dim3(16, 24), 256, 0, stream>>>(xb, wt_fc + (long)l * 4 * C * C,
        fc_b + l * 4 * C, mbuf, BTOK, 4 * C, C, C, C, 4 * C, nullptr, nullptr);
    k_gemm_s<<<dim3(32, 6), 256, 0, stream>>>(mbuf, wt_fc2 + (long)l * 4 * C * C,
        fc2_b + l * C, x, BTOK, C, 4 * C, 4 * C, 4 * C, C);
  }
  k_layernorm<<<BTOK, 256, 0, stream>>>(x, lnf_w, lnf_b, xb);
  k_gemm<0, true><<<dim3(16, (V + 127) / 128), 256, 0, stream>>>(xb, wt_head, nullptr,
      (float*)d_out, BTOK, V, C, C, C, V, nullptr, nullptr);
}

// Round 5
// 1204.417 us; speedup vs baseline: 1.4747x; 1.1292x over previous
//
#include <hip/hip_runtime.h>
#include <hip/hip_bf16.h>

typedef __hip_bfloat16 bf16;
typedef __attribute__((ext_vector_type(8))) short bf16x8;
typedef __attribute__((ext_vector_type(4))) float f32x4;
typedef __attribute__((ext_vector_type(4), aligned(4))) float f32x4u;  // unaligned-safe

#define NL 4
#define NH 12
#define C 768
#define T 1024
#define NB 2
#define BTOK 2048
#define V 50257
#define DH 64

__device__ __forceinline__ void gload16(const void* g, void* l) {
  __builtin_amdgcn_global_load_lds(
      (const __attribute__((address_space(1))) void*)g,
      (__attribute__((address_space(3))) void*)l, 16, 0, 0);
}

// ---------------- block reductions (256 threads = 4 waves) ----------------
__device__ __forceinline__ float block_sum(float v, float* red) {
#pragma unroll
  for (int off = 32; off; off >>= 1) v += __shfl_down(v, off);
  int lane = threadIdx.x & 63, wid = threadIdx.x >> 6;
  __syncthreads();
  if (lane == 0) red[wid] = v;
  __syncthreads();
  return red[0] + red[1] + red[2] + red[3];
}

// ---------------- embedding ----------------
__global__ __launch_bounds__(256) void k_embed(const int* __restrict__ idx,
    const float* __restrict__ wte, const float* __restrict__ wpe,
    float* __restrict__ x) {
  long i = (long)blockIdx.x * 256 + threadIdx.x;  // over BTOK*C (exact)
  int bt = (int)(i / C), c = (int)(i % C);
  int t = bt & (T - 1);
  x[i] = wte[(long)idx[bt] * C + c] + wpe[(long)t * C + c];
}

// ---------------- fp32 -> bf16 transposed weight convert ----------------
__global__ __launch_bounds__(256) void k_transpose_bf16(const float* __restrict__ W,
    bf16* __restrict__ Wt, int K, int N) {
  __shared__ float tile[32][33];
  long zoff = (long)blockIdx.z * K * N;
  W += zoff;
  Wt += zoff;
  int n0 = blockIdx.x * 32, k0 = blockIdx.y * 32;
  int tx = threadIdx.x, ty = threadIdx.y;
#pragma unroll
  for (int i = 0; i < 4; i++) {
    int k = k0 + ty + i * 8, n = n0 + tx;
    if (k < K && n < N) tile[ty + i * 8][tx] = W[(long)k * N + n];
  }
  __syncthreads();
#pragma unroll
  for (int i = 0; i < 4; i++) {
    int n = n0 + ty + i * 8, k = k0 + tx;
    if (n < N && k < K) Wt[(long)n * K + k] = __float2bfloat16(tile[tx][ty + i * 8]);
  }
}

// ---------------- layernorm: fp32 in -> bf16 out ----------------
__global__ __launch_bounds__(256) void k_layernorm(const float* __restrict__ x,
    const float* __restrict__ w, const float* __restrict__ b, bf16* __restrict__ out) {
  __shared__ float red[4];
  long row = blockIdx.x;
  const float* xr = x + row * C;
  int t = threadIdx.x;
  float v0 = xr[t], v1 = xr[t + 256], v2 = xr[t + 512];
  float s = block_sum(v0 + v1 + v2, red);
  float mu = s * (1.0f / C);
  float d0 = v0 - mu, d1 = v1 - mu, d2 = v2 - mu;
  float vs = block_sum(d0 * d0 + d1 * d1 + d2 * d2, red);
  float inv = rsqrtf(vs * (1.0f / C) + 1e-5f);
  bf16* orow = out + row * C;
  orow[t]       = __float2bfloat16(d0 * inv * w[t]       + b[t]);
  orow[t + 256] = __float2bfloat16(d1 * inv * w[t + 256] + b[t + 256]);
  orow[t + 512] = __float2bfloat16(d2 * inv * w[t + 512] + b[t + 512]);
}

// ---------------- fused causal flash attention ----------------
// grid (T/64, NB*NH); 4 waves/block, wave w owns q rows [qt*64+w*16, +16)
// Pl is strictly per-wave -> NO block barriers needed (same-wave lgkmcnt only)
__global__ __launch_bounds__(256) void k_attn(const bf16* __restrict__ q,
    const bf16* __restrict__ k, const bf16* __restrict__ vt,
    bf16* __restrict__ yb) {
  __shared__ __align__(16) bf16 Pl[4][16][72];  // per-wave P tile, +8 pad
  int qt = blockIdx.x, bh = blockIdx.y;
  int b = bh / NH, h = bh % NH;
  int tid = threadIdx.x, w = tid >> 6, lane = tid & 63;
  int l15 = lane & 15, hi = lane >> 4;
  const bf16* qbase = q + (long)bh * T * DH;
  const bf16* kbase = k + (long)bh * T * DH;
  const bf16* vbase = vt + (long)bh * DH * T;

  int qrow = qt * 64 + w * 16 + l15;  // softmax-layout q (col of S^T)
  bf16x8 qf0 = *(const bf16x8*)(qbase + (long)qrow * DH + hi * 8);
  bf16x8 qf1 = *(const bf16x8*)(qbase + (long)qrow * DH + 32 + hi * 8);

  f32x4 accy[4] = {};               // y: row q=hi*4+rr, col d=j*16+l15
  float m_run = -1e30f, l_run = 0.f;

  int nkt = qt + 1;
  for (int kt = 0; kt < nkt; kt++) {
    int kv0 = kt * 64;
    // S^T = mfma(K, Q): out col(l15)=q, row(hi*4+rr)=kv within 16-block kvi
    f32x4 accs[4] = {};
#pragma unroll
    for (int kvi = 0; kvi < 4; kvi++) {
      const bf16* kr = kbase + (long)(kv0 + kvi * 16 + l15) * DH + hi * 8;
      bf16x8 kf0 = *(const bf16x8*)kr;
      bf16x8 kf1 = *(const bf16x8*)(kr + 32);
      accs[kvi] = __builtin_amdgcn_mfma_f32_16x16x32_bf16(kf0, qf0, accs[kvi], 0, 0, 0);
      accs[kvi] = __builtin_amdgcn_mfma_f32_16x16x32_bf16(kf1, qf1, accs[kvi], 0, 0, 0);
    }
    bool diag = (kt == qt);
    float p[4][4];
    float tmax = -1e30f;
#pragma unroll
    for (int kvi = 0; kvi < 4; kvi++)
#pragma unroll
      for (int rr = 0; rr < 4; rr++) {
        float s = accs[kvi][rr];
        if (diag && (kvi * 16 + hi * 4 + rr > w * 16 + l15)) s = -1e30f;
        p[kvi][rr] = s;
        tmax = fmaxf(tmax, s);
      }
    tmax = fmaxf(tmax, __shfl_xor(tmax, 16));
    tmax = fmaxf(tmax, __shfl_xor(tmax, 32));
    float m_new = fmaxf(m_run, tmax);
    float scl = __expf(m_run - m_new);
    float psum = 0.f;
#pragma unroll
    for (int kvi = 0; kvi < 4; kvi++)
#pragma unroll
      for (int rr = 0; rr < 4; rr++) {
        float e = __expf(p[kvi][rr] - m_new);
        p[kvi][rr] = e;
        psum += e;
      }
    psum += __shfl_xor(psum, 16);
    psum += __shfl_xor(psum, 32);
    l_run = l_run * scl + psum;
    m_run = m_new;
#pragma unroll
    for (int rr = 0; rr < 4; rr++) {
      float sy = __shfl(scl, hi * 4 + rr);
#pragma unroll
      for (int j = 0; j < 4; j++) accy[j][rr] *= sy;
    }
    // P -> LDS (bf16), row = q(l15), col = kv  (per-wave buffer)
#pragma unroll
    for (int kvi = 0; kvi < 4; kvi++) {
      union { bf16 hh[2]; unsigned u; } pk0, pk1;
      pk0.hh[0] = __float2bfloat16(p[kvi][0]);
      pk0.hh[1] = __float2bfloat16(p[kvi][1]);
      pk1.hh[0] = __float2bfloat16(p[kvi][2]);
      pk1.hh[1] = __float2bfloat16(p[kvi][3]);
      *(unsigned*)&Pl[w][l15][kvi * 16 + hi * 4]     = pk0.u;
      *(unsigned*)&Pl[w][l15][kvi * 16 + hi * 4 + 2] = pk1.u;
    }
    // PV: A=P (row=q=l15, k=kv), B=V^T (row=d, k=kv)
#pragma unroll
    for (int c = 0; c < 2; c++) {
      bf16x8 pf = *(const bf16x8*)&Pl[w][l15][c * 32 + hi * 8];
#pragma unroll
      for (int j = 0; j < 4; j++) {
        const bf16* vr = vbase + (long)(j * 16 + l15) * T + kv0 + c * 32 + hi * 8;
        bf16x8 vf = *(const bf16x8*)vr;
        accy[j] = __builtin_amdgcn_mfma_f32_16x16x32_bf16(pf, vf, accy[j], 0, 0, 0);
      }
    }
  }
  float inv = 1.0f / l_run;
#pragma unroll
  for (int rr = 0; rr < 4; rr++) {
    float li = __shfl(inv, hi * 4 + rr);
    int qg = qt * 64 + w * 16 + hi * 4 + rr;
#pragma unroll
    for (int j = 0; j < 4; j++)
      yb[((long)(b * T + qg)) * C + h * DH + j * 16 + l15] =
          __float2bfloat16(accy[j][rr] * li);
  }
}

// ---------------- NT GEMM: depth-2 pipelined, counted vmcnt, BK=32 ----------
// C[M,N] = A[M,K] * Bt[N,K]^T (+epilogue)
// LDS swizzle: LDS[row][c16] holds global chunk c16 ^ ((row>>1)&3) (2-way free)
// EPI 0: fp32 out (+bias), LDS-transposed float4 stores
// EPI 2: bf16 out, gelu(acc+bias)
// EPI 5: qkv split-repack: Cv=q (scaled 0.125), Cv2=k, Cv3=vt
// requires: grid.x*grid.y % 8 == 0, M%128==0, K%32==0, K>=64
#define BK 32

template <int EPI, bool SWAPXY>
__global__ __launch_bounds__(256) void k_gemm(const bf16* __restrict__ A,
    const bf16* __restrict__ B, const float* __restrict__ bias,
    void* __restrict__ Cv, int M, int N, int K, int lda, int ldb, int ldc,
    void* __restrict__ Cv2, void* __restrict__ Cv3) {
  __shared__ __align__(16) bf16 As[2][128][BK];  // 16 KiB (also epilogue Ct)
  __shared__ __align__(16) bf16 Bs[2][128][BK];  // 16 KiB
  // T1: bijective XCD-chunked swizzle (nwg % 8 == 0 by construction)
  int nwg = gridDim.x * gridDim.y;
  int hw = blockIdx.y * gridDim.x + blockIdx.x;
  int logical = (hw & 7) * (nwg >> 3) + (hw >> 3);
  int bx = logical % gridDim.x, by = logical / gridDim.x;
  int m0 = (SWAPXY ? bx : by) * 128;
  int n0 = (SWAPXY ? by : bx) * 128;
  int tid = threadIdx.x;
  int lane = tid & 63, wid = tid >> 6;
  int wr = wid >> 1, wc = wid & 1;
  int l15 = lane & 15, hi = lane >> 4;
  // staging: each issue covers 16 rows x 64B; lane -> (row=lane>>2, chunk=lane&3)
  int srow = lane >> 2;
  int scol = (((lane & 3) ^ ((lane >> 3) & 3)) << 3);  // pre-swizzled source col
  f32x4 acc[4][4] = {};
  const bf16* Ag = A + (long)(m0 + wid * 32 + srow) * lda + scol;
  const bf16* Bg = B + (long)(n0 + wid * 32 + srow) * ldb + scol;
  int NT = K / BK;
  auto STAGE = [&](int t) {
    int k0 = t * BK, b = t & 1;
    gload16(Ag + k0,            &As[b][wid * 32][0]);
    gload16(Ag + k0 + 16 * lda, &As[b][wid * 32 + 16][0]);
    gload16(Bg + k0,            &Bs[b][wid * 32][0]);
    gload16(Bg + k0 + 16 * ldb, &Bs[b][wid * 32 + 16][0]);
  };
  STAGE(0);
  STAGE(1);
  int cA = (hi ^ ((l15 >> 1) & 3)) << 3;  // swizzled read col (elements)
  for (int t = 0; t < NT; t++) {
    int b = t & 1;
    if (t + 1 < NT) asm volatile("s_waitcnt vmcnt(4)" ::: "memory");
    else            asm volatile("s_waitcnt vmcnt(0)" ::: "memory");
    __builtin_amdgcn_s_barrier();
    bf16x8 af[4], bfr[4];
#pragma unroll
    for (int i = 0; i < 4; i++)
      af[i] = *(const bf16x8*)&As[b][wr * 64 + i * 16 + l15][cA];
#pragma unroll
    for (int j = 0; j < 4; j++)
      bfr[j] = *(const bf16x8*)&Bs[b][wc * 64 + j * 16 + l15][cA];
    asm volatile("s_waitcnt lgkmcnt(0)" ::: "memory");
    __builtin_amdgcn_s_barrier();
    if (t + 2 < NT) STAGE(t + 2);
#pragma unroll
    for (int i = 0; i < 4; i++)
#pragma unroll
      for (int j = 0; j < 4; j++)
        acc[i][j] = __builtin_amdgcn_mfma_f32_16x16x32_bf16(af[i], bfr[j], acc[i][j], 0, 0, 0);
  }
  if constexpr (EPI == 0) {
    // LDS-transposed epilogue: contiguous 16B stores per lane
    float* Ct = (float*)&As[0][0][0];  // 32 x 128 fp32 = 16 KiB
    __syncthreads();
#pragma unroll
    for (int i = 0; i < 4; i++) {
#pragma unroll
      for (int j = 0; j < 4; j++) {
        int lc = wc * 64 + j * 16 + l15;
#pragma unroll
        for (int rr = 0; rr < 4; rr++)
          Ct[(wr * 16 + hi * 4 + rr) * 128 + lc] = acc[i][j][rr];
      }
      __syncthreads();
#pragma unroll
      for (int s = 0; s < 4; s++) {
        int idxq = tid + s * 256;          // 0..1023
        int lr = idxq >> 5;                // 0..31
        int c4 = (idxq & 31) * 4;          // 0..124
        int gm = m0 + (lr >> 4) * 64 + i * 16 + (lr & 15);
        int gn = n0 + c4;
        f32x4 vv = *(const f32x4*)&Ct[lr * 128 + c4];
        if (bias != nullptr) {
#pragma unroll
          for (int e = 0; e < 4; e++) vv[e] += bias[gn + e];
        }
        float* dst = (float*)Cv + (long)gm * ldc + gn;
        if (gn + 3 < N) {
          *(f32x4u*)dst = vv;
        } else {
#pragma unroll
          for (int e = 0; e < 4; e++)
            if (gn + e < N) dst[e] = vv[e];
        }
      }
      __syncthreads();
    }
  } else {
#pragma unroll
    for (int j = 0; j < 4; j++) {
      int gn = n0 + wc * 64 + j * 16 + l15;
      if (gn >= N) continue;
      float bv = (bias != nullptr) ? bias[gn] : 0.0f;
#pragma unroll
      for (int i = 0; i < 4; i++) {
#pragma unroll
        for (int rr = 0; rr < 4; rr++) {
          int gm = m0 + wr * 64 + i * 16 + hi * 4 + rr;
          float v = acc[i][j][rr] + bv;
          if constexpr (EPI == 2) {
            float u = 0.7978845608028654f * (v + 0.044715f * v * v * v);
            u = fminf(fmaxf(u, -15.f), 15.f);
            float e2 = __expf(2.f * u);
            float th = (e2 - 1.f) / (e2 + 1.f);
            ((bf16*)Cv)[(long)gm * ldc + gn] = __float2bfloat16(0.5f * v * (1.f + th));
          } else if constexpr (EPI == 5) {
            int gb = gm >> 10, gt = gm & 1023;
            int which = gn / C;
            int r = gn - which * C;
            int h = r >> 6, d = r & 63;
            long bh = (long)(gb * NH + h);
            if (which == 0)
              ((bf16*)Cv)[(bh * T + gt) * DH + d] = __float2bfloat16(v * 0.125f);
            else if (which == 1)
              ((bf16*)Cv2)[(bh * T + gt) * DH + d] = __float2bfloat16(v);
            else
              ((bf16*)Cv3)[(bh * DH + d) * T + gt] = __float2bfloat16(v);
          }
        }
      }
    }
  }
}

// ---------------- small-N GEMM: BM=64, BN=128, depth-2 pipeline, residual ---
__global__ __launch_bounds__(256) void k_gemm_s(const bf16* __restrict__ A,
    const bf16* __restrict__ B, const float* __restrict__ bias,
    float* __restrict__ Cx, int M, int N, int K, int lda, int ldb, int ldc) {
  __shared__ __align__(16) bf16 As[2][64][BK];
  __shared__ __align__(16) bf16 Bs[2][128][BK];
  int m0 = blockIdx.x * 64, n0 = blockIdx.y * 128;
  int tid = threadIdx.x;
  int lane = tid & 63, w = tid >> 6;
  int l15 = lane & 15, hi = lane >> 4;
  int srow = lane >> 2;
  int scol = (((lane & 3) ^ ((lane >> 3) & 3)) << 3);
  f32x4 acc[4][2] = {};
  const bf16* Ag = A + (long)(m0 + w * 16 + srow) * lda + scol;
  const bf16* Bg = B + (long)(n0 + w * 32 + srow) * ldb + scol;
  int NT = K / BK;
  auto STAGE = [&](int t) {
    int k0 = t * BK, b = t & 1;
    gload16(Ag + k0,            &As[b][w * 16][0]);
    gload16(Bg + k0,            &Bs[b][w * 32][0]);
    gload16(Bg + k0 + 16 * ldb, &Bs[b][w * 32 + 16][0]);
  };
  STAGE(0);
  STAGE(1);
  int cA = (hi ^ ((l15 >> 1) & 3)) << 3;
  for (int t = 0; t < NT; t++) {
    int b = t & 1;
    if (t + 1 < NT) asm volatile("s_waitcnt vmcnt(3)" ::: "memory");
    else            asm volatile("s_waitcnt vmcnt(0)" ::: "memory");
    __builtin_amdgcn_s_barrier();
    bf16x8 af[4], bfr[2];
#pragma unroll
    for (int i = 0; i < 4; i++)
      af[i] = *(const bf16x8*)&As[b][i * 16 + l15][cA];
#pragma unroll
    for (int j = 0; j < 2; j++)
      bfr[j] = *(const bf16x8*)&Bs[b][w * 32 + j * 16 + l15][cA];
    asm volatile("s_waitcnt lgkmcnt(0)" ::: "memory");
    __builtin_amdgcn_s_barrier();
    if (t + 2 < NT) STAGE(t + 2);
#pragma unroll
    for (int i = 0; i < 4; i++)
#pragma unroll
      for (int j = 0; j < 2; j++)
        acc[i][j] = __builtin_amdgcn_mfma_f32_16x16x32_bf16(af[i], bfr[j], acc[i][j], 0, 0, 0);
  }
#pragma unroll
  for (int j = 0; j < 2; j++) {
    int gn = n0 + w * 32 + j * 16 + l15;
    float bv = bias[gn];
#pragma unroll
    for (int i = 0; i < 4; i++)
#pragma unroll
      for (int rr = 0; rr < 4; rr++) {
        int gm = m0 + i * 16 + hi * 4 + rr;
        long off = (long)gm * ldc + gn;
        Cx[off] = acc[i][j][rr] + bv + Cx[off];
      }
  }
}

extern "C" void kernel_launch(void* const* d_in, const int* in_sizes, int n_in,
                              void* d_out, int out_size, void* d_ws, size_t ws_size,
                              hipStream_t stream) {
  const int*   idx    = (const int*)d_in[0];
  const float* wte    = (const float*)d_in[1];
  const float* wpe    = (const float*)d_in[2];
  const float* ln1_w  = (const float*)d_in[3];
  const float* ln1_b  = (const float*)d_in[4];
  const float* qkv_w  = (const float*)d_in[5];
  const float* qkv_b  = (const float*)d_in[6];
  const float* proj_w = (const float*)d_in[7];
  const float* proj_b = (const float*)d_in[8];
  const float* ln2_w  = (const float*)d_in[9];
  const float* ln2_b  = (const float*)d_in[10];
  const float* fc_w   = (const float*)d_in[11];
  const float* fc_b   = (const float*)d_in[12];
  const float* fc2_w  = (const float*)d_in[13];
  const float* fc2_b  = (const float*)d_in[14];
  const float* lnf_w  = (const float*)d_in[15];
  const float* lnf_b  = (const float*)d_in[16];
  const float* head_w = (const float*)d_in[17];
  (void)in_sizes; (void)n_in; (void)out_size; (void)ws_size;

  char* base = (char*)d_ws;
  size_t off = 0;
  auto alloc = [&](size_t bytes) -> void* {
    void* p = base + off;
    off = (off + bytes + 255) & ~(size_t)255;
    return p;
  };
  bf16* wt_qkv  = (bf16*)alloc((size_t)NL * 3 * C * C * 2);
  bf16* wt_proj = (bf16*)alloc((size_t)NL * C * C * 2);
  bf16* wt_fc   = (bf16*)alloc((size_t)NL * 4 * C * C * 2);
  bf16* wt_fc2  = (bf16*)alloc((size_t)NL * 4 * C * C * 2);
  bf16* wt_head = (bf16*)alloc((size_t)V * C * 2);
  float* x      = (float*)alloc((size_t)BTOK * C * 4);   // absorbs head OOB reads
  bf16*  xb     = (bf16*)alloc((size_t)BTOK * C * 2);
  bf16*  qb     = (bf16*)alloc((size_t)NB * NH * T * DH * 2);
  bf16*  kb     = (bf16*)alloc((size_t)NB * NH * T * DH * 2);
  bf16*  vtb    = (bf16*)alloc((size_t)NB * NH * T * DH * 2);
  bf16*  yb     = (bf16*)alloc((size_t)BTOK * C * 2);
  bf16*  mbuf   = (bf16*)alloc((size_t)BTOK * 4 * C * 2);

  dim3 tb(32, 8);
  k_transpose_bf16<<<dim3(72, 24, NL), tb, 0, stream>>>(qkv_w, wt_qkv, C, 3 * C);
  k_transpose_bf16<<<dim3(24, 24, NL), tb, 0, stream>>>(proj_w, wt_proj, C, C);
  k_transpose_bf16<<<dim3(96, 24, NL), tb, 0, stream>>>(fc_w, wt_fc, C, 4 * C);
  k_transpose_bf16<<<dim3(24, 96, NL), tb, 0, stream>>>(fc2_w, wt_fc2, 4 * C, C);
  k_transpose_bf16<<<dim3((V + 31) / 32, 24, 1), tb, 0, stream>>>(head_w, wt_head, C, V);

  k_embed<<<BTOK * C / 256, 256, 0, stream>>>(idx, wte, wpe, x);

  for (int l = 0; l < NL; l++) {
    k_layernorm<<<BTOK, 256, 0, stream>>>(x, ln1_w + l * C, ln1_b + l * C, xb);
    k_gemm<5, true><<<dim3(16, 18), 256, 0, stream>>>(xb, wt_qkv + (long)l * 3 * C * C,
        qkv_b + l * 3 * C, qb, BTOK, 3 * C, C, C, C, 0, kb, vtb);
    k_attn<<<dim3(T / 64, NB * NH), 256, 0, stream>>>(qb, kb, vtb, yb);
    k_gemm_s<<<dim3(32, 6), 256, 0, stream>>>(yb, wt_proj + (long)l * C * C,
        proj_b + l * C, x, BTOK, C, C, C, C, C);
    k_layernorm<<<BTOK, 256, 0, stream>>>(x, ln2_w + l * C, ln2_b + l * C, xb);
    k_gemm<2, true><<<dim3(16, 24), 256, 0, stream>>>(xb, wt_fc + (long)l * 4 * C * C,
        fc_b + l * 4 * C, mbuf, BTOK, 4 * C, C, C, C, 4 * C, nullptr, nullptr);
    k_gemm_s<<<dim3(32, 6), 256, 0, stream>>>(mbuf, wt_fc2 + (long)l * 4 * C * C,
        fc2_b + l * C, x, BTOK, C, 4 * C, 4 * C, 4 * C, C);
  }
  k_layernorm<<<BTOK, 256, 0, stream>>>(x, lnf_w, lnf_b, xb);
  k_gemm<0, true><<<dim3(16, (V + 127) / 128), 256, 0, stream>>>(xb, wt_head, nullptr,
      (float*)d_out, BTOK, V, C, C, C, V, nullptr, nullptr);
}

// Round 6
// 1191.507 us; speedup vs baseline: 1.4907x; 1.0108x over previous
//
#include <hip/hip_runtime.h>
#include <hip/hip_bf16.h>

typedef __hip_bfloat16 bf16;
typedef __attribute__((ext_vector_type(8))) short bf16x8;
typedef __attribute__((ext_vector_type(4))) float f32x4;
typedef __attribute__((ext_vector_type(4), aligned(4))) float f32x4u;  // unaligned-safe

#define NL 4
#define NH 12
#define C 768
#define T 1024
#define NB 2
#define BTOK 2048
#define V 50257
#define DH 64

__device__ __forceinline__ void gload16(const void* g, void* l) {
  __builtin_amdgcn_global_load_lds(
      (const __attribute__((address_space(1))) void*)g,
      (__attribute__((address_space(3))) void*)l, 16, 0, 0);
}

// ---------------- block reductions (256 threads = 4 waves) ----------------
__device__ __forceinline__ float block_sum(float v, float* red) {
#pragma unroll
  for (int off = 32; off; off >>= 1) v += __shfl_down(v, off);
  int lane = threadIdx.x & 63, wid = threadIdx.x >> 6;
  __syncthreads();
  if (lane == 0) red[wid] = v;
  __syncthreads();
  return red[0] + red[1] + red[2] + red[3];
}

// ---------------- embedding ----------------
__global__ __launch_bounds__(256) void k_embed(const int* __restrict__ idx,
    const float* __restrict__ wte, const float* __restrict__ wpe,
    float* __restrict__ x) {
  long i = (long)blockIdx.x * 256 + threadIdx.x;  // over BTOK*C (exact)
  int bt = (int)(i / C), c = (int)(i % C);
  int t = bt & (T - 1);
  x[i] = wte[(long)idx[bt] * C + c] + wpe[(long)t * C + c];
}

// ---------------- fp32 -> bf16 transposed weight convert ----------------
__global__ __launch_bounds__(256) void k_transpose_bf16(const float* __restrict__ W,
    bf16* __restrict__ Wt, int K, int N) {
  __shared__ float tile[32][33];
  long zoff = (long)blockIdx.z * K * N;
  W += zoff;
  Wt += zoff;
  int n0 = blockIdx.x * 32, k0 = blockIdx.y * 32;
  int tx = threadIdx.x, ty = threadIdx.y;
#pragma unroll
  for (int i = 0; i < 4; i++) {
    int k = k0 + ty + i * 8, n = n0 + tx;
    if (k < K && n < N) tile[ty + i * 8][tx] = W[(long)k * N + n];
  }
  __syncthreads();
#pragma unroll
  for (int i = 0; i < 4; i++) {
    int n = n0 + ty + i * 8, k = k0 + tx;
    if (n < N && k < K) Wt[(long)n * K + k] = __float2bfloat16(tile[tx][ty + i * 8]);
  }
}

// ---------------- layernorm: fp32 in -> bf16 out ----------------
__global__ __launch_bounds__(256) void k_layernorm(const float* __restrict__ x,
    const float* __restrict__ w, const float* __restrict__ b, bf16* __restrict__ out) {
  __shared__ float red[4];
  long row = blockIdx.x;
  const float* xr = x + row * C;
  int t = threadIdx.x;
  float v0 = xr[t], v1 = xr[t + 256], v2 = xr[t + 512];
  float s = block_sum(v0 + v1 + v2, red);
  float mu = s * (1.0f / C);
  float d0 = v0 - mu, d1 = v1 - mu, d2 = v2 - mu;
  float vs = block_sum(d0 * d0 + d1 * d1 + d2 * d2, red);
  float inv = rsqrtf(vs * (1.0f / C) + 1e-5f);
  bf16* orow = out + row * C;
  orow[t]       = __float2bfloat16(d0 * inv * w[t]       + b[t]);
  orow[t + 256] = __float2bfloat16(d1 * inv * w[t + 256] + b[t + 256]);
  orow[t + 512] = __float2bfloat16(d2 * inv * w[t + 512] + b[t + 512]);
}

// ---------------- fused causal flash attention ----------------
__global__ __launch_bounds__(256) void k_attn(const bf16* __restrict__ q,
    const bf16* __restrict__ k, const bf16* __restrict__ vt,
    bf16* __restrict__ yb) {
  __shared__ __align__(16) bf16 Pl[4][16][72];  // per-wave P tile, +8 pad
  int qt = blockIdx.x, bh = blockIdx.y;
  int b = bh / NH, h = bh % NH;
  int tid = threadIdx.x, w = tid >> 6, lane = tid & 63;
  int l15 = lane & 15, hi = lane >> 4;
  const bf16* qbase = q + (long)bh * T * DH;
  const bf16* kbase = k + (long)bh * T * DH;
  const bf16* vbase = vt + (long)bh * DH * T;

  int qrow = qt * 64 + w * 16 + l15;  // softmax-layout q (col of S^T)
  bf16x8 qf0 = *(const bf16x8*)(qbase + (long)qrow * DH + hi * 8);
  bf16x8 qf1 = *(const bf16x8*)(qbase + (long)qrow * DH + 32 + hi * 8);

  f32x4 accy[4] = {};               // y: row q=hi*4+rr, col d=j*16+l15
  float m_run = -1e30f, l_run = 0.f;

  int nkt = qt + 1;
  for (int kt = 0; kt < nkt; kt++) {
    int kv0 = kt * 64;
    f32x4 accs[4] = {};
#pragma unroll
    for (int kvi = 0; kvi < 4; kvi++) {
      const bf16* kr = kbase + (long)(kv0 + kvi * 16 + l15) * DH + hi * 8;
      bf16x8 kf0 = *(const bf16x8*)kr;
      bf16x8 kf1 = *(const bf16x8*)(kr + 32);
      accs[kvi] = __builtin_amdgcn_mfma_f32_16x16x32_bf16(kf0, qf0, accs[kvi], 0, 0, 0);
      accs[kvi] = __builtin_amdgcn_mfma_f32_16x16x32_bf16(kf1, qf1, accs[kvi], 0, 0, 0);
    }
    bool diag = (kt == qt);
    float p[4][4];
    float tmax = -1e30f;
#pragma unroll
    for (int kvi = 0; kvi < 4; kvi++)
#pragma unroll
      for (int rr = 0; rr < 4; rr++) {
        float s = accs[kvi][rr];
        if (diag && (kvi * 16 + hi * 4 + rr > w * 16 + l15)) s = -1e30f;
        p[kvi][rr] = s;
        tmax = fmaxf(tmax, s);
      }
    tmax = fmaxf(tmax, __shfl_xor(tmax, 16));
    tmax = fmaxf(tmax, __shfl_xor(tmax, 32));
    float m_new = fmaxf(m_run, tmax);
    float scl = __expf(m_run - m_new);
    float psum = 0.f;
#pragma unroll
    for (int kvi = 0; kvi < 4; kvi++)
#pragma unroll
      for (int rr = 0; rr < 4; rr++) {
        float e = __expf(p[kvi][rr] - m_new);
        p[kvi][rr] = e;
        psum += e;
      }
    psum += __shfl_xor(psum, 16);
    psum += __shfl_xor(psum, 32);
    l_run = l_run * scl + psum;
    m_run = m_new;
#pragma unroll
    for (int rr = 0; rr < 4; rr++) {
      float sy = __shfl(scl, hi * 4 + rr);
#pragma unroll
      for (int j = 0; j < 4; j++) accy[j][rr] *= sy;
    }
#pragma unroll
    for (int kvi = 0; kvi < 4; kvi++) {
      union { bf16 hh[2]; unsigned u; } pk0, pk1;
      pk0.hh[0] = __float2bfloat16(p[kvi][0]);
      pk0.hh[1] = __float2bfloat16(p[kvi][1]);
      pk1.hh[0] = __float2bfloat16(p[kvi][2]);
      pk1.hh[1] = __float2bfloat16(p[kvi][3]);
      *(unsigned*)&Pl[w][l15][kvi * 16 + hi * 4]     = pk0.u;
      *(unsigned*)&Pl[w][l15][kvi * 16 + hi * 4 + 2] = pk1.u;
    }
#pragma unroll
    for (int c = 0; c < 2; c++) {
      bf16x8 pf = *(const bf16x8*)&Pl[w][l15][c * 32 + hi * 8];
#pragma unroll
      for (int j = 0; j < 4; j++) {
        const bf16* vr = vbase + (long)(j * 16 + l15) * T + kv0 + c * 32 + hi * 8;
        bf16x8 vf = *(const bf16x8*)vr;
        accy[j] = __builtin_amdgcn_mfma_f32_16x16x32_bf16(pf, vf, accy[j], 0, 0, 0);
      }
    }
  }
  float inv = 1.0f / l_run;
#pragma unroll
  for (int rr = 0; rr < 4; rr++) {
    float li = __shfl(inv, hi * 4 + rr);
    int qg = qt * 64 + w * 16 + hi * 4 + rr;
#pragma unroll
    for (int j = 0; j < 4; j++)
      yb[((long)(b * T + qg)) * C + h * DH + j * 16 + l15] =
          __float2bfloat16(accy[j][rr] * li);
  }
}

// ================= 8-phase 256x256 head GEMM (M=2048,N=V,K=768) ============
// 512 thr = 8 waves (2M x 4N); per-wave 128x64 out; BK=64, 12 K-tiles.
// LDS 128 KiB: 2 bufs x {A0,A1,B0,B1} halves of 16 KiB ([128][64] bf16).
// Swizzle: LDS[row][g16] holds global granule g16^(row&7), both sides.
// 4 phases/K-tile (kk-split); counted vmcnt(2) once per tile, never 0 mid-loop.
__global__ __launch_bounds__(512, 1) void k_head(const bf16* __restrict__ A,
    const bf16* __restrict__ B, float* __restrict__ Cv) {
  __shared__ __align__(16) char lds[131072];
  int hw = blockIdx.y * 8 + blockIdx.x;          // grid (8, 197), nwg=1576
  int L = (hw & 7) * 197 + (hw >> 3);            // bijective XCD chunk
  int mt = L & 7, nt = L >> 3;
  int m0 = mt * 256, n0 = nt * 256;
  int tid = threadIdx.x, lane = tid & 63, wid = tid >> 6;
  int wm = wid >> 2, wn = wid & 3;
  int l15 = lane & 15, hi = lane >> 4, l7 = lane & 7;
  int sg = (lane & 7) ^ (lane >> 3);             // pre-swizzled src granule
  int srA = wid * 8 + (lane >> 3);               // staging row (of 64/issue-round)
  const bf16* Ab = A + (long)(m0 + srA) * 768 + sg * 8;
  const bf16* Bb = B + (long)(n0 + srA) * 768 + sg * 8;  // OOB tail lands in ws
  auto STAGE = [&](int tile, int h) {            // h: 0=A0 1=A1 2=B0 3=B1
    char* dst = lds + (tile & 1) * 65536 + h * 16384 + wid * 1024;
    const bf16* src = (h < 2 ? Ab : Bb) + (long)((h & 1) * 128) * 768 + tile * 64;
    gload16(src, dst);
    gload16(src + 64 * 768, dst + 8192);
  };
  f32x4 acc[8][4] = {};
  STAGE(0, 0); STAGE(0, 1); STAGE(0, 2); STAGE(0, 3); STAGE(1, 0);
  asm volatile("s_waitcnt vmcnt(2)" ::: "memory");   // tile0 landed; A0(1) in flight
  __builtin_amdgcn_s_barrier();
  int bro = (wn & 1) * 64;
  int g0 = (hi ^ l7) * 16, g1 = ((4 + hi) ^ l7) * 16;  // kk0/kk1 swizzled bytes
  for (int t = 0; t < 12; t++) {
    char* ha = lds + (t & 1) * 65536 + wm * 16384;
    char* hb = lds + (t & 1) * 65536 + 32768 + (wn >> 1) * 16384;
    bf16x8 af[4], bv[4];
    // ---- ph0: A mf0-3 kk0 + B nf0-3 kk0 ; stage (t+1).A1,(t+1).B0
#pragma unroll
    for (int mf = 0; mf < 4; mf++)
      af[mf] = *(const bf16x8*)(ha + (mf * 16 + l15) * 128 + g0);
#pragma unroll
    for (int nf = 0; nf < 4; nf++)
      bv[nf] = *(const bf16x8*)(hb + (bro + nf * 16 + l15) * 128 + g0);
    if (t + 1 < 12) { STAGE(t + 1, 1); STAGE(t + 1, 2); }
    __builtin_amdgcn_s_barrier();
    __builtin_amdgcn_s_setprio(1);
#pragma unroll
    for (int mf = 0; mf < 4; mf++)
#pragma unroll
      for (int nf = 0; nf < 4; nf++)
        acc[mf][nf] = __builtin_amdgcn_mfma_f32_16x16x32_bf16(af[mf], bv[nf], acc[mf][nf], 0, 0, 0);
    __builtin_amdgcn_s_setprio(0);
    __builtin_amdgcn_s_barrier();
    // ---- ph1: A mf4-7 kk0 ; stage (t+1).B1
#pragma unroll
    for (int mf = 0; mf < 4; mf++)
      af[mf] = *(const bf16x8*)(ha + ((mf + 4) * 16 + l15) * 128 + g0);
    if (t + 1 < 12) STAGE(t + 1, 3);
    __builtin_amdgcn_s_barrier();
    __builtin_amdgcn_s_setprio(1);
#pragma unroll
    for (int mf = 0; mf < 4; mf++)
#pragma unroll
      for (int nf = 0; nf < 4; nf++)
        acc[mf + 4][nf] = __builtin_amdgcn_mfma_f32_16x16x32_bf16(af[mf], bv[nf], acc[mf + 4][nf], 0, 0, 0);
    __builtin_amdgcn_s_setprio(0);
    __builtin_amdgcn_s_barrier();
    // ---- ph2: A mf0-3 kk1 + B nf0-3 kk1
#pragma unroll
    for (int mf = 0; mf < 4; mf++)
      af[mf] = *(const bf16x8*)(ha + (mf * 16 + l15) * 128 + g1);
#pragma unroll
    for (int nf = 0; nf < 4; nf++)
      bv[nf] = *(const bf16x8*)(hb + (bro + nf * 16 + l15) * 128 + g1);
    __builtin_amdgcn_s_barrier();
    __builtin_amdgcn_s_setprio(1);
#pragma unroll
    for (int mf = 0; mf < 4; mf++)
#pragma unroll
      for (int nf = 0; nf < 4; nf++)
        acc[mf][nf] = __builtin_amdgcn_mfma_f32_16x16x32_bf16(af[mf], bv[nf], acc[mf][nf], 0, 0, 0);
    __builtin_amdgcn_s_setprio(0);
    __builtin_amdgcn_s_barrier();
    // ---- ph3: A mf4-7 kk1 ; stage (t+2).A0 ; counted vmcnt
#pragma unroll
    for (int mf = 0; mf < 4; mf++)
      af[mf] = *(const bf16x8*)(ha + ((mf + 4) * 16 + l15) * 128 + g1);
    if (t + 2 < 12) STAGE(t + 2, 0);
    __builtin_amdgcn_s_barrier();
    __builtin_amdgcn_s_setprio(1);
#pragma unroll
    for (int mf = 0; mf < 4; mf++)
#pragma unroll
      for (int nf = 0; nf < 4; nf++)
        acc[mf + 4][nf] = __builtin_amdgcn_mfma_f32_16x16x32_bf16(af[mf], bv[nf], acc[mf + 4][nf], 0, 0, 0);
    __builtin_amdgcn_s_setprio(0);
    if (t < 11) {
      if (t + 2 < 12) asm volatile("s_waitcnt vmcnt(2)" ::: "memory");
      else            asm volatile("s_waitcnt vmcnt(0)" ::: "memory");
      __builtin_amdgcn_s_barrier();
    }
  }
  // ---- epilogue: LDS-staged full-line fp32 stores ----
  __syncthreads();
  float* Cst = (float*)lds;  // [32][260] f32 = 33.3 KB
#pragma unroll
  for (int mf = 0; mf < 8; mf++) {
#pragma unroll
    for (int nf = 0; nf < 4; nf++)
#pragma unroll
      for (int rr = 0; rr < 4; rr++)
        Cst[(wm * 16 + hi * 4 + rr) * 260 + wn * 64 + nf * 16 + l15] = acc[mf][nf][rr];
    __syncthreads();
#pragma unroll
    for (int s = 0; s < 4; s++) {
      int gid = tid + s * 512;
      int r = gid >> 6, g = gid & 63;
      int grow = m0 + (r >> 4) * 128 + mf * 16 + (r & 15);
      int gcol = n0 + g * 4;
      f32x4 vv = *(const f32x4*)&Cst[r * 260 + g * 4];
      float* dst = Cv + (long)grow * V + gcol;
      if (gcol + 3 < V) {
        *(f32x4u*)dst = vv;
      } else {
#pragma unroll
        for (int e = 0; e < 4; e++)
          if (gcol + e < V) dst[e] = vv[e];
      }
    }
    __syncthreads();
  }
}

// ---------------- NT GEMM: depth-2 pipelined, counted vmcnt, BK=32 ----------
// EPI 2: bf16 out, gelu(acc+bias)
// EPI 5: qkv split-repack: Cv=q (scaled 0.125), Cv2=k, Cv3=vt
#define BK 32

template <int EPI, bool SWAPXY>
__global__ __launch_bounds__(256) void k_gemm(const bf16* __restrict__ A,
    const bf16* __restrict__ B, const float* __restrict__ bias,
    void* __restrict__ Cv, int M, int N, int K, int lda, int ldb, int ldc,
    void* __restrict__ Cv2, void* __restrict__ Cv3) {
  __shared__ __align__(16) bf16 As[2][128][BK];
  __shared__ __align__(16) bf16 Bs[2][128][BK];
  int nwg = gridDim.x * gridDim.y;
  int hw = blockIdx.y * gridDim.x + blockIdx.x;
  int logical = (hw & 7) * (nwg >> 3) + (hw >> 3);
  int bx = logical % gridDim.x, by = logical / gridDim.x;
  int m0 = (SWAPXY ? bx : by) * 128;
  int n0 = (SWAPXY ? by : bx) * 128;
  int tid = threadIdx.x;
  int lane = tid & 63, wid = tid >> 6;
  int wr = wid >> 1, wc = wid & 1;
  int l15 = lane & 15, hi = lane >> 4;
  int srow = lane >> 2;
  int scol = (((lane & 3) ^ ((lane >> 3) & 3)) << 3);
  f32x4 acc[4][4] = {};
  const bf16* Ag = A + (long)(m0 + wid * 32 + srow) * lda + scol;
  const bf16* Bg = B + (long)(n0 + wid * 32 + srow) * ldb + scol;
  int NT = K / BK;
  auto STAGE = [&](int t) {
    int k0 = t * BK, b = t & 1;
    gload16(Ag + k0,            &As[b][wid * 32][0]);
    gload16(Ag + k0 + 16 * lda, &As[b][wid * 32 + 16][0]);
    gload16(Bg + k0,            &Bs[b][wid * 32][0]);
    gload16(Bg + k0 + 16 * ldb, &Bs[b][wid * 32 + 16][0]);
  };
  STAGE(0);
  STAGE(1);
  int cA = (hi ^ ((l15 >> 1) & 3)) << 3;
  for (int t = 0; t < NT; t++) {
    int b = t & 1;
    if (t + 1 < NT) asm volatile("s_waitcnt vmcnt(4)" ::: "memory");
    else            asm volatile("s_waitcnt vmcnt(0)" ::: "memory");
    __builtin_amdgcn_s_barrier();
    bf16x8 af[4], bfr[4];
#pragma unroll
    for (int i = 0; i < 4; i++)
      af[i] = *(const bf16x8*)&As[b][wr * 64 + i * 16 + l15][cA];
#pragma unroll
    for (int j = 0; j < 4; j++)
      bfr[j] = *(const bf16x8*)&Bs[b][wc * 64 + j * 16 + l15][cA];
    asm volatile("s_waitcnt lgkmcnt(0)" ::: "memory");
    __builtin_amdgcn_s_barrier();
    if (t + 2 < NT) STAGE(t + 2);
#pragma unroll
    for (int i = 0; i < 4; i++)
#pragma unroll
      for (int j = 0; j < 4; j++)
        acc[i][j] = __builtin_amdgcn_mfma_f32_16x16x32_bf16(af[i], bfr[j], acc[i][j], 0, 0, 0);
  }
#pragma unroll
  for (int j = 0; j < 4; j++) {
    int gn = n0 + wc * 64 + j * 16 + l15;
    if (gn >= N) continue;
    float bv = (bias != nullptr) ? bias[gn] : 0.0f;
#pragma unroll
    for (int i = 0; i < 4; i++) {
#pragma unroll
      for (int rr = 0; rr < 4; rr++) {
        int gm = m0 + wr * 64 + i * 16 + hi * 4 + rr;
        float v = acc[i][j][rr] + bv;
        if constexpr (EPI == 2) {
          float u = 0.7978845608028654f * (v + 0.044715f * v * v * v);
          u = fminf(fmaxf(u, -15.f), 15.f);
          float e2 = __expf(2.f * u);
          float th = (e2 - 1.f) / (e2 + 1.f);
          ((bf16*)Cv)[(long)gm * ldc + gn] = __float2bfloat16(0.5f * v * (1.f + th));
        } else if constexpr (EPI == 5) {
          int gb = gm >> 10, gt = gm & 1023;
          int which = gn / C;
          int r = gn - which * C;
          int h = r >> 6, d = r & 63;
          long bh = (long)(gb * NH + h);
          if (which == 0)
            ((bf16*)Cv)[(bh * T + gt) * DH + d] = __float2bfloat16(v * 0.125f);
          else if (which == 1)
            ((bf16*)Cv2)[(bh * T + gt) * DH + d] = __float2bfloat16(v);
          else
            ((bf16*)Cv3)[(bh * DH + d) * T + gt] = __float2bfloat16(v);
        }
      }
    }
  }
}

// ---------------- small-N GEMM: BM=64, BN=128, depth-2 pipeline, residual ---
__global__ __launch_bounds__(256) void k_gemm_s(const bf16* __restrict__ A,
    const bf16* __restrict__ B, const float* __restrict__ bias,
    float* __restrict__ Cx, int M, int N, int K, int lda, int ldb, int ldc) {
  __shared__ __align__(16) bf16 As[2][64][BK];
  __shared__ __align__(16) bf16 Bs[2][128][BK];
  int m0 = blockIdx.x * 64, n0 = blockIdx.y * 128;
  int tid = threadIdx.x;
  int lane = tid & 63, w = tid >> 6;
  int l15 = lane & 15, hi = lane >> 4;
  int srow = lane >> 2;
  int scol = (((lane & 3) ^ ((lane >> 3) & 3)) << 3);
  f32x4 acc[4][2] = {};
  const bf16* Ag = A + (long)(m0 + w * 16 + srow) * lda + scol;
  const bf16* Bg = B + (long)(n0 + w * 32 + srow) * ldb + scol;
  int NT = K / BK;
  auto STAGE = [&](int t) {
    int k0 = t * BK, b = t & 1;
    gload16(Ag + k0,            &As[b][w * 16][0]);
    gload16(Bg + k0,            &Bs[b][w * 32][0]);
    gload16(Bg + k0 + 16 * ldb, &Bs[b][w * 32 + 16][0]);
  };
  STAGE(0);
  STAGE(1);
  int cA = (hi ^ ((l15 >> 1) & 3)) << 3;
  for (int t = 0; t < NT; t++) {
    int b = t & 1;
    if (t + 1 < NT) asm volatile("s_waitcnt vmcnt(3)" ::: "memory");
    else            asm volatile("s_waitcnt vmcnt(0)" ::: "memory");
    __builtin_amdgcn_s_barrier();
    bf16x8 af[4], bfr[2];
#pragma unroll
    for (int i = 0; i < 4; i++)
      af[i] = *(const bf16x8*)&As[b][i * 16 + l15][cA];
#pragma unroll
    for (int j = 0; j < 2; j++)
      bfr[j] = *(const bf16x8*)&Bs[b][w * 32 + j * 16 + l15][cA];
    asm volatile("s_waitcnt lgkmcnt(0)" ::: "memory");
    __builtin_amdgcn_s_barrier();
    if (t + 2 < NT) STAGE(t + 2);
#pragma unroll
    for (int i = 0; i < 4; i++)
#pragma unroll
      for (int j = 0; j < 2; j++)
        acc[i][j] = __builtin_amdgcn_mfma_f32_16x16x32_bf16(af[i], bfr[j], acc[i][j], 0, 0, 0);
  }
#pragma unroll
  for (int j = 0; j < 2; j++) {
    int gn = n0 + w * 32 + j * 16 + l15;
    float bv = bias[gn];
#pragma unroll
    for (int i = 0; i < 4; i++)
#pragma unroll
      for (int rr = 0; rr < 4; rr++) {
        int gm = m0 + i * 16 + hi * 4 + rr;
        long off = (long)gm * ldc + gn;
        Cx[off] = acc[i][j][rr] + bv + Cx[off];
      }
  }
}

extern "C" void kernel_launch(void* const* d_in, const int* in_sizes, int n_in,
                              void* d_out, int out_size, void* d_ws, size_t ws_size,
                              hipStream_t stream) {
  const int*   idx    = (const int*)d_in[0];
  const float* wte    = (const float*)d_in[1];
  const float* wpe    = (const float*)d_in[2];
  const float* ln1_w  = (const float*)d_in[3];
  const float* ln1_b  = (const float*)d_in[4];
  const float* qkv_w  = (const float*)d_in[5];
  const float* qkv_b  = (const float*)d_in[6];
  const float* proj_w = (const float*)d_in[7];
  const float* proj_b = (const float*)d_in[8];
  const float* ln2_w  = (const float*)d_in[9];
  const float* ln2_b  = (const float*)d_in[10];
  const float* fc_w   = (const float*)d_in[11];
  const float* fc_b   = (const float*)d_in[12];
  const float* fc2_w  = (const float*)d_in[13];
  const float* fc2_b  = (const float*)d_in[14];
  const float* lnf_w  = (const float*)d_in[15];
  const float* lnf_b  = (const float*)d_in[16];
  const float* head_w = (const float*)d_in[17];
  (void)in_sizes; (void)n_in; (void)out_size; (void)ws_size;

  char* base = (char*)d_ws;
  size_t off = 0;
  auto alloc = [&](size_t bytes) -> void* {
    void* p = base + off;
    off = (off + bytes + 255) & ~(size_t)255;
    return p;
  };
  bf16* wt_qkv  = (bf16*)alloc((size_t)NL * 3 * C * C * 2);
  bf16* wt_proj = (bf16*)alloc((size_t)NL * C * C * 2);
  bf16* wt_fc   = (bf16*)alloc((size_t)NL * 4 * C * C * 2);
  bf16* wt_fc2  = (bf16*)alloc((size_t)NL * 4 * C * C * 2);
  bf16* wt_head = (bf16*)alloc((size_t)V * C * 2);
  float* x      = (float*)alloc((size_t)BTOK * C * 4);   // absorbs head OOB reads
  bf16*  xb     = (bf16*)alloc((size_t)BTOK * C * 2);
  bf16*  qb     = (bf16*)alloc((size_t)NB * NH * T * DH * 2);
  bf16*  kb     = (bf16*)alloc((size_t)NB * NH * T * DH * 2);
  bf16*  vtb    = (bf16*)alloc((size_t)NB * NH * T * DH * 2);
  bf16*  yb     = (bf16*)alloc((size_t)BTOK * C * 2);
  bf16*  mbuf   = (bf16*)alloc((size_t)BTOK * 4 * C * 2);

  dim3 tb(32, 8);
  k_transpose_bf16<<<dim3(72, 24, NL), tb, 0, stream>>>(qkv_w, wt_qkv, C, 3 * C);
  k_transpose_bf16<<<dim3(24, 24, NL), tb, 0, stream>>>(proj_w, wt_proj, C, C);
  k_transpose_bf16<<<dim3(96, 24, NL), tb, 0, stream>>>(fc_w, wt_fc, C, 4 * C);
  k_transpose_bf16<<<dim3(24, 96, NL), tb, 0, stream>>>(fc2_w, wt_fc2, 4 * C, C);
  k_transpose_bf16<<<dim3((V + 31) / 32, 24, 1), tb, 0, stream>>>(head_w, wt_head, C, V);

  k_embed<<<BTOK * C / 256, 256, 0, stream>>>(idx, wte, wpe, x);

  for (int l = 0; l < NL; l++) {
    k_layernorm<<<BTOK, 256, 0, stream>>>(x, ln1_w + l * C, ln1_b + l * C, xb);
    k_gemm<5, true><<<dim3(16, 18), 256, 0, stream>>>(xb, wt_qkv + (long)l * 3 * C * C,
        qkv_b + l * 3 * C, qb, BTOK, 3 * C, C, C, C, 0, kb, vtb);
    k_attn<<<dim3(T / 64, NB * NH), 256, 0, stream>>>(qb, kb, vtb, yb);
    k_gemm_s<<<dim3(32, 6), 256, 0, stream>>>(yb, wt_proj + (long)l * C * C,
        proj_b + l * C, x, BTOK, C, C, C, C, C);
    k_layernorm<<<BTOK, 256, 0, stream>>>(x, ln2_w + l * C, ln2_b + l * C, xb);
    k_gemm<2, true><<<dim3(16, 24), 256, 0, stream>>>(xb, wt_fc + (long)l * 4 * C * C,
        fc_b + l * 4 * C, mbuf, BTOK, 4 * C, C, C, C, 4 * C, nullptr, nullptr);
    k_gemm_s<<<dim3(32, 6), 256, 0, stream>>>(mbuf, wt_fc2 + (long)l * 4 * C * C,
        fc2_b + l * C, x, BTOK, C, 4 * C, 4 * C, 4 * C, C);
  }
  k_layernorm<<<BTOK, 256, 0, stream>>>(x, lnf_w, lnf_b, xb);
  k_head<<<dim3(8, 197), 512, 0, stream>>>(xb, wt_head, (float*)d_out);
}

// Round 7
// 1130.301 us; speedup vs baseline: 1.5714x; 1.0542x over previous
//
#include <hip/hip_runtime.h>
#include <hip/hip_bf16.h>

typedef __hip_bfloat16 bf16;
typedef __attribute__((ext_vector_type(8))) short bf16x8;
typedef __attribute__((ext_vector_type(4))) float f32x4;
typedef __attribute__((ext_vector_type(4), aligned(4))) float f32x4u;  // unaligned-safe

#define NL 4
#define NH 12
#define C 768
#define T 1024
#define NB 2
#define BTOK 2048
#define V 50257
#define DH 64

__device__ __forceinline__ void gload16(const void* g, void* l) {
  __builtin_amdgcn_global_load_lds(
      (const __attribute__((address_space(1))) void*)g,
      (__attribute__((address_space(3))) void*)l, 16, 0, 0);
}

// ---------------- block reductions (256 threads = 4 waves) ----------------
__device__ __forceinline__ float block_sum(float v, float* red) {
#pragma unroll
  for (int off = 32; off; off >>= 1) v += __shfl_down(v, off);
  int lane = threadIdx.x & 63, wid = threadIdx.x >> 6;
  __syncthreads();
  if (lane == 0) red[wid] = v;
  __syncthreads();
  return red[0] + red[1] + red[2] + red[3];
}

// ---------------- embedding ----------------
__global__ __launch_bounds__(256) void k_embed(const int* __restrict__ idx,
    const float* __restrict__ wte, const float* __restrict__ wpe,
    float* __restrict__ x) {
  long i = (long)blockIdx.x * 256 + threadIdx.x;  // over BTOK*C (exact)
  int bt = (int)(i / C), c = (int)(i % C);
  int t = bt & (T - 1);
  x[i] = wte[(long)idx[bt] * C + c] + wpe[(long)t * C + c];
}

// ---------------- fp32 -> bf16 transposed weight convert ----------------
__global__ __launch_bounds__(256) void k_transpose_bf16(const float* __restrict__ W,
    bf16* __restrict__ Wt, int K, int N) {
  __shared__ float tile[32][33];
  long zoff = (long)blockIdx.z * K * N;
  W += zoff;
  Wt += zoff;
  int n0 = blockIdx.x * 32, k0 = blockIdx.y * 32;
  int tx = threadIdx.x, ty = threadIdx.y;
#pragma unroll
  for (int i = 0; i < 4; i++) {
    int k = k0 + ty + i * 8, n = n0 + tx;
    if (k < K && n < N) tile[ty + i * 8][tx] = W[(long)k * N + n];
  }
  __syncthreads();
#pragma unroll
  for (int i = 0; i < 4; i++) {
    int n = n0 + ty + i * 8, k = k0 + tx;
    if (n < N && k < K) Wt[(long)n * K + k] = __float2bfloat16(tile[tx][ty + i * 8]);
  }
}

// ---------------- layernorm: fp32 in -> bf16 out ----------------
__global__ __launch_bounds__(256) void k_layernorm(const float* __restrict__ x,
    const float* __restrict__ w, const float* __restrict__ b, bf16* __restrict__ out) {
  __shared__ float red[4];
  long row = blockIdx.x;
  const float* xr = x + row * C;
  int t = threadIdx.x;
  float v0 = xr[t], v1 = xr[t + 256], v2 = xr[t + 512];
  float s = block_sum(v0 + v1 + v2, red);
  float mu = s * (1.0f / C);
  float d0 = v0 - mu, d1 = v1 - mu, d2 = v2 - mu;
  float vs = block_sum(d0 * d0 + d1 * d1 + d2 * d2, red);
  float inv = rsqrtf(vs * (1.0f / C) + 1e-5f);
  bf16* orow = out + row * C;
  orow[t]       = __float2bfloat16(d0 * inv * w[t]       + b[t]);
  orow[t + 256] = __float2bfloat16(d1 * inv * w[t + 256] + b[t + 256]);
  orow[t + 512] = __float2bfloat16(d2 * inv * w[t + 512] + b[t + 512]);
}

// ---------------- fused causal flash attention (balanced pairs) ----------
// grid (T/128, NB*NH): block p handles q-tiles {p, 15-p} -> 17 KV-iters/block
__global__ __launch_bounds__(256) void k_attn(const bf16* __restrict__ q,
    const bf16* __restrict__ k, const bf16* __restrict__ vt,
    bf16* __restrict__ yb) {
  __shared__ __align__(16) bf16 Pl[4][16][72];  // per-wave P tile, +8 pad
  int pr = blockIdx.x, bh = blockIdx.y;
  int b = bh / NH, h = bh % NH;
  int tid = threadIdx.x, w = tid >> 6, lane = tid & 63;
  int l15 = lane & 15, hi = lane >> 4;
  const bf16* qbase = q + (long)bh * T * DH;
  const bf16* kbase = k + (long)bh * T * DH;
  const bf16* vbase = vt + (long)bh * DH * T;

  for (int s2 = 0; s2 < 2; s2++) {
    int qt = s2 ? (T / 64 - 1 - pr) : pr;
    int qrow = qt * 64 + w * 16 + l15;  // softmax-layout q (col of S^T)
    bf16x8 qf0 = *(const bf16x8*)(qbase + (long)qrow * DH + hi * 8);
    bf16x8 qf1 = *(const bf16x8*)(qbase + (long)qrow * DH + 32 + hi * 8);

    f32x4 accy[4] = {};               // y: row q=hi*4+rr, col d=j*16+l15
    float m_run = -1e30f, l_run = 0.f;

    int nkt = qt + 1;
    for (int kt = 0; kt < nkt; kt++) {
      int kv0 = kt * 64;
      f32x4 accs[4] = {};
#pragma unroll
      for (int kvi = 0; kvi < 4; kvi++) {
        const bf16* kr = kbase + (long)(kv0 + kvi * 16 + l15) * DH + hi * 8;
        bf16x8 kf0 = *(const bf16x8*)kr;
        bf16x8 kf1 = *(const bf16x8*)(kr + 32);
        accs[kvi] = __builtin_amdgcn_mfma_f32_16x16x32_bf16(kf0, qf0, accs[kvi], 0, 0, 0);
        accs[kvi] = __builtin_amdgcn_mfma_f32_16x16x32_bf16(kf1, qf1, accs[kvi], 0, 0, 0);
      }
      bool diag = (kt == qt);
      float p[4][4];
      float tmax = -1e30f;
#pragma unroll
      for (int kvi = 0; kvi < 4; kvi++)
#pragma unroll
        for (int rr = 0; rr < 4; rr++) {
          float s = accs[kvi][rr];
          if (diag && (kvi * 16 + hi * 4 + rr > w * 16 + l15)) s = -1e30f;
          p[kvi][rr] = s;
          tmax = fmaxf(tmax, s);
        }
      tmax = fmaxf(tmax, __shfl_xor(tmax, 16));
      tmax = fmaxf(tmax, __shfl_xor(tmax, 32));
      float m_new = fmaxf(m_run, tmax);
      float scl = __expf(m_run - m_new);
      float psum = 0.f;
#pragma unroll
      for (int kvi = 0; kvi < 4; kvi++)
#pragma unroll
        for (int rr = 0; rr < 4; rr++) {
          float e = __expf(p[kvi][rr] - m_new);
          p[kvi][rr] = e;
          psum += e;
        }
      psum += __shfl_xor(psum, 16);
      psum += __shfl_xor(psum, 32);
      l_run = l_run * scl + psum;
      m_run = m_new;
#pragma unroll
      for (int rr = 0; rr < 4; rr++) {
        float sy = __shfl(scl, hi * 4 + rr);
#pragma unroll
        for (int j = 0; j < 4; j++) accy[j][rr] *= sy;
      }
#pragma unroll
      for (int kvi = 0; kvi < 4; kvi++) {
        union { bf16 hh[2]; unsigned u; } pk0, pk1;
        pk0.hh[0] = __float2bfloat16(p[kvi][0]);
        pk0.hh[1] = __float2bfloat16(p[kvi][1]);
        pk1.hh[0] = __float2bfloat16(p[kvi][2]);
        pk1.hh[1] = __float2bfloat16(p[kvi][3]);
        *(unsigned*)&Pl[w][l15][kvi * 16 + hi * 4]     = pk0.u;
        *(unsigned*)&Pl[w][l15][kvi * 16 + hi * 4 + 2] = pk1.u;
      }
#pragma unroll
      for (int c = 0; c < 2; c++) {
        bf16x8 pf = *(const bf16x8*)&Pl[w][l15][c * 32 + hi * 8];
#pragma unroll
        for (int j = 0; j < 4; j++) {
          const bf16* vr = vbase + (long)(j * 16 + l15) * T + kv0 + c * 32 + hi * 8;
          bf16x8 vf = *(const bf16x8*)vr;
          accy[j] = __builtin_amdgcn_mfma_f32_16x16x32_bf16(pf, vf, accy[j], 0, 0, 0);
        }
      }
    }
    float inv = 1.0f / l_run;
#pragma unroll
    for (int rr = 0; rr < 4; rr++) {
      float li = __shfl(inv, hi * 4 + rr);
      int qg = qt * 64 + w * 16 + hi * 4 + rr;
#pragma unroll
      for (int j = 0; j < 4; j++)
        yb[((long)(b * T + qg)) * C + h * DH + j * 16 + l15] =
            __float2bfloat16(accy[j][rr] * li);
    }
  }
}

// ================= 8-phase 256x256 head GEMM (M=2048,N=V,K=768) ============
__global__ __launch_bounds__(512, 1) void k_head(const bf16* __restrict__ A,
    const bf16* __restrict__ B, float* __restrict__ Cv) {
  __shared__ __align__(16) char lds[131072];
  int hw = blockIdx.y * 8 + blockIdx.x;          // grid (8, 197), nwg=1576
  int L = (hw & 7) * 197 + (hw >> 3);            // bijective XCD chunk
  int mt = L & 7, nt = L >> 3;
  int m0 = mt * 256, n0 = nt * 256;
  int tid = threadIdx.x, lane = tid & 63, wid = tid >> 6;
  int wm = wid >> 2, wn = wid & 3;
  int l15 = lane & 15, hi = lane >> 4, l7 = lane & 7;
  int sg = (lane & 7) ^ (lane >> 3);             // pre-swizzled src granule
  int srA = wid * 8 + (lane >> 3);               // staging row
  const bf16* Ab = A + (long)(m0 + srA) * 768 + sg * 8;
  const bf16* Bb = B + (long)(n0 + srA) * 768 + sg * 8;  // OOB tail lands in ws
  auto STAGE = [&](int tile, int h) {            // h: 0=A0 1=A1 2=B0 3=B1
    char* dst = lds + (tile & 1) * 65536 + h * 16384 + wid * 1024;
    const bf16* src = (h < 2 ? Ab : Bb) + (long)((h & 1) * 128) * 768 + tile * 64;
    gload16(src, dst);
    gload16(src + 64 * 768, dst + 8192);
  };
  f32x4 acc[8][4] = {};
  STAGE(0, 0); STAGE(0, 1); STAGE(0, 2); STAGE(0, 3); STAGE(1, 0);
  asm volatile("s_waitcnt vmcnt(2)" ::: "memory");
  __builtin_amdgcn_s_barrier();
  int bro = (wn & 1) * 64;
  int g0 = (hi ^ l7) * 16, g1 = ((4 + hi) ^ l7) * 16;
  for (int t = 0; t < 12; t++) {
    char* ha = lds + (t & 1) * 65536 + wm * 16384;
    char* hb = lds + (t & 1) * 65536 + 32768 + (wn >> 1) * 16384;
    bf16x8 af[4], bv[4];
#pragma unroll
    for (int mf = 0; mf < 4; mf++)
      af[mf] = *(const bf16x8*)(ha + (mf * 16 + l15) * 128 + g0);
#pragma unroll
    for (int nf = 0; nf < 4; nf++)
      bv[nf] = *(const bf16x8*)(hb + (bro + nf * 16 + l15) * 128 + g0);
    if (t + 1 < 12) { STAGE(t + 1, 1); STAGE(t + 1, 2); }
    __builtin_amdgcn_s_barrier();
    __builtin_amdgcn_s_setprio(1);
#pragma unroll
    for (int mf = 0; mf < 4; mf++)
#pragma unroll
      for (int nf = 0; nf < 4; nf++)
        acc[mf][nf] = __builtin_amdgcn_mfma_f32_16x16x32_bf16(af[mf], bv[nf], acc[mf][nf], 0, 0, 0);
    __builtin_amdgcn_s_setprio(0);
    __builtin_amdgcn_s_barrier();
#pragma unroll
    for (int mf = 0; mf < 4; mf++)
      af[mf] = *(const bf16x8*)(ha + ((mf + 4) * 16 + l15) * 128 + g0);
    if (t + 1 < 12) STAGE(t + 1, 3);
    __builtin_amdgcn_s_barrier();
    __builtin_amdgcn_s_setprio(1);
#pragma unroll
    for (int mf = 0; mf < 4; mf++)
#pragma unroll
      for (int nf = 0; nf < 4; nf++)
        acc[mf + 4][nf] = __builtin_amdgcn_mfma_f32_16x16x32_bf16(af[mf], bv[nf], acc[mf + 4][nf], 0, 0, 0);
    __builtin_amdgcn_s_setprio(0);
    __builtin_amdgcn_s_barrier();
#pragma unroll
    for (int mf = 0; mf < 4; mf++)
      af[mf] = *(const bf16x8*)(ha + (mf * 16 + l15) * 128 + g1);
#pragma unroll
    for (int nf = 0; nf < 4; nf++)
      bv[nf] = *(const bf16x8*)(hb + (bro + nf * 16 + l15) * 128 + g1);
    __builtin_amdgcn_s_barrier();
    __builtin_amdgcn_s_setprio(1);
#pragma unroll
    for (int mf = 0; mf < 4; mf++)
#pragma unroll
      for (int nf = 0; nf < 4; nf++)
        acc[mf][nf] = __builtin_amdgcn_mfma_f32_16x16x32_bf16(af[mf], bv[nf], acc[mf][nf], 0, 0, 0);
    __builtin_amdgcn_s_setprio(0);
    __builtin_amdgcn_s_barrier();
#pragma unroll
    for (int mf = 0; mf < 4; mf++)
      af[mf] = *(const bf16x8*)(ha + ((mf + 4) * 16 + l15) * 128 + g1);
    if (t + 2 < 12) STAGE(t + 2, 0);
    __builtin_amdgcn_s_barrier();
    __builtin_amdgcn_s_setprio(1);
#pragma unroll
    for (int mf = 0; mf < 4; mf++)
#pragma unroll
      for (int nf = 0; nf < 4; nf++)
        acc[mf + 4][nf] = __builtin_amdgcn_mfma_f32_16x16x32_bf16(af[mf], bv[nf], acc[mf + 4][nf], 0, 0, 0);
    __builtin_amdgcn_s_setprio(0);
    if (t < 11) {
      if (t + 2 < 12) asm volatile("s_waitcnt vmcnt(2)" ::: "memory");
      else            asm volatile("s_waitcnt vmcnt(0)" ::: "memory");
      __builtin_amdgcn_s_barrier();
    }
  }
  __syncthreads();
  float* Cst = (float*)lds;  // [32][260] f32
#pragma unroll
  for (int mf = 0; mf < 8; mf++) {
#pragma unroll
    for (int nf = 0; nf < 4; nf++)
#pragma unroll
      for (int rr = 0; rr < 4; rr++)
        Cst[(wm * 16 + hi * 4 + rr) * 260 + wn * 64 + nf * 16 + l15] = acc[mf][nf][rr];
    __syncthreads();
#pragma unroll
    for (int s = 0; s < 4; s++) {
      int gid = tid + s * 512;
      int r = gid >> 6, g = gid & 63;
      int grow = m0 + (r >> 4) * 128 + mf * 16 + (r & 15);
      int gcol = n0 + g * 4;
      f32x4 vv = *(const f32x4*)&Cst[r * 260 + g * 4];
      float* dst = Cv + (long)grow * V + gcol;
      if (gcol + 3 < V) {
        *(f32x4u*)dst = vv;
      } else {
#pragma unroll
        for (int e = 0; e < 4; e++)
          if (gcol + e < V) dst[e] = vv[e];
      }
    }
    __syncthreads();
  }
}

// ---------------- NT GEMM: depth-2 pipelined, counted vmcnt, BK=32 ----------
#define BK 32

template <int EPI, bool SWAPXY>
__global__ __launch_bounds__(256) void k_gemm(const bf16* __restrict__ A,
    const bf16* __restrict__ B, const float* __restrict__ bias,
    void* __restrict__ Cv, int M, int N, int K, int lda, int ldb, int ldc,
    void* __restrict__ Cv2, void* __restrict__ Cv3) {
  __shared__ __align__(16) bf16 As[2][128][BK];
  __shared__ __align__(16) bf16 Bs[2][128][BK];
  int nwg = gridDim.x * gridDim.y;
  int hw = blockIdx.y * gridDim.x + blockIdx.x;
  int logical = (hw & 7) * (nwg >> 3) + (hw >> 3);
  int bx = logical % gridDim.x, by = logical / gridDim.x;
  int m0 = (SWAPXY ? bx : by) * 128;
  int n0 = (SWAPXY ? by : bx) * 128;
  int tid = threadIdx.x;
  int lane = tid & 63, wid = tid >> 6;
  int wr = wid >> 1, wc = wid & 1;
  int l15 = lane & 15, hi = lane >> 4;
  int srow = lane >> 2;
  int scol = (((lane & 3) ^ ((lane >> 3) & 3)) << 3);
  f32x4 acc[4][4] = {};
  const bf16* Ag = A + (long)(m0 + wid * 32 + srow) * lda + scol;
  const bf16* Bg = B + (long)(n0 + wid * 32 + srow) * ldb + scol;
  int NT = K / BK;
  auto STAGE = [&](int t) {
    int k0 = t * BK, b = t & 1;
    gload16(Ag + k0,            &As[b][wid * 32][0]);
    gload16(Ag + k0 + 16 * lda, &As[b][wid * 32 + 16][0]);
    gload16(Bg + k0,            &Bs[b][wid * 32][0]);
    gload16(Bg + k0 + 16 * ldb, &Bs[b][wid * 32 + 16][0]);
  };
  STAGE(0);
  STAGE(1);
  int cA = (hi ^ ((l15 >> 1) & 3)) << 3;
  for (int t = 0; t < NT; t++) {
    int b = t & 1;
    if (t + 1 < NT) asm volatile("s_waitcnt vmcnt(4)" ::: "memory");
    else            asm volatile("s_waitcnt vmcnt(0)" ::: "memory");
    __builtin_amdgcn_s_barrier();
    bf16x8 af[4], bfr[4];
#pragma unroll
    for (int i = 0; i < 4; i++)
      af[i] = *(const bf16x8*)&As[b][wr * 64 + i * 16 + l15][cA];
#pragma unroll
    for (int j = 0; j < 4; j++)
      bfr[j] = *(const bf16x8*)&Bs[b][wc * 64 + j * 16 + l15][cA];
    asm volatile("s_waitcnt lgkmcnt(0)" ::: "memory");
    __builtin_amdgcn_s_barrier();
    if (t + 2 < NT) STAGE(t + 2);
#pragma unroll
    for (int i = 0; i < 4; i++)
#pragma unroll
      for (int j = 0; j < 4; j++)
        acc[i][j] = __builtin_amdgcn_mfma_f32_16x16x32_bf16(af[i], bfr[j], acc[i][j], 0, 0, 0);
  }
#pragma unroll
  for (int j = 0; j < 4; j++) {
    int gn = n0 + wc * 64 + j * 16 + l15;
    if (gn >= N) continue;
    float bv = (bias != nullptr) ? bias[gn] : 0.0f;
#pragma unroll
    for (int i = 0; i < 4; i++) {
#pragma unroll
      for (int rr = 0; rr < 4; rr++) {
        int gm = m0 + wr * 64 + i * 16 + hi * 4 + rr;
        float v = acc[i][j][rr] + bv;
        if constexpr (EPI == 2) {
          float u = 0.7978845608028654f * (v + 0.044715f * v * v * v);
          u = fminf(fmaxf(u, -15.f), 15.f);
          float e2 = __expf(2.f * u);
          float th = (e2 - 1.f) / (e2 + 1.f);
          ((bf16*)Cv)[(long)gm * ldc + gn] = __float2bfloat16(0.5f * v * (1.f + th));
        } else if constexpr (EPI == 5) {
          int gb = gm >> 10, gt = gm & 1023;
          int which = gn / C;
          int r = gn - which * C;
          int h = r >> 6, d = r & 63;
          long bh = (long)(gb * NH + h);
          if (which == 0)
            ((bf16*)Cv)[(bh * T + gt) * DH + d] = __float2bfloat16(v * 0.125f);
          else if (which == 1)
            ((bf16*)Cv2)[(bh * T + gt) * DH + d] = __float2bfloat16(v);
          else
            ((bf16*)Cv3)[(bh * DH + d) * T + gt] = __float2bfloat16(v);
        }
      }
    }
  }
}

// ------- small-N GEMM: BM=64, BN=128, BK=64, depth-2 pipeline, residual -----
// LDS[row][g] holds global granule g^(row&7); write linear, read XOR.
#define SBK 64
__global__ __launch_bounds__(256) void k_gemm_s(const bf16* __restrict__ A,
    const bf16* __restrict__ B, const float* __restrict__ bias,
    float* __restrict__ Cx, int M, int N, int K, int lda, int ldb, int ldc) {
  __shared__ __align__(16) bf16 As[2][64][SBK];   // 16 KiB
  __shared__ __align__(16) bf16 Bs[2][128][SBK];  // 32 KiB
  int m0 = blockIdx.x * 64, n0 = blockIdx.y * 128;
  int tid = threadIdx.x;
  int lane = tid & 63, w = tid >> 6;
  int l15 = lane & 15, hi = lane >> 4, l7 = lane & 7;
  int srow = lane >> 3;                 // 0..7
  int sgr = lane & 7;
  int scol = ((sgr ^ srow) << 3);       // pre-swizzled source col (elements)
  f32x4 acc[4][2] = {};
  const bf16* Ag = A + (long)(m0 + w * 8 + srow) * lda + scol;
  const bf16* Bg = B + (long)(n0 + w * 8 + srow) * ldb + scol;
  int NT = K / SBK;
  auto STAGE = [&](int t) {
    int k0 = t * SBK, b = t & 1;
    gload16(Ag + k0,            &As[b][w * 8][0]);
    gload16(Ag + k0 + 32 * lda, &As[b][w * 8 + 32][0]);
    gload16(Bg + k0,            &Bs[b][w * 8][0]);
    gload16(Bg + k0 + 32 * ldb, &Bs[b][w * 8 + 32][0]);
    gload16(Bg + k0 + 64 * ldb, &Bs[b][w * 8 + 64][0]);
    gload16(Bg + k0 + 96 * ldb, &Bs[b][w * 8 + 96][0]);
  };
  STAGE(0);
  STAGE(1);
  int c0 = (hi ^ l7) << 3, c1 = ((4 + hi) ^ l7) << 3;  // kk0/kk1 read cols
  for (int t = 0; t < NT; t++) {
    int b = t & 1;
    if (t + 1 < NT) asm volatile("s_waitcnt vmcnt(6)" ::: "memory");
    else            asm volatile("s_waitcnt vmcnt(0)" ::: "memory");
    __builtin_amdgcn_s_barrier();
    bf16x8 a0[4], a1[4], b0[2], b1[2];
#pragma unroll
    for (int i = 0; i < 4; i++) {
      a0[i] = *(const bf16x8*)&As[b][i * 16 + l15][c0];
      a1[i] = *(const bf16x8*)&As[b][i * 16 + l15][c1];
    }
#pragma unroll
    for (int j = 0; j < 2; j++) {
      b0[j] = *(const bf16x8*)&Bs[b][w * 32 + j * 16 + l15][c0];
      b1[j] = *(const bf16x8*)&Bs[b][w * 32 + j * 16 + l15][c1];
    }
    asm volatile("s_waitcnt lgkmcnt(0)" ::: "memory");
    __builtin_amdgcn_s_barrier();
    if (t + 2 < NT) STAGE(t + 2);
    __builtin_amdgcn_s_setprio(1);
#pragma unroll
    for (int i = 0; i < 4; i++)
#pragma unroll
      for (int j = 0; j < 2; j++) {
        acc[i][j] = __builtin_amdgcn_mfma_f32_16x16x32_bf16(a0[i], b0[j], acc[i][j], 0, 0, 0);
        acc[i][j] = __builtin_amdgcn_mfma_f32_16x16x32_bf16(a1[i], b1[j], acc[i][j], 0, 0, 0);
      }
    __builtin_amdgcn_s_setprio(0);
  }
#pragma unroll
  for (int j = 0; j < 2; j++) {
    int gn = n0 + w * 32 + j * 16 + l15;
    float bv = bias[gn];
#pragma unroll
    for (int i = 0; i < 4; i++)
#pragma unroll
      for (int rr = 0; rr < 4; rr++) {
        int gm = m0 + i * 16 + hi * 4 + rr;
        long off = (long)gm * ldc + gn;
        Cx[off] = acc[i][j][rr] + bv + Cx[off];
      }
  }
}

extern "C" void kernel_launch(void* const* d_in, const int* in_sizes, int n_in,
                              void* d_out, int out_size, void* d_ws, size_t ws_size,
                              hipStream_t stream) {
  const int*   idx    = (const int*)d_in[0];
  const float* wte    = (const float*)d_in[1];
  const float* wpe    = (const float*)d_in[2];
  const float* ln1_w  = (const float*)d_in[3];
  const float* ln1_b  = (const float*)d_in[4];
  const float* qkv_w  = (const float*)d_in[5];
  const float* qkv_b  = (const float*)d_in[6];
  const float* proj_w = (const float*)d_in[7];
  const float* proj_b = (const float*)d_in[8];
  const float* ln2_w  = (const float*)d_in[9];
  const float* ln2_b  = (const float*)d_in[10];
  const float* fc_w   = (const float*)d_in[11];
  const float* fc_b   = (const float*)d_in[12];
  const float* fc2_w  = (const float*)d_in[13];
  const float* fc2_b  = (const float*)d_in[14];
  const float* lnf_w  = (const float*)d_in[15];
  const float* lnf_b  = (const float*)d_in[16];
  const float* head_w = (const float*)d_in[17];
  (void)in_sizes; (void)n_in; (void)out_size; (void)ws_size;

  char* base = (char*)d_ws;
  size_t off = 0;
  auto alloc = [&](size_t bytes) -> void* {
    void* p = base + off;
    off = (off + bytes + 255) & ~(size_t)255;
    return p;
  };
  bf16* wt_qkv  = (bf16*)alloc((size_t)NL * 3 * C * C * 2);
  bf16* wt_proj = (bf16*)alloc((size_t)NL * C * C * 2);
  bf16* wt_fc   = (bf16*)alloc((size_t)NL * 4 * C * C * 2);
  bf16* wt_fc2  = (bf16*)alloc((size_t)NL * 4 * C * C * 2);
  bf16* wt_head = (bf16*)alloc((size_t)V * C * 2);
  float* x      = (float*)alloc((size_t)BTOK * C * 4);   // absorbs head OOB reads
  bf16*  xb     = (bf16*)alloc((size_t)BTOK * C * 2);
  bf16*  qb     = (bf16*)alloc((size_t)NB * NH * T * DH * 2);
  bf16*  kb     = (bf16*)alloc((size_t)NB * NH * T * DH * 2);
  bf16*  vtb    = (bf16*)alloc((size_t)NB * NH * T * DH * 2);
  bf16*  yb     = (bf16*)alloc((size_t)BTOK * C * 2);
  bf16*  mbuf   = (bf16*)alloc((size_t)BTOK * 4 * C * 2);

  dim3 tb(32, 8);
  k_transpose_bf16<<<dim3(72, 24, NL), tb, 0, stream>>>(qkv_w, wt_qkv, C, 3 * C);
  k_transpose_bf16<<<dim3(24, 24, NL), tb, 0, stream>>>(proj_w, wt_proj, C, C);
  k_transpose_bf16<<<dim3(96, 24, NL), tb, 0, stream>>>(fc_w, wt_fc, C, 4 * C);
  k_transpose_bf16<<<dim3(24, 96, NL), tb, 0, stream>>>(fc2_w, wt_fc2, 4 * C, C);
  k_transpose_bf16<<<dim3((V + 31) / 32, 24, 1), tb, 0, stream>>>(head_w, wt_head, C, V);

  k_embed<<<BTOK * C / 256, 256, 0, stream>>>(idx, wte, wpe, x);

  for (int l = 0; l < NL; l++) {
    k_layernorm<<<BTOK, 256, 0, stream>>>(x, ln1_w + l * C, ln1_b + l * C, xb);
    k_gemm<5, true><<<dim3(16, 18), 256, 0, stream>>>(xb, wt_qkv + (long)l * 3 * C * C,
        qkv_b + l * 3 * C, qb, BTOK, 3 * C, C, C, C, 0, kb, vtb);
    k_attn<<<dim3(T / 128, NB * NH), 256, 0, stream>>>(qb, kb, vtb, yb);
    k_gemm_s<<<dim3(32, 6), 256, 0, stream>>>(yb, wt_proj + (long)l * C * C,
        proj_b + l * C, x, BTOK, C, C, C, C, C);
    k_layernorm<<<BTOK, 256, 0, stream>>>(x, ln2_w + l * C, ln2_b + l * C, xb);
    k_gemm<2, true><<<dim3(16, 24), 256, 0, stream>>>(xb, wt_fc + (long)l * 4 * C * C,
        fc_b + l * 4 * C, mbuf, BTOK, 4 * C, C, C, C, 4 * C, nullptr, nullptr);
    k_gemm_s<<<dim3(32, 6), 256, 0, stream>>>(mbuf, wt_fc2 + (long)l * 4 * C * C,
        fc2_b + l * C, x, BTOK, C, 4 * C, 4 * C, 4 * C, C);
  }
  k_layernorm<<<BTOK, 256, 0, stream>>>(x, lnf_w, lnf_b, xb);
  k_head<<<dim3(8, 197), 512, 0, stream>>>(xb, wt_head, (float*)d_out);
}

// Round 8
// 1072.918 us; speedup vs baseline: 1.6554x; 1.0535x over previous
//
#include <hip/hip_runtime.h>
#include <hip/hip_bf16.h>

typedef __hip_bfloat16 bf16;
typedef __attribute__((ext_vector_type(8))) short bf16x8;
typedef __attribute__((ext_vector_type(4))) float f32x4;
typedef __attribute__((ext_vector_type(4), aligned(4))) float f32x4u;  // unaligned-safe

#define NL 4
#define NH 12
#define C 768
#define T 1024
#define NB 2
#define BTOK 2048
#define V 50257
#define DH 64

__device__ __forceinline__ void gload16(const void* g, void* l) {
  __builtin_amdgcn_global_load_lds(
      (const __attribute__((address_space(1))) void*)g,
      (__attribute__((address_space(3))) void*)l, 16, 0, 0);
}

// ---------------- block reductions (256 threads = 4 waves) ----------------
__device__ __forceinline__ float block_sum(float v, float* red) {
#pragma unroll
  for (int off = 32; off; off >>= 1) v += __shfl_down(v, off);
  int lane = threadIdx.x & 63, wid = threadIdx.x >> 6;
  __syncthreads();
  if (lane == 0) red[wid] = v;
  __syncthreads();
  return red[0] + red[1] + red[2] + red[3];
}

// ---------------- embedding ----------------
__global__ __launch_bounds__(256) void k_embed(const int* __restrict__ idx,
    const float* __restrict__ wte, const float* __restrict__ wpe,
    float* __restrict__ x) {
  long i = (long)blockIdx.x * 256 + threadIdx.x;  // over BTOK*C (exact)
  int bt = (int)(i / C), c = (int)(i % C);
  int t = bt & (T - 1);
  x[i] = wte[(long)idx[bt] * C + c] + wpe[(long)t * C + c];
}

// ---------------- fp32 -> bf16 transposed weight convert ----------------
__global__ __launch_bounds__(256) void k_transpose_bf16(const float* __restrict__ W,
    bf16* __restrict__ Wt, int K, int N) {
  __shared__ float tile[32][33];
  long zoff = (long)blockIdx.z * K * N;
  W += zoff;
  Wt += zoff;
  int n0 = blockIdx.x * 32, k0 = blockIdx.y * 32;
  int tx = threadIdx.x, ty = threadIdx.y;
#pragma unroll
  for (int i = 0; i < 4; i++) {
    int k = k0 + ty + i * 8, n = n0 + tx;
    if (k < K && n < N) tile[ty + i * 8][tx] = W[(long)k * N + n];
  }
  __syncthreads();
#pragma unroll
  for (int i = 0; i < 4; i++) {
    int n = n0 + ty + i * 8, k = k0 + tx;
    if (n < N && k < K) Wt[(long)n * K + k] = __float2bfloat16(tile[tx][ty + i * 8]);
  }
}

// ---------------- layernorm: fp32 in -> bf16 out ----------------
__global__ __launch_bounds__(256) void k_layernorm(const float* __restrict__ x,
    const float* __restrict__ w, const float* __restrict__ b, bf16* __restrict__ out) {
  __shared__ float red[4];
  long row = blockIdx.x;
  const float* xr = x + row * C;
  int t = threadIdx.x;
  float v0 = xr[t], v1 = xr[t + 256], v2 = xr[t + 512];
  float s = block_sum(v0 + v1 + v2, red);
  float mu = s * (1.0f / C);
  float d0 = v0 - mu, d1 = v1 - mu, d2 = v2 - mu;
  float vs = block_sum(d0 * d0 + d1 * d1 + d2 * d2, red);
  float inv = rsqrtf(vs * (1.0f / C) + 1e-5f);
  bf16* orow = out + row * C;
  orow[t]       = __float2bfloat16(d0 * inv * w[t]       + b[t]);
  orow[t + 256] = __float2bfloat16(d1 * inv * w[t + 256] + b[t + 256]);
  orow[t + 512] = __float2bfloat16(d2 * inv * w[t + 512] + b[t + 512]);
}

// ---------------- fused causal flash attention (balanced pairs) ----------
// grid (T/128, NB*NH): block p handles q-tiles {p, 15-p} -> 17 KV-iters/block
__global__ __launch_bounds__(256) void k_attn(const bf16* __restrict__ q,
    const bf16* __restrict__ k, const bf16* __restrict__ vt,
    bf16* __restrict__ yb) {
  __shared__ __align__(16) bf16 Pl[4][16][72];  // per-wave P tile, +8 pad
  int pr = blockIdx.x, bh = blockIdx.y;
  int b = bh / NH, h = bh % NH;
  int tid = threadIdx.x, w = tid >> 6, lane = tid & 63;
  int l15 = lane & 15, hi = lane >> 4;
  const bf16* qbase = q + (long)bh * T * DH;
  const bf16* kbase = k + (long)bh * T * DH;
  const bf16* vbase = vt + (long)bh * DH * T;

  for (int s2 = 0; s2 < 2; s2++) {
    int qt = s2 ? (T / 64 - 1 - pr) : pr;
    int qrow = qt * 64 + w * 16 + l15;  // softmax-layout q (col of S^T)
    bf16x8 qf0 = *(const bf16x8*)(qbase + (long)qrow * DH + hi * 8);
    bf16x8 qf1 = *(const bf16x8*)(qbase + (long)qrow * DH + 32 + hi * 8);

    f32x4 accy[4] = {};               // y: row q=hi*4+rr, col d=j*16+l15
    float m_run = -1e30f, l_run = 0.f;

    int nkt = qt + 1;
    for (int kt = 0; kt < nkt; kt++) {
      int kv0 = kt * 64;
      f32x4 accs[4] = {};
#pragma unroll
      for (int kvi = 0; kvi < 4; kvi++) {
        const bf16* kr = kbase + (long)(kv0 + kvi * 16 + l15) * DH + hi * 8;
        bf16x8 kf0 = *(const bf16x8*)kr;
        bf16x8 kf1 = *(const bf16x8*)(kr + 32);
        accs[kvi] = __builtin_amdgcn_mfma_f32_16x16x32_bf16(kf0, qf0, accs[kvi], 0, 0, 0);
        accs[kvi] = __builtin_amdgcn_mfma_f32_16x16x32_bf16(kf1, qf1, accs[kvi], 0, 0, 0);
      }
      bool diag = (kt == qt);
      float p[4][4];
      float tmax = -1e30f;
#pragma unroll
      for (int kvi = 0; kvi < 4; kvi++)
#pragma unroll
        for (int rr = 0; rr < 4; rr++) {
          float s = accs[kvi][rr];
          if (diag && (kvi * 16 + hi * 4 + rr > w * 16 + l15)) s = -1e30f;
          p[kvi][rr] = s;
          tmax = fmaxf(tmax, s);
        }
      tmax = fmaxf(tmax, __shfl_xor(tmax, 16));
      tmax = fmaxf(tmax, __shfl_xor(tmax, 32));
      float m_new = fmaxf(m_run, tmax);
      float scl = __expf(m_run - m_new);
      float psum = 0.f;
#pragma unroll
      for (int kvi = 0; kvi < 4; kvi++)
#pragma unroll
        for (int rr = 0; rr < 4; rr++) {
          float e = __expf(p[kvi][rr] - m_new);
          p[kvi][rr] = e;
          psum += e;
        }
      psum += __shfl_xor(psum, 16);
      psum += __shfl_xor(psum, 32);
      l_run = l_run * scl + psum;
      m_run = m_new;
#pragma unroll
      for (int rr = 0; rr < 4; rr++) {
        float sy = __shfl(scl, hi * 4 + rr);
#pragma unroll
        for (int j = 0; j < 4; j++) accy[j][rr] *= sy;
      }
#pragma unroll
      for (int kvi = 0; kvi < 4; kvi++) {
        union { bf16 hh[2]; unsigned u; } pk0, pk1;
        pk0.hh[0] = __float2bfloat16(p[kvi][0]);
        pk0.hh[1] = __float2bfloat16(p[kvi][1]);
        pk1.hh[0] = __float2bfloat16(p[kvi][2]);
        pk1.hh[1] = __float2bfloat16(p[kvi][3]);
        *(unsigned*)&Pl[w][l15][kvi * 16 + hi * 4]     = pk0.u;
        *(unsigned*)&Pl[w][l15][kvi * 16 + hi * 4 + 2] = pk1.u;
      }
#pragma unroll
      for (int c = 0; c < 2; c++) {
        bf16x8 pf = *(const bf16x8*)&Pl[w][l15][c * 32 + hi * 8];
#pragma unroll
        for (int j = 0; j < 4; j++) {
          const bf16* vr = vbase + (long)(j * 16 + l15) * T + kv0 + c * 32 + hi * 8;
          bf16x8 vf = *(const bf16x8*)vr;
          accy[j] = __builtin_amdgcn_mfma_f32_16x16x32_bf16(pf, vf, accy[j], 0, 0, 0);
        }
      }
    }
    float inv = 1.0f / l_run;
#pragma unroll
    for (int rr = 0; rr < 4; rr++) {
      float li = __shfl(inv, hi * 4 + rr);
      int qg = qt * 64 + w * 16 + hi * 4 + rr;
#pragma unroll
      for (int j = 0; j < 4; j++)
        yb[((long)(b * T + qg)) * C + h * DH + j * 16 + l15] =
            __float2bfloat16(accy[j][rr] * li);
    }
  }
}

// ================= 8-phase 256x256 head GEMM (M=2048,N=V,K=768) ============
__global__ __launch_bounds__(512, 1) void k_head(const bf16* __restrict__ A,
    const bf16* __restrict__ B, float* __restrict__ Cv) {
  __shared__ __align__(16) char lds[131072];
  int hw = blockIdx.y * 8 + blockIdx.x;          // grid (8, 197), nwg=1576
  int L = (hw & 7) * 197 + (hw >> 3);            // bijective XCD chunk
  int mt = L & 7, nt = L >> 3;
  int m0 = mt * 256, n0 = nt * 256;
  int tid = threadIdx.x, lane = tid & 63, wid = tid >> 6;
  int wm = wid >> 2, wn = wid & 3;
  int l15 = lane & 15, hi = lane >> 4, l7 = lane & 7;
  int sg = (lane & 7) ^ (lane >> 3);             // pre-swizzled src granule
  int srA = wid * 8 + (lane >> 3);               // staging row
  const bf16* Ab = A + (long)(m0 + srA) * 768 + sg * 8;
  const bf16* Bb = B + (long)(n0 + srA) * 768 + sg * 8;  // OOB tail lands in ws
  auto STAGE = [&](int tile, int h) {            // h: 0=A0 1=A1 2=B0 3=B1
    char* dst = lds + (tile & 1) * 65536 + h * 16384 + wid * 1024;
    const bf16* src = (h < 2 ? Ab : Bb) + (long)((h & 1) * 128) * 768 + tile * 64;
    gload16(src, dst);
    gload16(src + 64 * 768, dst + 8192);
  };
  f32x4 acc[8][4] = {};
  STAGE(0, 0); STAGE(0, 1); STAGE(0, 2); STAGE(0, 3); STAGE(1, 0);
  asm volatile("s_waitcnt vmcnt(2)" ::: "memory");
  __builtin_amdgcn_s_barrier();
  int bro = (wn & 1) * 64;
  int g0 = (hi ^ l7) * 16, g1 = ((4 + hi) ^ l7) * 16;
  for (int t = 0; t < 12; t++) {
    char* ha = lds + (t & 1) * 65536 + wm * 16384;
    char* hb = lds + (t & 1) * 65536 + 32768 + (wn >> 1) * 16384;
    bf16x8 af[4], bv[4];
#pragma unroll
    for (int mf = 0; mf < 4; mf++)
      af[mf] = *(const bf16x8*)(ha + (mf * 16 + l15) * 128 + g0);
#pragma unroll
    for (int nf = 0; nf < 4; nf++)
      bv[nf] = *(const bf16x8*)(hb + (bro + nf * 16 + l15) * 128 + g0);
    if (t + 1 < 12) { STAGE(t + 1, 1); STAGE(t + 1, 2); }
    __builtin_amdgcn_s_barrier();
    __builtin_amdgcn_s_setprio(1);
#pragma unroll
    for (int mf = 0; mf < 4; mf++)
#pragma unroll
      for (int nf = 0; nf < 4; nf++)
        acc[mf][nf] = __builtin_amdgcn_mfma_f32_16x16x32_bf16(af[mf], bv[nf], acc[mf][nf], 0, 0, 0);
    __builtin_amdgcn_s_setprio(0);
    __builtin_amdgcn_s_barrier();
#pragma unroll
    for (int mf = 0; mf < 4; mf++)
      af[mf] = *(const bf16x8*)(ha + ((mf + 4) * 16 + l15) * 128 + g0);
    if (t + 1 < 12) STAGE(t + 1, 3);
    __builtin_amdgcn_s_barrier();
    __builtin_amdgcn_s_setprio(1);
#pragma unroll
    for (int mf = 0; mf < 4; mf++)
#pragma unroll
      for (int nf = 0; nf < 4; nf++)
        acc[mf + 4][nf] = __builtin_amdgcn_mfma_f32_16x16x32_bf16(af[mf], bv[nf], acc[mf + 4][nf], 0, 0, 0);
    __builtin_amdgcn_s_setprio(0);
    __builtin_amdgcn_s_barrier();
#pragma unroll
    for (int mf = 0; mf < 4; mf++)
      af[mf] = *(const bf16x8*)(ha + (mf * 16 + l15) * 128 + g1);
#pragma unroll
    for (int nf = 0; nf < 4; nf++)
      bv[nf] = *(const bf16x8*)(hb + (bro + nf * 16 + l15) * 128 + g1);
    __builtin_amdgcn_s_barrier();
    __builtin_amdgcn_s_setprio(1);
#pragma unroll
    for (int mf = 0; mf < 4; mf++)
#pragma unroll
      for (int nf = 0; nf < 4; nf++)
        acc[mf][nf] = __builtin_amdgcn_mfma_f32_16x16x32_bf16(af[mf], bv[nf], acc[mf][nf], 0, 0, 0);
    __builtin_amdgcn_s_setprio(0);
    __builtin_amdgcn_s_barrier();
#pragma unroll
    for (int mf = 0; mf < 4; mf++)
      af[mf] = *(const bf16x8*)(ha + ((mf + 4) * 16 + l15) * 128 + g1);
    if (t + 2 < 12) STAGE(t + 2, 0);
    __builtin_amdgcn_s_barrier();
    __builtin_amdgcn_s_setprio(1);
#pragma unroll
    for (int mf = 0; mf < 4; mf++)
#pragma unroll
      for (int nf = 0; nf < 4; nf++)
        acc[mf + 4][nf] = __builtin_amdgcn_mfma_f32_16x16x32_bf16(af[mf], bv[nf], acc[mf + 4][nf], 0, 0, 0);
    __builtin_amdgcn_s_setprio(0);
    if (t < 11) {
      if (t + 2 < 12) asm volatile("s_waitcnt vmcnt(2)" ::: "memory");
      else            asm volatile("s_waitcnt vmcnt(0)" ::: "memory");
      __builtin_amdgcn_s_barrier();
    }
  }
  // ---- epilogue: 2 mf-slices per LDS round ([64][260] f32 = 66.6 KB) ----
  __syncthreads();
  float* Cst = (float*)lds;
#pragma unroll
  for (int rnd = 0; rnd < 4; rnd++) {
#pragma unroll
    for (int mfl = 0; mfl < 2; mfl++) {
      int mf = rnd * 2 + mfl;
#pragma unroll
      for (int nf = 0; nf < 4; nf++)
#pragma unroll
        for (int rr = 0; rr < 4; rr++)
          Cst[(wm * 32 + mfl * 16 + hi * 4 + rr) * 260 + wn * 64 + nf * 16 + l15] =
              acc[mf][nf][rr];
    }
    __syncthreads();
#pragma unroll
    for (int s = 0; s < 8; s++) {
      int gid = tid + s * 512;           // 0..4095
      int r = gid >> 6, g = gid & 63;    // row 0..63, 4-col granule
      int grow = m0 + (r >> 5) * 128 + (rnd * 2 + ((r >> 4) & 1)) * 16 + (r & 15);
      int gcol = n0 + g * 4;
      f32x4 vv = *(const f32x4*)&Cst[r * 260 + g * 4];
      float* dst = Cv + (long)grow * V + gcol;
      if (gcol + 3 < V) {
        *(f32x4u*)dst = vv;
      } else {
#pragma unroll
        for (int e = 0; e < 4; e++)
          if (gcol + e < V) dst[e] = vv[e];
      }
    }
    __syncthreads();
  }
}

// ------- layer GEMM: BM=64, BN=128, BK=64, depth-2 pipeline, XCD swizzle ----
// LDS[row][g] holds global granule g^(row&7); write linear, read XOR.
// EPI 2: bf16 out, gelu(acc+bias). EPI 3: fp32 residual in-place.
// EPI 5: qkv split-repack: Cv=q (scaled 0.125), Cv2=k, Cv3=vt.
// requires: nwg%8==0, M%64==0, N%128==0, K%64==0
#define SBK 64
template <int EPI>
__global__ __launch_bounds__(256) void k_gemm_s(const bf16* __restrict__ A,
    const bf16* __restrict__ B, const float* __restrict__ bias,
    void* __restrict__ Cv, int M, int N, int K, int lda, int ldb, int ldc,
    void* __restrict__ Cv2, void* __restrict__ Cv3) {
  __shared__ __align__(16) bf16 As[2][64][SBK];   // 16 KiB
  __shared__ __align__(16) bf16 Bs[2][128][SBK];  // 32 KiB
  int nwg = gridDim.x * gridDim.y;
  int hw = blockIdx.y * gridDim.x + blockIdx.x;
  int logical = (hw & 7) * (nwg >> 3) + (hw >> 3);
  int bx = logical % gridDim.x, by = logical / gridDim.x;
  int m0 = bx * 64, n0 = by * 128;
  int tid = threadIdx.x;
  int lane = tid & 63, w = tid >> 6;
  int l15 = lane & 15, hi = lane >> 4, l7 = lane & 7;
  int srow = lane >> 3;                 // 0..7
  int sgr = lane & 7;
  int scol = ((sgr ^ srow) << 3);       // pre-swizzled source col (elements)
  f32x4 acc[4][2] = {};
  const bf16* Ag = A + (long)(m0 + w * 8 + srow) * lda + scol;
  const bf16* Bg = B + (long)(n0 + w * 8 + srow) * ldb + scol;
  int NT = K / SBK;
  auto STAGE = [&](int t) {
    int k0 = t * SBK, b = t & 1;
    gload16(Ag + k0,            &As[b][w * 8][0]);
    gload16(Ag + k0 + 32 * lda, &As[b][w * 8 + 32][0]);
    gload16(Bg + k0,            &Bs[b][w * 8][0]);
    gload16(Bg + k0 + 32 * ldb, &Bs[b][w * 8 + 32][0]);
    gload16(Bg + k0 + 64 * ldb, &Bs[b][w * 8 + 64][0]);
    gload16(Bg + k0 + 96 * ldb, &Bs[b][w * 8 + 96][0]);
  };
  STAGE(0);
  STAGE(1);
  int c0 = (hi ^ l7) << 3, c1 = ((4 + hi) ^ l7) << 3;  // kk0/kk1 read cols
  for (int t = 0; t < NT; t++) {
    int b = t & 1;
    if (t + 1 < NT) asm volatile("s_waitcnt vmcnt(6)" ::: "memory");
    else            asm volatile("s_waitcnt vmcnt(0)" ::: "memory");
    __builtin_amdgcn_s_barrier();
    bf16x8 a0[4], a1[4], b0[2], b1[2];
#pragma unroll
    for (int i = 0; i < 4; i++) {
      a0[i] = *(const bf16x8*)&As[b][i * 16 + l15][c0];
      a1[i] = *(const bf16x8*)&As[b][i * 16 + l15][c1];
    }
#pragma unroll
    for (int j = 0; j < 2; j++) {
      b0[j] = *(const bf16x8*)&Bs[b][w * 32 + j * 16 + l15][c0];
      b1[j] = *(const bf16x8*)&Bs[b][w * 32 + j * 16 + l15][c1];
    }
    asm volatile("s_waitcnt lgkmcnt(0)" ::: "memory");
    __builtin_amdgcn_s_barrier();
    if (t + 2 < NT) STAGE(t + 2);
    __builtin_amdgcn_s_setprio(1);
#pragma unroll
    for (int i = 0; i < 4; i++)
#pragma unroll
      for (int j = 0; j < 2; j++) {
        acc[i][j] = __builtin_amdgcn_mfma_f32_16x16x32_bf16(a0[i], b0[j], acc[i][j], 0, 0, 0);
        acc[i][j] = __builtin_amdgcn_mfma_f32_16x16x32_bf16(a1[i], b1[j], acc[i][j], 0, 0, 0);
      }
    __builtin_amdgcn_s_setprio(0);
  }
#pragma unroll
  for (int j = 0; j < 2; j++) {
    int gn = n0 + w * 32 + j * 16 + l15;
    float bv = bias[gn];
#pragma unroll
    for (int i = 0; i < 4; i++)
#pragma unroll
      for (int rr = 0; rr < 4; rr++) {
        int gm = m0 + i * 16 + hi * 4 + rr;
        float v = acc[i][j][rr] + bv;
        if constexpr (EPI == 3) {
          long off = (long)gm * ldc + gn;
          ((float*)Cv)[off] = v + ((float*)Cv)[off];
        } else if constexpr (EPI == 2) {
          float u = 0.7978845608028654f * (v + 0.044715f * v * v * v);
          u = fminf(fmaxf(u, -15.f), 15.f);
          float e2 = __expf(2.f * u);
          float th = (e2 - 1.f) / (e2 + 1.f);
          ((bf16*)Cv)[(long)gm * ldc + gn] = __float2bfloat16(0.5f * v * (1.f + th));
        } else if constexpr (EPI == 5) {
          int gb = gm >> 10, gt = gm & 1023;
          int which = gn / C;
          int r = gn - which * C;
          int h = r >> 6, d = r & 63;
          long bh = (long)(gb * NH + h);
          if (which == 0)
            ((bf16*)Cv)[(bh * T + gt) * DH + d] = __float2bfloat16(v * 0.125f);
          else if (which == 1)
            ((bf16*)Cv2)[(bh * T + gt) * DH + d] = __float2bfloat16(v);
          else
            ((bf16*)Cv3)[(bh * DH + d) * T + gt] = __float2bfloat16(v);
        }
      }
  }
}

extern "C" void kernel_launch(void* const* d_in, const int* in_sizes, int n_in,
                              void* d_out, int out_size, void* d_ws, size_t ws_size,
                              hipStream_t stream) {
  const int*   idx    = (const int*)d_in[0];
  const float* wte    = (const float*)d_in[1];
  const float* wpe    = (const float*)d_in[2];
  const float* ln1_w  = (const float*)d_in[3];
  const float* ln1_b  = (const float*)d_in[4];
  const float* qkv_w  = (const float*)d_in[5];
  const float* qkv_b  = (const float*)d_in[6];
  const float* proj_w = (const float*)d_in[7];
  const float* proj_b = (const float*)d_in[8];
  const float* ln2_w  = (const float*)d_in[9];
  const float* ln2_b  = (const float*)d_in[10];
  const float* fc_w   = (const float*)d_in[11];
  const float* fc_b   = (const float*)d_in[12];
  const float* fc2_w  = (const float*)d_in[13];
  const float* fc2_b  = (const float*)d_in[14];
  const float* lnf_w  = (const float*)d_in[15];
  const float* lnf_b  = (const float*)d_in[16];
  const float* head_w = (const float*)d_in[17];
  (void)in_sizes; (void)n_in; (void)out_size; (void)ws_size;

  char* base = (char*)d_ws;
  size_t off = 0;
  auto alloc = [&](size_t bytes) -> void* {
    void* p = base + off;
    off = (off + bytes + 255) & ~(size_t)255;
    return p;
  };
  bf16* wt_qkv  = (bf16*)alloc((size_t)NL * 3 * C * C * 2);
  bf16* wt_proj = (bf16*)alloc((size_t)NL * C * C * 2);
  bf16* wt_fc   = (bf16*)alloc((size_t)NL * 4 * C * C * 2);
  bf16* wt_fc2  = (bf16*)alloc((size_t)NL * 4 * C * C * 2);
  bf16* wt_head = (bf16*)alloc((size_t)V * C * 2);
  float* x      = (float*)alloc((size_t)BTOK * C * 4);   // absorbs head OOB reads
  bf16*  xb     = (bf16*)alloc((size_t)BTOK * C * 2);
  bf16*  qb     = (bf16*)alloc((size_t)NB * NH * T * DH * 2);
  bf16*  kb     = (bf16*)alloc((size_t)NB * NH * T * DH * 2);
  bf16*  vtb    = (bf16*)alloc((size_t)NB * NH * T * DH * 2);
  bf16*  yb     = (bf16*)alloc((size_t)BTOK * C * 2);
  bf16*  mbuf   = (bf16*)alloc((size_t)BTOK * 4 * C * 2);

  dim3 tb(32, 8);
  k_transpose_bf16<<<dim3(72, 24, NL), tb, 0, stream>>>(qkv_w, wt_qkv, C, 3 * C);
  k_transpose_bf16<<<dim3(24, 24, NL), tb, 0, stream>>>(proj_w, wt_proj, C, C);
  k_transpose_bf16<<<dim3(96, 24, NL), tb, 0, stream>>>(fc_w, wt_fc, C, 4 * C);
  k_transpose_bf16<<<dim3(24, 96, NL), tb, 0, stream>>>(fc2_w, wt_fc2, 4 * C, C);
  k_transpose_bf16<<<dim3((V + 31) / 32, 24, 1), tb, 0, stream>>>(head_w, wt_head, C, V);

  k_embed<<<BTOK * C / 256, 256, 0, stream>>>(idx, wte, wpe, x);

  for (int l = 0; l < NL; l++) {
    k_layernorm<<<BTOK, 256, 0, stream>>>(x, ln1_w + l * C, ln1_b + l * C, xb);
    k_gemm_s<5><<<dim3(32, 18), 256, 0, stream>>>(xb, wt_qkv + (long)l * 3 * C * C,
        qkv_b + l * 3 * C, qb, BTOK, 3 * C, C, C, C, 0, kb, vtb);
    k_attn<<<dim3(T / 128, NB * NH), 256, 0, stream>>>(qb, kb, vtb, yb);
    k_gemm_s<3><<<dim3(32, 6), 256, 0, stream>>>(yb, wt_proj + (long)l * C * C,
        proj_b + l * C, x, BTOK, C, C, C, C, C, nullptr, nullptr);
    k_layernorm<<<BTOK, 256, 0, stream>>>(x, ln2_w + l * C, ln2_b + l * C, xb);
    k_gemm_s<2><<<dim3(32, 24), 256, 0, stream>>>(xb, wt_fc + (long)l * 4 * C * C,
        fc_b + l * 4 * C, mbuf, BTOK, 4 * C, C, C, C, 4 * C, nullptr, nullptr);
    k_gemm_s<3><<<dim3(32, 6), 256, 0, stream>>>(mbuf, wt_fc2 + (long)l * 4 * C * C,
        fc2_b + l * C, x, BTOK, C, 4 * C, 4 * C, 4 * C, C, nullptr, nullptr);
  }
  k_layernorm<<<BTOK, 256, 0, stream>>>(x, lnf_w, lnf_b, xb);
  k_head<<<dim3(8, 197), 512, 0, stream>>>(xb, wt_head, (float*)d_out);
}

// Round 9
// 1059.617 us; speedup vs baseline: 1.6762x; 1.0126x over previous
//
#include <hip/hip_runtime.h>
#include <hip/hip_bf16.h>

typedef __hip_bfloat16 bf16;
typedef __attribute__((ext_vector_type(8))) short bf16x8;
typedef __attribute__((ext_vector_type(4))) float f32x4;
typedef __attribute__((ext_vector_type(4), aligned(4))) float f32x4u;  // unaligned-safe

#define NL 4
#define NH 12
#define C 768
#define T 1024
#define NB 2
#define BTOK 2048
#define V 50257
#define DH 64

__device__ __forceinline__ void gload16(const void* g, void* l) {
  __builtin_amdgcn_global_load_lds(
      (const __attribute__((address_space(1))) void*)g,
      (__attribute__((address_space(3))) void*)l, 16, 0, 0);
}

// ---------------- block reductions (256 threads = 4 waves) ----------------
__device__ __forceinline__ float block_sum(float v, float* red) {
#pragma unroll
  for (int off = 32; off; off >>= 1) v += __shfl_down(v, off);
  int lane = threadIdx.x & 63, wid = threadIdx.x >> 6;
  __syncthreads();
  if (lane == 0) red[wid] = v;
  __syncthreads();
  return red[0] + red[1] + red[2] + red[3];
}

// ---------------- embedding ----------------
__global__ __launch_bounds__(256) void k_embed(const int* __restrict__ idx,
    const float* __restrict__ wte, const float* __restrict__ wpe,
    float* __restrict__ x) {
  long i = (long)blockIdx.x * 256 + threadIdx.x;  // over BTOK*C (exact)
  int bt = (int)(i / C), c = (int)(i % C);
  int t = bt & (T - 1);
  x[i] = wte[(long)idx[bt] * C + c] + wpe[(long)t * C + c];
}

// ---------------- fp32 -> bf16 transposed weight convert ----------------
__global__ __launch_bounds__(256) void k_transpose_bf16(const float* __restrict__ W,
    bf16* __restrict__ Wt, int K, int N) {
  __shared__ float tile[32][33];
  long zoff = (long)blockIdx.z * K * N;
  W += zoff;
  Wt += zoff;
  int n0 = blockIdx.x * 32, k0 = blockIdx.y * 32;
  int tx = threadIdx.x, ty = threadIdx.y;
#pragma unroll
  for (int i = 0; i < 4; i++) {
    int k = k0 + ty + i * 8, n = n0 + tx;
    if (k < K && n < N) tile[ty + i * 8][tx] = W[(long)k * N + n];
  }
  __syncthreads();
#pragma unroll
  for (int i = 0; i < 4; i++) {
    int n = n0 + ty + i * 8, k = k0 + tx;
    if (n < N && k < K) Wt[(long)n * K + k] = __float2bfloat16(tile[tx][ty + i * 8]);
  }
}

// ---------------- layernorm: fp32 in -> bf16 out ----------------
__global__ __launch_bounds__(256) void k_layernorm(const float* __restrict__ x,
    const float* __restrict__ w, const float* __restrict__ b, bf16* __restrict__ out) {
  __shared__ float red[4];
  long row = blockIdx.x;
  const float* xr = x + row * C;
  int t = threadIdx.x;
  float v0 = xr[t], v1 = xr[t + 256], v2 = xr[t + 512];
  float s = block_sum(v0 + v1 + v2, red);
  float mu = s * (1.0f / C);
  float d0 = v0 - mu, d1 = v1 - mu, d2 = v2 - mu;
  float vs = block_sum(d0 * d0 + d1 * d1 + d2 * d2, red);
  float inv = rsqrtf(vs * (1.0f / C) + 1e-5f);
  bf16* orow = out + row * C;
  orow[t]       = __float2bfloat16(d0 * inv * w[t]       + b[t]);
  orow[t + 256] = __float2bfloat16(d1 * inv * w[t + 256] + b[t + 256]);
  orow[t + 512] = __float2bfloat16(d2 * inv * w[t + 512] + b[t + 512]);
}

// ---------------- fused causal flash attention (balanced pairs, z-split) ----
// grid (8, NB*NH, 2): block (p, bh, z) handles qt = z ? 15-p : p
__global__ __launch_bounds__(256) void k_attn(const bf16* __restrict__ q,
    const bf16* __restrict__ k, const bf16* __restrict__ vt,
    bf16* __restrict__ yb) {
  __shared__ __align__(16) bf16 Pl[4][16][72];  // per-wave P tile, +8 pad
  int pr = blockIdx.x, bh = blockIdx.y;
  int b = bh / NH, h = bh % NH;
  int tid = threadIdx.x, w = tid >> 6, lane = tid & 63;
  int l15 = lane & 15, hi = lane >> 4;
  const bf16* qbase = q + (long)bh * T * DH;
  const bf16* kbase = k + (long)bh * T * DH;
  const bf16* vbase = vt + (long)bh * DH * T;

  int qt = blockIdx.z ? (T / 64 - 1 - pr) : pr;
  int qrow = qt * 64 + w * 16 + l15;  // softmax-layout q (col of S^T)
  bf16x8 qf0 = *(const bf16x8*)(qbase + (long)qrow * DH + hi * 8);
  bf16x8 qf1 = *(const bf16x8*)(qbase + (long)qrow * DH + 32 + hi * 8);

  f32x4 accy[4] = {};               // y: row q=hi*4+rr, col d=j*16+l15
  float m_run = -1e30f, l_run = 0.f;

  int nkt = qt + 1;
  for (int kt = 0; kt < nkt; kt++) {
    int kv0 = kt * 64;
    f32x4 accs[4] = {};
#pragma unroll
    for (int kvi = 0; kvi < 4; kvi++) {
      const bf16* kr = kbase + (long)(kv0 + kvi * 16 + l15) * DH + hi * 8;
      bf16x8 kf0 = *(const bf16x8*)kr;
      bf16x8 kf1 = *(const bf16x8*)(kr + 32);
      accs[kvi] = __builtin_amdgcn_mfma_f32_16x16x32_bf16(kf0, qf0, accs[kvi], 0, 0, 0);
      accs[kvi] = __builtin_amdgcn_mfma_f32_16x16x32_bf16(kf1, qf1, accs[kvi], 0, 0, 0);
    }
    bool diag = (kt == qt);
    float p[4][4];
    float tmax = -1e30f;
#pragma unroll
    for (int kvi = 0; kvi < 4; kvi++)
#pragma unroll
      for (int rr = 0; rr < 4; rr++) {
        float s = accs[kvi][rr];
        if (diag && (kvi * 16 + hi * 4 + rr > w * 16 + l15)) s = -1e30f;
        p[kvi][rr] = s;
        tmax = fmaxf(tmax, s);
      }
    tmax = fmaxf(tmax, __shfl_xor(tmax, 16));
    tmax = fmaxf(tmax, __shfl_xor(tmax, 32));
    float m_new = fmaxf(m_run, tmax);
    float scl = __expf(m_run - m_new);
    float psum = 0.f;
#pragma unroll
    for (int kvi = 0; kvi < 4; kvi++)
#pragma unroll
      for (int rr = 0; rr < 4; rr++) {
        float e = __expf(p[kvi][rr] - m_new);
        p[kvi][rr] = e;
        psum += e;
      }
    psum += __shfl_xor(psum, 16);
    psum += __shfl_xor(psum, 32);
    l_run = l_run * scl + psum;
    m_run = m_new;
#pragma unroll
    for (int rr = 0; rr < 4; rr++) {
      float sy = __shfl(scl, hi * 4 + rr);
#pragma unroll
      for (int j = 0; j < 4; j++) accy[j][rr] *= sy;
    }
#pragma unroll
    for (int kvi = 0; kvi < 4; kvi++) {
      union { bf16 hh[2]; unsigned u; } pk0, pk1;
      pk0.hh[0] = __float2bfloat16(p[kvi][0]);
      pk0.hh[1] = __float2bfloat16(p[kvi][1]);
      pk1.hh[0] = __float2bfloat16(p[kvi][2]);
      pk1.hh[1] = __float2bfloat16(p[kvi][3]);
      *(unsigned*)&Pl[w][l15][kvi * 16 + hi * 4]     = pk0.u;
      *(unsigned*)&Pl[w][l15][kvi * 16 + hi * 4 + 2] = pk1.u;
    }
#pragma unroll
    for (int c = 0; c < 2; c++) {
      bf16x8 pf = *(const bf16x8*)&Pl[w][l15][c * 32 + hi * 8];
#pragma unroll
      for (int j = 0; j < 4; j++) {
        const bf16* vr = vbase + (long)(j * 16 + l15) * T + kv0 + c * 32 + hi * 8;
        bf16x8 vf = *(const bf16x8*)vr;
        accy[j] = __builtin_amdgcn_mfma_f32_16x16x32_bf16(pf, vf, accy[j], 0, 0, 0);
      }
    }
  }
  float inv = 1.0f / l_run;
#pragma unroll
  for (int rr = 0; rr < 4; rr++) {
    float li = __shfl(inv, hi * 4 + rr);
    int qg = qt * 64 + w * 16 + hi * 4 + rr;
#pragma unroll
    for (int j = 0; j < 4; j++)
      yb[((long)(b * T + qg)) * C + h * DH + j * 16 + l15] =
          __float2bfloat16(accy[j][rr] * li);
  }
}

// ====== head GEMM: 128x128, BK=64, depth-2 counted vmcnt, 2 blocks/CU ======
// M=2048 K=768 fixed; lda=ldb=768; ldc=N=V. fp32 out via LDS-transposed stores.
// LDS[row][g] holds global granule g^(row&7); write linear (pre-swz src), read XOR.
__global__ __launch_bounds__(256, 2) void k_gemm_b(const bf16* __restrict__ A,
    const bf16* __restrict__ B, float* __restrict__ Cv, int N) {
  __shared__ __align__(16) bf16 As[2][128][64];  // 32 KiB
  __shared__ __align__(16) bf16 Bs[2][128][64];  // 32 KiB
  int nwg = gridDim.x * gridDim.y;               // (16, 393) -> 6288, %8==0
  int hw = blockIdx.y * gridDim.x + blockIdx.x;
  int logical = (hw & 7) * (nwg >> 3) + (hw >> 3);
  int bx = logical % gridDim.x, by = logical / gridDim.x;
  int m0 = bx * 128, n0 = by * 128;
  int tid = threadIdx.x, lane = tid & 63, wid = tid >> 6;
  int wr = wid >> 1, wc = wid & 1;
  int l15 = lane & 15, hi = lane >> 4, l7 = lane & 7;
  int srow = lane >> 3, sgr = lane & 7;
  int scol = ((sgr ^ srow) << 3);                // pre-swizzled source col
  f32x4 acc[4][4] = {};
  const bf16* Ag = A + (long)(m0 + wid * 8 + srow) * 768 + scol;
  const bf16* Bg = B + (long)(n0 + wid * 8 + srow) * 768 + scol;  // OOB tail in ws
  const int NT = 12;
  auto STAGE = [&](int t) {
    int k0 = t * 64, b = t & 1;
#pragma unroll
    for (int r = 0; r < 4; r++) {
      gload16(Ag + k0 + (long)(r * 32) * 768, &As[b][wid * 8 + r * 32][0]);
      gload16(Bg + k0 + (long)(r * 32) * 768, &Bs[b][wid * 8 + r * 32][0]);
    }
  };
  STAGE(0);
  STAGE(1);
  int c0 = (hi ^ l7) << 3, c1 = ((4 + hi) ^ l7) << 3;
  for (int t = 0; t < NT; t++) {
    int b = t & 1;
    if (t + 1 < NT) asm volatile("s_waitcnt vmcnt(8)" ::: "memory");
    else            asm volatile("s_waitcnt vmcnt(0)" ::: "memory");
    __builtin_amdgcn_s_barrier();
    bf16x8 a0[4], a1[4], b0[4], b1[4];
#pragma unroll
    for (int i = 0; i < 4; i++) {
      a0[i] = *(const bf16x8*)&As[b][wr * 64 + i * 16 + l15][c0];
      a1[i] = *(const bf16x8*)&As[b][wr * 64 + i * 16 + l15][c1];
      b0[i] = *(const bf16x8*)&Bs[b][wc * 64 + i * 16 + l15][c0];
      b1[i] = *(const bf16x8*)&Bs[b][wc * 64 + i * 16 + l15][c1];
    }
    asm volatile("s_waitcnt lgkmcnt(0)" ::: "memory");
    __builtin_amdgcn_s_barrier();
    if (t + 2 < NT) STAGE(t + 2);
    __builtin_amdgcn_s_setprio(1);
#pragma unroll
    for (int i = 0; i < 4; i++)
#pragma unroll
      for (int j = 0; j < 4; j++) {
        acc[i][j] = __builtin_amdgcn_mfma_f32_16x16x32_bf16(a0[i], b0[j], acc[i][j], 0, 0, 0);
        acc[i][j] = __builtin_amdgcn_mfma_f32_16x16x32_bf16(a1[i], b1[j], acc[i][j], 0, 0, 0);
      }
    __builtin_amdgcn_s_setprio(0);
  }
  // LDS-transposed epilogue: contiguous 16B fp32 stores
  float* Ct = (float*)&As[0][0][0];  // 32 x 128 f32 = 16 KiB
  __syncthreads();
#pragma unroll
  for (int i = 0; i < 4; i++) {
#pragma unroll
    for (int j = 0; j < 4; j++) {
      int lc = wc * 64 + j * 16 + l15;
#pragma unroll
      for (int rr = 0; rr < 4; rr++)
        Ct[(wr * 16 + hi * 4 + rr) * 128 + lc] = acc[i][j][rr];
    }
    __syncthreads();
#pragma unroll
    for (int s = 0; s < 4; s++) {
      int idxq = tid + s * 256;          // 0..1023
      int lr = idxq >> 5;                // 0..31
      int c4 = (idxq & 31) * 4;          // 0..124
      int gm = m0 + (lr >> 4) * 64 + i * 16 + (lr & 15);
      int gn = n0 + c4;
      f32x4 vv = *(const f32x4*)&Ct[lr * 128 + c4];
      float* dst = Cv + (long)gm * N + gn;
      if (gn + 3 < N) {
        *(f32x4u*)dst = vv;
      } else {
#pragma unroll
        for (int e = 0; e < 4; e++)
          if (gn + e < N) dst[e] = vv[e];
      }
    }
    __syncthreads();
  }
}

// ------- layer GEMM: BM=64, BN=128, BK=64, depth-2 pipeline, XCD swizzle ----
// LDS[row][g] holds global granule g^(row&7); write linear, read XOR.
// EPI 2: bf16 out, gelu(acc+bias). EPI 3: fp32 residual in-place.
// EPI 5: qkv split-repack: Cv=q (scaled 0.125), Cv2=k, Cv3=vt.
#define SBK 64
template <int EPI>
__global__ __launch_bounds__(256) void k_gemm_s(const bf16* __restrict__ A,
    const bf16* __restrict__ B, const float* __restrict__ bias,
    void* __restrict__ Cv, int M, int N, int K, int lda, int ldb, int ldc,
    void* __restrict__ Cv2, void* __restrict__ Cv3) {
  __shared__ __align__(16) bf16 As[2][64][SBK];   // 16 KiB
  __shared__ __align__(16) bf16 Bs[2][128][SBK];  // 32 KiB
  int nwg = gridDim.x * gridDim.y;
  int hw = blockIdx.y * gridDim.x + blockIdx.x;
  int logical = (hw & 7) * (nwg >> 3) + (hw >> 3);
  int bx = logical % gridDim.x, by = logical / gridDim.x;
  int m0 = bx * 64, n0 = by * 128;
  int tid = threadIdx.x;
  int lane = tid & 63, w = tid >> 6;
  int l15 = lane & 15, hi = lane >> 4, l7 = lane & 7;
  int srow = lane >> 3;                 // 0..7
  int sgr = lane & 7;
  int scol = ((sgr ^ srow) << 3);       // pre-swizzled source col (elements)
  f32x4 acc[4][2] = {};
  const bf16* Ag = A + (long)(m0 + w * 8 + srow) * lda + scol;
  const bf16* Bg = B + (long)(n0 + w * 8 + srow) * ldb + scol;
  int NT = K / SBK;
  auto STAGE = [&](int t) {
    int k0 = t * SBK, b = t & 1;
    gload16(Ag + k0,            &As[b][w * 8][0]);
    gload16(Ag + k0 + 32 * lda, &As[b][w * 8 + 32][0]);
    gload16(Bg + k0,            &Bs[b][w * 8][0]);
    gload16(Bg + k0 + 32 * ldb, &Bs[b][w * 8 + 32][0]);
    gload16(Bg + k0 + 64 * ldb, &Bs[b][w * 8 + 64][0]);
    gload16(Bg + k0 + 96 * ldb, &Bs[b][w * 8 + 96][0]);
  };
  STAGE(0);
  STAGE(1);
  int c0 = (hi ^ l7) << 3, c1 = ((4 + hi) ^ l7) << 3;  // kk0/kk1 read cols
  for (int t = 0; t < NT; t++) {
    int b = t & 1;
    if (t + 1 < NT) asm volatile("s_waitcnt vmcnt(6)" ::: "memory");
    else            asm volatile("s_waitcnt vmcnt(0)" ::: "memory");
    __builtin_amdgcn_s_barrier();
    bf16x8 a0[4], a1[4], b0[2], b1[2];
#pragma unroll
    for (int i = 0; i < 4; i++) {
      a0[i] = *(const bf16x8*)&As[b][i * 16 + l15][c0];
      a1[i] = *(const bf16x8*)&As[b][i * 16 + l15][c1];
    }
#pragma unroll
    for (int j = 0; j < 2; j++) {
      b0[j] = *(const bf16x8*)&Bs[b][w * 32 + j * 16 + l15][c0];
      b1[j] = *(const bf16x8*)&Bs[b][w * 32 + j * 16 + l15][c1];
    }
    asm volatile("s_waitcnt lgkmcnt(0)" ::: "memory");
    __builtin_amdgcn_s_barrier();
    if (t + 2 < NT) STAGE(t + 2);
    __builtin_amdgcn_s_setprio(1);
#pragma unroll
    for (int i = 0; i < 4; i++)
#pragma unroll
      for (int j = 0; j < 2; j++) {
        acc[i][j] = __builtin_amdgcn_mfma_f32_16x16x32_bf16(a0[i], b0[j], acc[i][j], 0, 0, 0);
        acc[i][j] = __builtin_amdgcn_mfma_f32_16x16x32_bf16(a1[i], b1[j], acc[i][j], 0, 0, 0);
      }
    __builtin_amdgcn_s_setprio(0);
  }
#pragma unroll
  for (int j = 0; j < 2; j++) {
    int gn = n0 + w * 32 + j * 16 + l15;
    float bv = bias[gn];
#pragma unroll
    for (int i = 0; i < 4; i++)
#pragma unroll
      for (int rr = 0; rr < 4; rr++) {
        int gm = m0 + i * 16 + hi * 4 + rr;
        float v = acc[i][j][rr] + bv;
        if constexpr (EPI == 3) {
          long off = (long)gm * ldc + gn;
          ((float*)Cv)[off] = v + ((float*)Cv)[off];
        } else if constexpr (EPI == 2) {
          float u = 0.7978845608028654f * (v + 0.044715f * v * v * v);
          u = fminf(fmaxf(u, -15.f), 15.f);
          float e2 = __expf(2.f * u);
          float th = (e2 - 1.f) / (e2 + 1.f);
          ((bf16*)Cv)[(long)gm * ldc + gn] = __float2bfloat16(0.5f * v * (1.f + th));
        } else if constexpr (EPI == 5) {
          int gb = gm >> 10, gt = gm & 1023;
          int which = gn / C;
          int r = gn - which * C;
          int h = r >> 6, d = r & 63;
          long bh = (long)(gb * NH + h);
          if (which == 0)
            ((bf16*)Cv)[(bh * T + gt) * DH + d] = __float2bfloat16(v * 0.125f);
          else if (which == 1)
            ((bf16*)Cv2)[(bh * T + gt) * DH + d] = __float2bfloat16(v);
          else
            ((bf16*)Cv3)[(bh * DH + d) * T + gt] = __float2bfloat16(v);
        }
      }
  }
}

extern "C" void kernel_launch(void* const* d_in, const int* in_sizes, int n_in,
                              void* d_out, int out_size, void* d_ws, size_t ws_size,
                              hipStream_t stream) {
  const int*   idx    = (const int*)d_in[0];
  const float* wte    = (const float*)d_in[1];
  const float* wpe    = (const float*)d_in[2];
  const float* ln1_w  = (const float*)d_in[3];
  const float* ln1_b  = (const float*)d_in[4];
  const float* qkv_w  = (const float*)d_in[5];
  const float* qkv_b  = (const float*)d_in[6];
  const float* proj_w = (const float*)d_in[7];
  const float* proj_b = (const float*)d_in[8];
  const float* ln2_w  = (const float*)d_in[9];
  const float* ln2_b  = (const float*)d_in[10];
  const float* fc_w   = (const float*)d_in[11];
  const float* fc_b   = (const float*)d_in[12];
  const float* fc2_w  = (const float*)d_in[13];
  const float* fc2_b  = (const float*)d_in[14];
  const float* lnf_w  = (const float*)d_in[15];
  const float* lnf_b  = (const float*)d_in[16];
  const float* head_w = (const float*)d_in[17];
  (void)in_sizes; (void)n_in; (void)out_size; (void)ws_size;

  char* base = (char*)d_ws;
  size_t off = 0;
  auto alloc = [&](size_t bytes) -> void* {
    void* p = base + off;
    off = (off + bytes + 255) & ~(size_t)255;
    return p;
  };
  bf16* wt_qkv  = (bf16*)alloc((size_t)NL * 3 * C * C * 2);
  bf16* wt_proj = (bf16*)alloc((size_t)NL * C * C * 2);
  bf16* wt_fc   = (bf16*)alloc((size_t)NL * 4 * C * C * 2);
  bf16* wt_fc2  = (bf16*)alloc((size_t)NL * 4 * C * C * 2);
  bf16* wt_head = (bf16*)alloc((size_t)V * C * 2);
  float* x      = (float*)alloc((size_t)BTOK * C * 4);   // absorbs head OOB reads
  bf16*  xb     = (bf16*)alloc((size_t)BTOK * C * 2);
  bf16*  qb     = (bf16*)alloc((size_t)NB * NH * T * DH * 2);
  bf16*  kb     = (bf16*)alloc((size_t)NB * NH * T * DH * 2);
  bf16*  vtb    = (bf16*)alloc((size_t)NB * NH * T * DH * 2);
  bf16*  yb     = (bf16*)alloc((size_t)BTOK * C * 2);
  bf16*  mbuf   = (bf16*)alloc((size_t)BTOK * 4 * C * 2);

  dim3 tb(32, 8);
  k_transpose_bf16<<<dim3(72, 24, NL), tb, 0, stream>>>(qkv_w, wt_qkv, C, 3 * C);
  k_transpose_bf16<<<dim3(24, 24, NL), tb, 0, stream>>>(proj_w, wt_proj, C, C);
  k_transpose_bf16<<<dim3(96, 24, NL), tb, 0, stream>>>(fc_w, wt_fc, C, 4 * C);
  k_transpose_bf16<<<dim3(24, 96, NL), tb, 0, stream>>>(fc2_w, wt_fc2, 4 * C, C);
  k_transpose_bf16<<<dim3((V + 31) / 32, 24, 1), tb, 0, stream>>>(head_w, wt_head, C, V);

  k_embed<<<BTOK * C / 256, 256, 0, stream>>>(idx, wte, wpe, x);

  for (int l = 0; l < NL; l++) {
    k_layernorm<<<BTOK, 256, 0, stream>>>(x, ln1_w + l * C, ln1_b + l * C, xb);
    k_gemm_s<5><<<dim3(32, 18), 256, 0, stream>>>(xb, wt_qkv + (long)l * 3 * C * C,
        qkv_b + l * 3 * C, qb, BTOK, 3 * C, C, C, C, 0, kb, vtb);
    k_attn<<<dim3(T / 128, NB * NH, 2), 256, 0, stream>>>(qb, kb, vtb, yb);
    k_gemm_s<3><<<dim3(32, 6), 256, 0, stream>>>(yb, wt_proj + (long)l * C * C,
        proj_b + l * C, x, BTOK, C, C, C, C, C, nullptr, nullptr);
    k_layernorm<<<BTOK, 256, 0, stream>>>(x, ln2_w + l * C, ln2_b + l * C, xb);
    k_gemm_s<2><<<dim3(32, 24), 256, 0, stream>>>(xb, wt_fc + (long)l * 4 * C * C,
        fc_b + l * 4 * C, mbuf, BTOK, 4 * C, C, C, C, 4 * C, nullptr, nullptr);
    k_gemm_s<3><<<dim3(32, 6), 256, 0, stream>>>(mbuf, wt_fc2 + (long)l * 4 * C * C,
        fc2_b + l * C, x, BTOK, C, 4 * C, 4 * C, 4 * C, C, nullptr, nullptr);
  }
  k_layernorm<<<BTOK, 256, 0, stream>>>(x, lnf_w, lnf_b, xb);
  k_gemm_b<<<dim3(16, (V + 127) / 128), 256, 0, stream>>>(xb, wt_head, (float*)d_out, V);
}

// Round 10
// 1006.703 us; speedup vs baseline: 1.7643x; 1.0526x over previous
//
#include <hip/hip_runtime.h>
#include <hip/hip_bf16.h>

typedef __hip_bfloat16 bf16;
typedef __attribute__((ext_vector_type(8))) short bf16x8;
typedef __attribute__((ext_vector_type(4))) float f32x4;
typedef __attribute__((ext_vector_type(4), aligned(4))) float f32x4u;  // unaligned-safe

#define NL 4
#define NH 12
#define C 768
#define T 1024
#define NB 2
#define BTOK 2048
#define V 50257
#define DH 64

__device__ __forceinline__ void gload16(const void* g, void* l) {
  __builtin_amdgcn_global_load_lds(
      (const __attribute__((address_space(1))) void*)g,
      (__attribute__((address_space(3))) void*)l, 16, 0, 0);
}

// ---------------- block reductions (256 threads = 4 waves) ----------------
__device__ __forceinline__ float block_sum(float v, float* red) {
#pragma unroll
  for (int off = 32; off; off >>= 1) v += __shfl_down(v, off);
  int lane = threadIdx.x & 63, wid = threadIdx.x >> 6;
  __syncthreads();
  if (lane == 0) red[wid] = v;
  __syncthreads();
  return red[0] + red[1] + red[2] + red[3];
}

// ---------------- embedding ----------------
__global__ __launch_bounds__(256) void k_embed(const int* __restrict__ idx,
    const float* __restrict__ wte, const float* __restrict__ wpe,
    float* __restrict__ x) {
  long i = (long)blockIdx.x * 256 + threadIdx.x;  // over BTOK*C (exact)
  int bt = (int)(i / C), c = (int)(i % C);
  int t = bt & (T - 1);
  x[i] = wte[(long)idx[bt] * C + c] + wpe[(long)t * C + c];
}

// ---------------- fp32 -> bf16 transposed weight convert ----------------
__global__ __launch_bounds__(256) void k_transpose_bf16(const float* __restrict__ W,
    bf16* __restrict__ Wt, int K, int N) {
  __shared__ float tile[32][33];
  long zoff = (long)blockIdx.z * K * N;
  W += zoff;
  Wt += zoff;
  int n0 = blockIdx.x * 32, k0 = blockIdx.y * 32;
  int tx = threadIdx.x, ty = threadIdx.y;
#pragma unroll
  for (int i = 0; i < 4; i++) {
    int k = k0 + ty + i * 8, n = n0 + tx;
    if (k < K && n < N) tile[ty + i * 8][tx] = W[(long)k * N + n];
  }
  __syncthreads();
#pragma unroll
  for (int i = 0; i < 4; i++) {
    int n = n0 + ty + i * 8, k = k0 + tx;
    if (n < N && k < K) Wt[(long)n * K + k] = __float2bfloat16(tile[tx][ty + i * 8]);
  }
}

// ---------------- layernorm: fp32 in -> bf16 out ----------------
__global__ __launch_bounds__(256) void k_layernorm(const float* __restrict__ x,
    const float* __restrict__ w, const float* __restrict__ b, bf16* __restrict__ out) {
  __shared__ float red[4];
  long row = blockIdx.x;
  const float* xr = x + row * C;
  int t = threadIdx.x;
  float v0 = xr[t], v1 = xr[t + 256], v2 = xr[t + 512];
  float s = block_sum(v0 + v1 + v2, red);
  float mu = s * (1.0f / C);
  float d0 = v0 - mu, d1 = v1 - mu, d2 = v2 - mu;
  float vs = block_sum(d0 * d0 + d1 * d1 + d2 * d2, red);
  float inv = rsqrtf(vs * (1.0f / C) + 1e-5f);
  bf16* orow = out + row * C;
  orow[t]       = __float2bfloat16(d0 * inv * w[t]       + b[t]);
  orow[t + 256] = __float2bfloat16(d1 * inv * w[t + 256] + b[t + 256]);
  orow[t + 512] = __float2bfloat16(d2 * inv * w[t + 512] + b[t + 512]);
}

// ---------------- fused causal flash attention (balanced pairs, z-split) ----
// grid (8, NB*NH, 2): block (p, bh, z) handles qt = z ? 15-p : p
__global__ __launch_bounds__(256) void k_attn(const bf16* __restrict__ q,
    const bf16* __restrict__ k, const bf16* __restrict__ vt,
    bf16* __restrict__ yb) {
  __shared__ __align__(16) bf16 Pl[4][16][72];  // per-wave P tile, +8 pad
  int pr = blockIdx.x, bh = blockIdx.y;
  int b = bh / NH, h = bh % NH;
  int tid = threadIdx.x, w = tid >> 6, lane = tid & 63;
  int l15 = lane & 15, hi = lane >> 4;
  const bf16* qbase = q + (long)bh * T * DH;
  const bf16* kbase = k + (long)bh * T * DH;
  const bf16* vbase = vt + (long)bh * DH * T;

  int qt = blockIdx.z ? (T / 64 - 1 - pr) : pr;
  int qrow = qt * 64 + w * 16 + l15;  // softmax-layout q (col of S^T)
  bf16x8 qf0 = *(const bf16x8*)(qbase + (long)qrow * DH + hi * 8);
  bf16x8 qf1 = *(const bf16x8*)(qbase + (long)qrow * DH + 32 + hi * 8);

  f32x4 accy[4] = {};               // y: row q=hi*4+rr, col d=j*16+l15
  float m_run = -1e30f, l_run = 0.f;

  int nkt = qt + 1;
  for (int kt = 0; kt < nkt; kt++) {
    int kv0 = kt * 64;
    f32x4 accs[4] = {};
#pragma unroll
    for (int kvi = 0; kvi < 4; kvi++) {
      const bf16* kr = kbase + (long)(kv0 + kvi * 16 + l15) * DH + hi * 8;
      bf16x8 kf0 = *(const bf16x8*)kr;
      bf16x8 kf1 = *(const bf16x8*)(kr + 32);
      accs[kvi] = __builtin_amdgcn_mfma_f32_16x16x32_bf16(kf0, qf0, accs[kvi], 0, 0, 0);
      accs[kvi] = __builtin_amdgcn_mfma_f32_16x16x32_bf16(kf1, qf1, accs[kvi], 0, 0, 0);
    }
    bool diag = (kt == qt);
    float p[4][4];
    float tmax = -1e30f;
#pragma unroll
    for (int kvi = 0; kvi < 4; kvi++)
#pragma unroll
      for (int rr = 0; rr < 4; rr++) {
        float s = accs[kvi][rr];
        if (diag && (kvi * 16 + hi * 4 + rr > w * 16 + l15)) s = -1e30f;
        p[kvi][rr] = s;
        tmax = fmaxf(tmax, s);
      }
    tmax = fmaxf(tmax, __shfl_xor(tmax, 16));
    tmax = fmaxf(tmax, __shfl_xor(tmax, 32));
    float m_new = fmaxf(m_run, tmax);
    float scl = __expf(m_run - m_new);
    float psum = 0.f;
#pragma unroll
    for (int kvi = 0; kvi < 4; kvi++)
#pragma unroll
      for (int rr = 0; rr < 4; rr++) {
        float e = __expf(p[kvi][rr] - m_new);
        p[kvi][rr] = e;
        psum += e;
      }
    psum += __shfl_xor(psum, 16);
    psum += __shfl_xor(psum, 32);
    l_run = l_run * scl + psum;
    m_run = m_new;
#pragma unroll
    for (int rr = 0; rr < 4; rr++) {
      float sy = __shfl(scl, hi * 4 + rr);
#pragma unroll
      for (int j = 0; j < 4; j++) accy[j][rr] *= sy;
    }
#pragma unroll
    for (int kvi = 0; kvi < 4; kvi++) {
      union { bf16 hh[2]; unsigned u; } pk0, pk1;
      pk0.hh[0] = __float2bfloat16(p[kvi][0]);
      pk0.hh[1] = __float2bfloat16(p[kvi][1]);
      pk1.hh[0] = __float2bfloat16(p[kvi][2]);
      pk1.hh[1] = __float2bfloat16(p[kvi][3]);
      *(unsigned*)&Pl[w][l15][kvi * 16 + hi * 4]     = pk0.u;
      *(unsigned*)&Pl[w][l15][kvi * 16 + hi * 4 + 2] = pk1.u;
    }
#pragma unroll
    for (int c = 0; c < 2; c++) {
      bf16x8 pf = *(const bf16x8*)&Pl[w][l15][c * 32 + hi * 8];
#pragma unroll
      for (int j = 0; j < 4; j++) {
        const bf16* vr = vbase + (long)(j * 16 + l15) * T + kv0 + c * 32 + hi * 8;
        bf16x8 vf = *(const bf16x8*)vr;
        accy[j] = __builtin_amdgcn_mfma_f32_16x16x32_bf16(pf, vf, accy[j], 0, 0, 0);
      }
    }
  }
  float inv = 1.0f / l_run;
#pragma unroll
  for (int rr = 0; rr < 4; rr++) {
    float li = __shfl(inv, hi * 4 + rr);
    int qg = qt * 64 + w * 16 + hi * 4 + rr;
#pragma unroll
    for (int j = 0; j < 4; j++)
      yb[((long)(b * T + qg)) * C + h * DH + j * 16 + l15] =
          __float2bfloat16(accy[j][rr] * li);
  }
}

// ================= 8-phase 256x256 head GEMM (M=2048,N=V,K=768) ============
__global__ __launch_bounds__(512, 1) void k_head(const bf16* __restrict__ A,
    const bf16* __restrict__ B, float* __restrict__ Cv) {
  __shared__ __align__(16) char lds[131072];
  int hw = blockIdx.y * 8 + blockIdx.x;          // grid (8, 197), nwg=1576
  int L = (hw & 7) * 197 + (hw >> 3);            // bijective XCD chunk
  int mt = L & 7, nt = L >> 3;
  int m0 = mt * 256, n0 = nt * 256;
  int tid = threadIdx.x, lane = tid & 63, wid = tid >> 6;
  int wm = wid >> 2, wn = wid & 3;
  int l15 = lane & 15, hi = lane >> 4, l7 = lane & 7;
  int sg = (lane & 7) ^ (lane >> 3);             // pre-swizzled src granule
  int srA = wid * 8 + (lane >> 3);               // staging row
  const bf16* Ab = A + (long)(m0 + srA) * 768 + sg * 8;
  const bf16* Bb = B + (long)(n0 + srA) * 768 + sg * 8;  // OOB tail lands in ws
  auto STAGE = [&](int tile, int h) {            // h: 0=A0 1=A1 2=B0 3=B1
    char* dst = lds + (tile & 1) * 65536 + h * 16384 + wid * 1024;
    const bf16* src = (h < 2 ? Ab : Bb) + (long)((h & 1) * 128) * 768 + tile * 64;
    gload16(src, dst);
    gload16(src + 64 * 768, dst + 8192);
  };
  f32x4 acc[8][4] = {};
  STAGE(0, 0); STAGE(0, 1); STAGE(0, 2); STAGE(0, 3); STAGE(1, 0);
  asm volatile("s_waitcnt vmcnt(2)" ::: "memory");
  __builtin_amdgcn_s_barrier();
  int bro = (wn & 1) * 64;
  int g0 = (hi ^ l7) * 16, g1 = ((4 + hi) ^ l7) * 16;
  for (int t = 0; t < 12; t++) {
    char* ha = lds + (t & 1) * 65536 + wm * 16384;
    char* hb = lds + (t & 1) * 65536 + 32768 + (wn >> 1) * 16384;
    bf16x8 af[4], bv[4];
#pragma unroll
    for (int mf = 0; mf < 4; mf++)
      af[mf] = *(const bf16x8*)(ha + (mf * 16 + l15) * 128 + g0);
#pragma unroll
    for (int nf = 0; nf < 4; nf++)
      bv[nf] = *(const bf16x8*)(hb + (bro + nf * 16 + l15) * 128 + g0);
    if (t + 1 < 12) { STAGE(t + 1, 1); STAGE(t + 1, 2); }
    __builtin_amdgcn_s_barrier();
    __builtin_amdgcn_s_setprio(1);
#pragma unroll
    for (int mf = 0; mf < 4; mf++)
#pragma unroll
      for (int nf = 0; nf < 4; nf++)
        acc[mf][nf] = __builtin_amdgcn_mfma_f32_16x16x32_bf16(af[mf], bv[nf], acc[mf][nf], 0, 0, 0);
    __builtin_amdgcn_s_setprio(0);
    __builtin_amdgcn_s_barrier();
#pragma unroll
    for (int mf = 0; mf < 4; mf++)
      af[mf] = *(const bf16x8*)(ha + ((mf + 4) * 16 + l15) * 128 + g0);
    if (t + 1 < 12) STAGE(t + 1, 3);
    __builtin_amdgcn_s_barrier();
    __builtin_amdgcn_s_setprio(1);
#pragma unroll
    for (int mf = 0; mf < 4; mf++)
#pragma unroll
      for (int nf = 0; nf < 4; nf++)
        acc[mf + 4][nf] = __builtin_amdgcn_mfma_f32_16x16x32_bf16(af[mf], bv[nf], acc[mf + 4][nf], 0, 0, 0);
    __builtin_amdgcn_s_setprio(0);
    __builtin_amdgcn_s_barrier();
#pragma unroll
    for (int mf = 0; mf < 4; mf++)
      af[mf] = *(const bf16x8*)(ha + (mf * 16 + l15) * 128 + g1);
#pragma unroll
    for (int nf = 0; nf < 4; nf++)
      bv[nf] = *(const bf16x8*)(hb + (bro + nf * 16 + l15) * 128 + g1);
    __builtin_amdgcn_s_barrier();
    __builtin_amdgcn_s_setprio(1);
#pragma unroll
    for (int mf = 0; mf < 4; mf++)
#pragma unroll
      for (int nf = 0; nf < 4; nf++)
        acc[mf][nf] = __builtin_amdgcn_mfma_f32_16x16x32_bf16(af[mf], bv[nf], acc[mf][nf], 0, 0, 0);
    __builtin_amdgcn_s_setprio(0);
    __builtin_amdgcn_s_barrier();
#pragma unroll
    for (int mf = 0; mf < 4; mf++)
      af[mf] = *(const bf16x8*)(ha + ((mf + 4) * 16 + l15) * 128 + g1);
    if (t + 2 < 12) STAGE(t + 2, 0);
    __builtin_amdgcn_s_barrier();
    __builtin_amdgcn_s_setprio(1);
#pragma unroll
    for (int mf = 0; mf < 4; mf++)
#pragma unroll
      for (int nf = 0; nf < 4; nf++)
        acc[mf + 4][nf] = __builtin_amdgcn_mfma_f32_16x16x32_bf16(af[mf], bv[nf], acc[mf + 4][nf], 0, 0, 0);
    __builtin_amdgcn_s_setprio(0);
    if (t < 11) {
      if (t + 2 < 12) asm volatile("s_waitcnt vmcnt(2)" ::: "memory");
      else            asm volatile("s_waitcnt vmcnt(0)" ::: "memory");
      __builtin_amdgcn_s_barrier();
    }
  }
  // ---- epilogue: 2 mf-slices per LDS round ([64][260] f32 = 66.6 KB) ----
  __syncthreads();
  float* Cst = (float*)lds;
#pragma unroll
  for (int rnd = 0; rnd < 4; rnd++) {
#pragma unroll
    for (int mfl = 0; mfl < 2; mfl++) {
      int mf = rnd * 2 + mfl;
#pragma unroll
      for (int nf = 0; nf < 4; nf++)
#pragma unroll
        for (int rr = 0; rr < 4; rr++)
          Cst[(wm * 32 + mfl * 16 + hi * 4 + rr) * 260 + wn * 64 + nf * 16 + l15] =
              acc[mf][nf][rr];
    }
    __syncthreads();
#pragma unroll
    for (int s = 0; s < 8; s++) {
      int gid = tid + s * 512;           // 0..4095
      int r = gid >> 6, g = gid & 63;    // row 0..63, 4-col granule
      int grow = m0 + (r >> 5) * 128 + (rnd * 2 + ((r >> 4) & 1)) * 16 + (r & 15);
      int gcol = n0 + g * 4;
      f32x4 vv = *(const f32x4*)&Cst[r * 260 + g * 4];
      float* dst = Cv + (long)grow * V + gcol;
      if (gcol + 3 < V) {
        *(f32x4u*)dst = vv;
      } else {
#pragma unroll
        for (int e = 0; e < 4; e++)
          if (gcol + e < V) dst[e] = vv[e];
      }
    }
    __syncthreads();
  }
}

// ------- layer GEMM: BM=64, BN=128, BK=64, depth-2 pipeline, XCD swizzle ----
// LDS[row][g] holds global granule g^(row&7); write linear, read XOR.
// EPI 2: bf16 out, gelu(acc+bias). EPI 3: fp32 residual in-place.
// EPI 5: qkv split-repack: Cv=q (scaled 0.125), Cv2=k, Cv3=vt.
#define SBK 64
template <int EPI>
__global__ __launch_bounds__(256) void k_gemm_s(const bf16* __restrict__ A,
    const bf16* __restrict__ B, const float* __restrict__ bias,
    void* __restrict__ Cv, int M, int N, int K, int lda, int ldb, int ldc,
    void* __restrict__ Cv2, void* __restrict__ Cv3) {
  __shared__ __align__(16) bf16 As[2][64][SBK];   // 16 KiB
  __shared__ __align__(16) bf16 Bs[2][128][SBK];  // 32 KiB
  int nwg = gridDim.x * gridDim.y;
  int hw = blockIdx.y * gridDim.x + blockIdx.x;
  int logical = (hw & 7) * (nwg >> 3) + (hw >> 3);
  int bx = logical % gridDim.x, by = logical / gridDim.x;
  int m0 = bx * 64, n0 = by * 128;
  int tid = threadIdx.x;
  int lane = tid & 63, w = tid >> 6;
  int l15 = lane & 15, hi = lane >> 4, l7 = lane & 7;
  int srow = lane >> 3;                 // 0..7
  int sgr = lane & 7;
  int scol = ((sgr ^ srow) << 3);       // pre-swizzled source col (elements)
  f32x4 acc[4][2] = {};
  const bf16* Ag = A + (long)(m0 + w * 8 + srow) * lda + scol;
  const bf16* Bg = B + (long)(n0 + w * 8 + srow) * ldb + scol;
  int NT = K / SBK;
  auto STAGE = [&](int t) {
    int k0 = t * SBK, b = t & 1;
    gload16(Ag + k0,            &As[b][w * 8][0]);
    gload16(Ag + k0 + 32 * lda, &As[b][w * 8 + 32][0]);
    gload16(Bg + k0,            &Bs[b][w * 8][0]);
    gload16(Bg + k0 + 32 * ldb, &Bs[b][w * 8 + 32][0]);
    gload16(Bg + k0 + 64 * ldb, &Bs[b][w * 8 + 64][0]);
    gload16(Bg + k0 + 96 * ldb, &Bs[b][w * 8 + 96][0]);
  };
  STAGE(0);
  STAGE(1);
  int c0 = (hi ^ l7) << 3, c1 = ((4 + hi) ^ l7) << 3;  // kk0/kk1 read cols
  for (int t = 0; t < NT; t++) {
    int b = t & 1;
    if (t + 1 < NT) asm volatile("s_waitcnt vmcnt(6)" ::: "memory");
    else            asm volatile("s_waitcnt vmcnt(0)" ::: "memory");
    __builtin_amdgcn_s_barrier();
    bf16x8 a0[4], a1[4], b0[2], b1[2];
#pragma unroll
    for (int i = 0; i < 4; i++) {
      a0[i] = *(const bf16x8*)&As[b][i * 16 + l15][c0];
      a1[i] = *(const bf16x8*)&As[b][i * 16 + l15][c1];
    }
#pragma unroll
    for (int j = 0; j < 2; j++) {
      b0[j] = *(const bf16x8*)&Bs[b][w * 32 + j * 16 + l15][c0];
      b1[j] = *(const bf16x8*)&Bs[b][w * 32 + j * 16 + l15][c1];
    }
    asm volatile("s_waitcnt lgkmcnt(0)" ::: "memory");
    __builtin_amdgcn_s_barrier();
    if (t + 2 < NT) STAGE(t + 2);
    __builtin_amdgcn_s_setprio(1);
#pragma unroll
    for (int i = 0; i < 4; i++)
#pragma unroll
      for (int j = 0; j < 2; j++) {
        acc[i][j] = __builtin_amdgcn_mfma_f32_16x16x32_bf16(a0[i], b0[j], acc[i][j], 0, 0, 0);
        acc[i][j] = __builtin_amdgcn_mfma_f32_16x16x32_bf16(a1[i], b1[j], acc[i][j], 0, 0, 0);
      }
    __builtin_amdgcn_s_setprio(0);
  }
#pragma unroll
  for (int j = 0; j < 2; j++) {
    int gn = n0 + w * 32 + j * 16 + l15;
    float bv = bias[gn];
#pragma unroll
    for (int i = 0; i < 4; i++)
#pragma unroll
      for (int rr = 0; rr < 4; rr++) {
        int gm = m0 + i * 16 + hi * 4 + rr;
        float v = acc[i][j][rr] + bv;
        if constexpr (EPI == 3) {
          long off = (long)gm * ldc + gn;
          ((float*)Cv)[off] = v + ((float*)Cv)[off];
        } else if constexpr (EPI == 2) {
          float u = 0.7978845608028654f * (v + 0.044715f * v * v * v);
          u = fminf(fmaxf(u, -15.f), 15.f);
          float e2 = __expf(2.f * u);
          float th = (e2 - 1.f) / (e2 + 1.f);
          ((bf16*)Cv)[(long)gm * ldc + gn] = __float2bfloat16(0.5f * v * (1.f + th));
        } else if constexpr (EPI == 5) {
          int gb = gm >> 10, gt = gm & 1023;
          int which = gn / C;
          int r = gn - which * C;
          int h = r >> 6, d = r & 63;
          long bh = (long)(gb * NH + h);
          if (which == 0)
            ((bf16*)Cv)[(bh * T + gt) * DH + d] = __float2bfloat16(v * 0.125f);
          else if (which == 1)
            ((bf16*)Cv2)[(bh * T + gt) * DH + d] = __float2bfloat16(v);
          else
            ((bf16*)Cv3)[(bh * DH + d) * T + gt] = __float2bfloat16(v);
        }
      }
  }
}

extern "C" void kernel_launch(void* const* d_in, const int* in_sizes, int n_in,
                              void* d_out, int out_size, void* d_ws, size_t ws_size,
                              hipStream_t stream) {
  const int*   idx    = (const int*)d_in[0];
  const float* wte    = (const float*)d_in[1];
  const float* wpe    = (const float*)d_in[2];
  const float* ln1_w  = (const float*)d_in[3];
  const float* ln1_b  = (const float*)d_in[4];
  const float* qkv_w  = (const float*)d_in[5];
  const float* qkv_b  = (const float*)d_in[6];
  const float* proj_w = (const float*)d_in[7];
  const float* proj_b = (const float*)d_in[8];
  const float* ln2_w  = (const float*)d_in[9];
  const float* ln2_b  = (const float*)d_in[10];
  const float* fc_w   = (const float*)d_in[11];
  const float* fc_b   = (const float*)d_in[12];
  const float* fc2_w  = (const float*)d_in[13];
  const float* fc2_b  = (const float*)d_in[14];
  const float* lnf_w  = (const float*)d_in[15];
  const float* lnf_b  = (const float*)d_in[16];
  const float* head_w = (const float*)d_in[17];
  (void)in_sizes; (void)n_in; (void)out_size; (void)ws_size;

  char* base = (char*)d_ws;
  size_t off = 0;
  auto alloc = [&](size_t bytes) -> void* {
    void* p = base + off;
    off = (off + bytes + 255) & ~(size_t)255;
    return p;
  };
  bf16* wt_qkv  = (bf16*)alloc((size_t)NL * 3 * C * C * 2);
  bf16* wt_proj = (bf16*)alloc((size_t)NL * C * C * 2);
  bf16* wt_fc   = (bf16*)alloc((size_t)NL * 4 * C * C * 2);
  bf16* wt_fc2  = (bf16*)alloc((size_t)NL * 4 * C * C * 2);
  bf16* wt_head = (bf16*)alloc((size_t)V * C * 2);
  float* x      = (float*)alloc((size_t)BTOK * C * 4);   // absorbs head OOB reads
  bf16*  xb     = (bf16*)alloc((size_t)BTOK * C * 2);
  bf16*  qb     = (bf16*)alloc((size_t)NB * NH * T * DH * 2);
  bf16*  kb     = (bf16*)alloc((size_t)NB * NH * T * DH * 2);
  bf16*  vtb    = (bf16*)alloc((size_t)NB * NH * T * DH * 2);
  bf16*  yb     = (bf16*)alloc((size_t)BTOK * C * 2);
  bf16*  mbuf   = (bf16*)alloc((size_t)BTOK * 4 * C * 2);

  dim3 tb(32, 8);
  k_transpose_bf16<<<dim3(72, 24, NL), tb, 0, stream>>>(qkv_w, wt_qkv, C, 3 * C);
  k_transpose_bf16<<<dim3(24, 24, NL), tb, 0, stream>>>(proj_w, wt_proj, C, C);
  k_transpose_bf16<<<dim3(96, 24, NL), tb, 0, stream>>>(fc_w, wt_fc, C, 4 * C);
  k_transpose_bf16<<<dim3(24, 96, NL), tb, 0, stream>>>(fc2_w, wt_fc2, 4 * C, C);
  k_transpose_bf16<<<dim3((V + 31) / 32, 24, 1), tb, 0, stream>>>(head_w, wt_head, C, V);

  k_embed<<<BTOK * C / 256, 256, 0, stream>>>(idx, wte, wpe, x);

  for (int l = 0; l < NL; l++) {
    k_layernorm<<<BTOK, 256, 0, stream>>>(x, ln1_w + l * C, ln1_b + l * C, xb);
    k_gemm_s<5><<<dim3(32, 18), 256, 0, stream>>>(xb, wt_qkv + (long)l * 3 * C * C,
        qkv_b + l * 3 * C, qb, BTOK, 3 * C, C, C, C, 0, kb, vtb);
    k_attn<<<dim3(T / 128, NB * NH, 2), 256, 0, stream>>>(qb, kb, vtb, yb);
    k_gemm_s<3><<<dim3(32, 6), 256, 0, stream>>>(yb, wt_proj + (long)l * C * C,
        proj_b + l * C, x, BTOK, C, C, C, C, C, nullptr, nullptr);
    k_layernorm<<<BTOK, 256, 0, stream>>>(x, ln2_w + l * C, ln2_b + l * C, xb);
    k_gemm_s<2><<<dim3(32, 24), 256, 0, stream>>>(xb, wt_fc + (long)l * 4 * C * C,
        fc_b + l * 4 * C, mbuf, BTOK, 4 * C, C, C, C, 4 * C, nullptr, nullptr);
    k_gemm_s<3><<<dim3(32, 6), 256, 0, stream>>>(mbuf, wt_fc2 + (long)l * 4 * C * C,
        fc2_b + l * C, x, BTOK, C, 4 * C, 4 * C, 4 * C, C, nullptr, nullptr);
  }
  k_layernorm<<<BTOK, 256, 0, stream>>>(x, lnf_w, lnf_b, xb);
  k_head<<<dim3(8, 197), 512, 0, stream>>>(xb, wt_head, (float*)d_out);
}

// Round 11
// 986.042 us; speedup vs baseline: 1.8013x; 1.0210x over previous
//
#include <hip/hip_runtime.h>
#include <hip/hip_bf16.h>

typedef __hip_bfloat16 bf16;
typedef __attribute__((ext_vector_type(8))) short bf16x8;
typedef __attribute__((ext_vector_type(4))) float f32x4;
typedef __attribute__((ext_vector_type(4), aligned(4))) float f32x4u;  // unaligned-safe

#define NL 4
#define NH 12
#define C 768
#define T 1024
#define NB 2
#define BTOK 2048
#define V 50257
#define DH 64

__device__ __forceinline__ void gload16(const void* g, void* l) {
  __builtin_amdgcn_global_load_lds(
      (const __attribute__((address_space(1))) void*)g,
      (__attribute__((address_space(3))) void*)l, 16, 0, 0);
}

// ---------------- block reductions (256 threads = 4 waves) ----------------
__device__ __forceinline__ float block_sum(float v, float* red) {
#pragma unroll
  for (int off = 32; off; off >>= 1) v += __shfl_down(v, off);
  int lane = threadIdx.x & 63, wid = threadIdx.x >> 6;
  __syncthreads();
  if (lane == 0) red[wid] = v;
  __syncthreads();
  return red[0] + red[1] + red[2] + red[3];
}

// ---------------- fp32 -> bf16 transposed weight convert (64x64 tiles) -----
// read: float4/lane coalesced; write: bf16x8/lane coalesced. K%64==0 required.
__global__ __launch_bounds__(256) void k_transpose_bf16(const float* __restrict__ W,
    bf16* __restrict__ Wt, int K, int N) {
  __shared__ float tile[64][69];  // pad 69: write-phase col reads 2-way (free)
  long zoff = (long)blockIdx.z * K * N;
  W += zoff;
  Wt += zoff;
  int k0 = blockIdx.x * 64, n0 = blockIdx.y * 64;
  int tid = threadIdx.x;
  int rr = tid >> 4, rc = (tid & 15) * 4;
#pragma unroll
  for (int it = 0; it < 4; it++) {
    int k = it * 16 + rr;
    int gn = n0 + rc;
    const float* src = W + (long)(k0 + k) * N + gn;
    if (gn + 3 < N) {
      f32x4 v = *(const f32x4u*)src;
      tile[k][rc] = v[0]; tile[k][rc + 1] = v[1];
      tile[k][rc + 2] = v[2]; tile[k][rc + 3] = v[3];
    } else {
#pragma unroll
      for (int e = 0; e < 4; e++)
        tile[k][rc + e] = (gn + e < N) ? src[e] : 0.0f;
    }
  }
  __syncthreads();
  int wkc = tid & 7;
#pragma unroll
  for (int it = 0; it < 2; it++) {
    int n = it * 32 + (tid >> 3);
    int gn = n0 + n;
    if (gn < N) {
      union { bf16 h[8]; bf16x8 v; } u;
#pragma unroll
      for (int j = 0; j < 8; j++)
        u.h[j] = __float2bfloat16(tile[wkc * 8 + j][n]);
      *(bf16x8*)&Wt[(long)gn * K + k0 + wkc * 8] = u.v;
    }
  }
}

// ---------------- layernorm: fp32 in -> bf16 out ----------------
__global__ __launch_bounds__(256) void k_layernorm(const float* __restrict__ x,
    const float* __restrict__ w, const float* __restrict__ b, bf16* __restrict__ out) {
  __shared__ float red[4];
  long row = blockIdx.x;
  const float* xr = x + row * C;
  int t = threadIdx.x;
  float v0 = xr[t], v1 = xr[t + 256], v2 = xr[t + 512];
  float s = block_sum(v0 + v1 + v2, red);
  float mu = s * (1.0f / C);
  float d0 = v0 - mu, d1 = v1 - mu, d2 = v2 - mu;
  float vs = block_sum(d0 * d0 + d1 * d1 + d2 * d2, red);
  float inv = rsqrtf(vs * (1.0f / C) + 1e-5f);
  bf16* orow = out + row * C;
  orow[t]       = __float2bfloat16(d0 * inv * w[t]       + b[t]);
  orow[t + 256] = __float2bfloat16(d1 * inv * w[t + 256] + b[t + 256]);
  orow[t + 512] = __float2bfloat16(d2 * inv * w[t + 512] + b[t + 512]);
}

// ---------------- fused embed + layernorm (layer 0) ----------------
__global__ __launch_bounds__(256) void k_embed_ln(const int* __restrict__ idx,
    const float* __restrict__ wte, const float* __restrict__ wpe,
    const float* __restrict__ w, const float* __restrict__ b,
    float* __restrict__ x, bf16* __restrict__ out) {
  __shared__ float red[4];
  long row = blockIdx.x;
  int t = threadIdx.x;
  int tok = idx[row];
  int pos = (int)(row & (T - 1));
  const float* we = wte + (long)tok * C;
  const float* pe = wpe + (long)pos * C;
  float v0 = we[t] + pe[t], v1 = we[t + 256] + pe[t + 256], v2 = we[t + 512] + pe[t + 512];
  float* xr = x + row * C;
  xr[t] = v0; xr[t + 256] = v1; xr[t + 512] = v2;
  float s = block_sum(v0 + v1 + v2, red);
  float mu = s * (1.0f / C);
  float d0 = v0 - mu, d1 = v1 - mu, d2 = v2 - mu;
  float vs = block_sum(d0 * d0 + d1 * d1 + d2 * d2, red);
  float inv = rsqrtf(vs * (1.0f / C) + 1e-5f);
  bf16* orow = out + row * C;
  orow[t]       = __float2bfloat16(d0 * inv * w[t]       + b[t]);
  orow[t + 256] = __float2bfloat16(d1 * inv * w[t + 256] + b[t + 256]);
  orow[t + 512] = __float2bfloat16(d2 * inv * w[t + 512] + b[t + 512]);
}

// ---------------- fused causal flash attention (balanced pairs, z-split) ----
// grid (8, NB*NH, 2): block (p, bh, z) handles qt = z ? 15-p : p
// T13 defer-max: skip O-rescale while per-tile max growth <= 8.
__global__ __launch_bounds__(256) void k_attn(const bf16* __restrict__ q,
    const bf16* __restrict__ k, const bf16* __restrict__ vt,
    bf16* __restrict__ yb) {
  __shared__ __align__(16) bf16 Pl[4][16][72];  // per-wave P tile, +8 pad
  int pr = blockIdx.x, bh = blockIdx.y;
  int b = bh / NH, h = bh % NH;
  int tid = threadIdx.x, w = tid >> 6, lane = tid & 63;
  int l15 = lane & 15, hi = lane >> 4;
  const bf16* qbase = q + (long)bh * T * DH;
  const bf16* kbase = k + (long)bh * T * DH;
  const bf16* vbase = vt + (long)bh * DH * T;

  int qt = blockIdx.z ? (T / 64 - 1 - pr) : pr;
  int qrow = qt * 64 + w * 16 + l15;  // softmax-layout q (col of S^T)
  bf16x8 qf0 = *(const bf16x8*)(qbase + (long)qrow * DH + hi * 8);
  bf16x8 qf1 = *(const bf16x8*)(qbase + (long)qrow * DH + 32 + hi * 8);

  f32x4 accy[4] = {};               // y: row q=hi*4+rr, col d=j*16+l15
  float m_run = -1e30f, l_run = 0.f;

  int nkt = qt + 1;
  for (int kt = 0; kt < nkt; kt++) {
    int kv0 = kt * 64;
    f32x4 accs[4] = {};
#pragma unroll
    for (int kvi = 0; kvi < 4; kvi++) {
      const bf16* kr = kbase + (long)(kv0 + kvi * 16 + l15) * DH + hi * 8;
      bf16x8 kf0 = *(const bf16x8*)kr;
      bf16x8 kf1 = *(const bf16x8*)(kr + 32);
      accs[kvi] = __builtin_amdgcn_mfma_f32_16x16x32_bf16(kf0, qf0, accs[kvi], 0, 0, 0);
      accs[kvi] = __builtin_amdgcn_mfma_f32_16x16x32_bf16(kf1, qf1, accs[kvi], 0, 0, 0);
    }
    bool diag = (kt == qt);
    float p[4][4];
    float tmax = -1e30f;
#pragma unroll
    for (int kvi = 0; kvi < 4; kvi++)
#pragma unroll
      for (int rr = 0; rr < 4; rr++) {
        float s = accs[kvi][rr];
        if (diag && (kvi * 16 + hi * 4 + rr > w * 16 + l15)) s = -1e30f;
        p[kvi][rr] = s;
        tmax = fmaxf(tmax, s);
      }
    tmax = fmaxf(tmax, __shfl_xor(tmax, 16));
    tmax = fmaxf(tmax, __shfl_xor(tmax, 32));
    if (!__all(tmax - m_run <= 8.0f)) {  // wave-uniform
      float m_new = fmaxf(m_run, tmax);
      float scl = __expf(m_run - m_new);
      l_run *= scl;
#pragma unroll
      for (int rr = 0; rr < 4; rr++) {
        float sy = __shfl(scl, hi * 4 + rr);
#pragma unroll
        for (int j = 0; j < 4; j++) accy[j][rr] *= sy;
      }
      m_run = m_new;
    }
    float psum = 0.f;
#pragma unroll
    for (int kvi = 0; kvi < 4; kvi++)
#pragma unroll
      for (int rr = 0; rr < 4; rr++) {
        float e = __expf(p[kvi][rr] - m_run);
        p[kvi][rr] = e;
        psum += e;
      }
    psum += __shfl_xor(psum, 16);
    psum += __shfl_xor(psum, 32);
    l_run += psum;
#pragma unroll
    for (int kvi = 0; kvi < 4; kvi++) {
      union { bf16 hh[2]; unsigned u; } pk0, pk1;
      pk0.hh[0] = __float2bfloat16(p[kvi][0]);
      pk0.hh[1] = __float2bfloat16(p[kvi][1]);
      pk1.hh[0] = __float2bfloat16(p[kvi][2]);
      pk1.hh[1] = __float2bfloat16(p[kvi][3]);
      *(unsigned*)&Pl[w][l15][kvi * 16 + hi * 4]     = pk0.u;
      *(unsigned*)&Pl[w][l15][kvi * 16 + hi * 4 + 2] = pk1.u;
    }
#pragma unroll
    for (int c = 0; c < 2; c++) {
      bf16x8 pf = *(const bf16x8*)&Pl[w][l15][c * 32 + hi * 8];
#pragma unroll
      for (int j = 0; j < 4; j++) {
        const bf16* vr = vbase + (long)(j * 16 + l15) * T + kv0 + c * 32 + hi * 8;
        bf16x8 vf = *(const bf16x8*)vr;
        accy[j] = __builtin_amdgcn_mfma_f32_16x16x32_bf16(pf, vf, accy[j], 0, 0, 0);
      }
    }
  }
  float inv = 1.0f / l_run;
#pragma unroll
  for (int rr = 0; rr < 4; rr++) {
    float li = __shfl(inv, hi * 4 + rr);
    int qg = qt * 64 + w * 16 + hi * 4 + rr;
#pragma unroll
    for (int j = 0; j < 4; j++)
      yb[((long)(b * T + qg)) * C + h * DH + j * 16 + l15] =
          __float2bfloat16(accy[j][rr] * li);
  }
}

// ================= 8-phase 256x256 head GEMM (M=2048,N=V,K=768) ============
__global__ __launch_bounds__(512, 1) void k_head(const bf16* __restrict__ A,
    const bf16* __restrict__ B, float* __restrict__ Cv) {
  __shared__ __align__(16) char lds[131072];
  int hw = blockIdx.y * 8 + blockIdx.x;          // grid (8, 197), nwg=1576
  int L = (hw & 7) * 197 + (hw >> 3);            // bijective XCD chunk
  int mt = L & 7, nt = L >> 3;
  int m0 = mt * 256, n0 = nt * 256;
  int tid = threadIdx.x, lane = tid & 63, wid = tid >> 6;
  int wm = wid >> 2, wn = wid & 3;
  int l15 = lane & 15, hi = lane >> 4, l7 = lane & 7;
  int sg = (lane & 7) ^ (lane >> 3);             // pre-swizzled src granule
  int srA = wid * 8 + (lane >> 3);               // staging row
  const bf16* Ab = A + (long)(m0 + srA) * 768 + sg * 8;
  const bf16* Bb = B + (long)(n0 + srA) * 768 + sg * 8;  // OOB tail lands in ws
  auto STAGE = [&](int tile, int h) {            // h: 0=A0 1=A1 2=B0 3=B1
    char* dst = lds + (tile & 1) * 65536 + h * 16384 + wid * 1024;
    const bf16* src = (h < 2 ? Ab : Bb) + (long)((h & 1) * 128) * 768 + tile * 64;
    gload16(src, dst);
    gload16(src + 64 * 768, dst + 8192);
  };
  f32x4 acc[8][4] = {};
  STAGE(0, 0); STAGE(0, 1); STAGE(0, 2); STAGE(0, 3); STAGE(1, 0);
  asm volatile("s_waitcnt vmcnt(2)" ::: "memory");
  __builtin_amdgcn_s_barrier();
  int bro = (wn & 1) * 64;
  int g0 = (hi ^ l7) * 16, g1 = ((4 + hi) ^ l7) * 16;
  for (int t = 0; t < 12; t++) {
    char* ha = lds + (t & 1) * 65536 + wm * 16384;
    char* hb = lds + (t & 1) * 65536 + 32768 + (wn >> 1) * 16384;
    bf16x8 af[4], bv[4];
#pragma unroll
    for (int mf = 0; mf < 4; mf++)
      af[mf] = *(const bf16x8*)(ha + (mf * 16 + l15) * 128 + g0);
#pragma unroll
    for (int nf = 0; nf < 4; nf++)
      bv[nf] = *(const bf16x8*)(hb + (bro + nf * 16 + l15) * 128 + g0);
    if (t + 1 < 12) { STAGE(t + 1, 1); STAGE(t + 1, 2); }
    __builtin_amdgcn_s_barrier();
    __builtin_amdgcn_s_setprio(1);
#pragma unroll
    for (int mf = 0; mf < 4; mf++)
#pragma unroll
      for (int nf = 0; nf < 4; nf++)
        acc[mf][nf] = __builtin_amdgcn_mfma_f32_16x16x32_bf16(af[mf], bv[nf], acc[mf][nf], 0, 0, 0);
    __builtin_amdgcn_s_setprio(0);
    __builtin_amdgcn_s_barrier();
#pragma unroll
    for (int mf = 0; mf < 4; mf++)
      af[mf] = *(const bf16x8*)(ha + ((mf + 4) * 16 + l15) * 128 + g0);
    if (t + 1 < 12) STAGE(t + 1, 3);
    __builtin_amdgcn_s_barrier();
    __builtin_amdgcn_s_setprio(1);
#pragma unroll
    for (int mf = 0; mf < 4; mf++)
#pragma unroll
      for (int nf = 0; nf < 4; nf++)
        acc[mf + 4][nf] = __builtin_amdgcn_mfma_f32_16x16x32_bf16(af[mf], bv[nf], acc[mf + 4][nf], 0, 0, 0);
    __builtin_amdgcn_s_setprio(0);
    __builtin_amdgcn_s_barrier();
#pragma unroll
    for (int mf = 0; mf < 4; mf++)
      af[mf] = *(const bf16x8*)(ha + (mf * 16 + l15) * 128 + g1);
#pragma unroll
    for (int nf = 0; nf < 4; nf++)
      bv[nf] = *(const bf16x8*)(hb + (bro + nf * 16 + l15) * 128 + g1);
    __builtin_amdgcn_s_barrier();
    __builtin_amdgcn_s_setprio(1);
#pragma unroll
    for (int mf = 0; mf < 4; mf++)
#pragma unroll
      for (int nf = 0; nf < 4; nf++)
        acc[mf][nf] = __builtin_amdgcn_mfma_f32_16x16x32_bf16(af[mf], bv[nf], acc[mf][nf], 0, 0, 0);
    __builtin_amdgcn_s_setprio(0);
    __builtin_amdgcn_s_barrier();
#pragma unroll
    for (int mf = 0; mf < 4; mf++)
      af[mf] = *(const bf16x8*)(ha + ((mf + 4) * 16 + l15) * 128 + g1);
    if (t + 2 < 12) STAGE(t + 2, 0);
    __builtin_amdgcn_s_barrier();
    __builtin_amdgcn_s_setprio(1);
#pragma unroll
    for (int mf = 0; mf < 4; mf++)
#pragma unroll
      for (int nf = 0; nf < 4; nf++)
        acc[mf + 4][nf] = __builtin_amdgcn_mfma_f32_16x16x32_bf16(af[mf], bv[nf], acc[mf + 4][nf], 0, 0, 0);
    __builtin_amdgcn_s_setprio(0);
    if (t < 11) {
      if (t + 2 < 12) asm volatile("s_waitcnt vmcnt(2)" ::: "memory");
      else            asm volatile("s_waitcnt vmcnt(0)" ::: "memory");
      __builtin_amdgcn_s_barrier();
    }
  }
  // ---- epilogue: 2 mf-slices per LDS round ([64][260] f32 = 66.6 KB) ----
  __syncthreads();
  float* Cst = (float*)lds;
#pragma unroll
  for (int rnd = 0; rnd < 4; rnd++) {
#pragma unroll
    for (int mfl = 0; mfl < 2; mfl++) {
      int mf = rnd * 2 + mfl;
#pragma unroll
      for (int nf = 0; nf < 4; nf++)
#pragma unroll
        for (int rr = 0; rr < 4; rr++)
          Cst[(wm * 32 + mfl * 16 + hi * 4 + rr) * 260 + wn * 64 + nf * 16 + l15] =
              acc[mf][nf][rr];
    }
    __syncthreads();
#pragma unroll
    for (int s = 0; s < 8; s++) {
      int gid = tid + s * 512;           // 0..4095
      int r = gid >> 6, g = gid & 63;    // row 0..63, 4-col granule
      int grow = m0 + (r >> 5) * 128 + (rnd * 2 + ((r >> 4) & 1)) * 16 + (r & 15);
      int gcol = n0 + g * 4;
      f32x4 vv = *(const f32x4*)&Cst[r * 260 + g * 4];
      float* dst = Cv + (long)grow * V + gcol;
      if (gcol + 3 < V) {
        *(f32x4u*)dst = vv;
      } else {
#pragma unroll
        for (int e = 0; e < 4; e++)
          if (gcol + e < V) dst[e] = vv[e];
      }
    }
    __syncthreads();
  }
}

// ------- layer GEMM: BM=64, BN=128, BK=64, depth-2 pipeline, XCD swizzle ----
// LDS[row][g] holds global granule g^(row&7); write linear, read XOR.
// EPI 2: bf16 out, gelu(acc+bias). EPI 3: fp32 residual in-place.
// EPI 5: qkv split-repack: Cv=q (scaled 0.125), Cv2=k, Cv3=vt.
#define SBK 64
template <int EPI>
__global__ __launch_bounds__(256) void k_gemm_s(const bf16* __restrict__ A,
    const bf16* __restrict__ B, const float* __restrict__ bias,
    void* __restrict__ Cv, int M, int N, int K, int lda, int ldb, int ldc,
    void* __restrict__ Cv2, void* __restrict__ Cv3) {
  __shared__ __align__(16) bf16 As[2][64][SBK];   // 16 KiB
  __shared__ __align__(16) bf16 Bs[2][128][SBK];  // 32 KiB
  int nwg = gridDim.x * gridDim.y;
  int hw = blockIdx.y * gridDim.x + blockIdx.x;
  int logical = (hw & 7) * (nwg >> 3) + (hw >> 3);
  int bx = logical % gridDim.x, by = logical / gridDim.x;
  int m0 = bx * 64, n0 = by * 128;
  int tid = threadIdx.x;
  int lane = tid & 63, w = tid >> 6;
  int l15 = lane & 15, hi = lane >> 4, l7 = lane & 7;
  int srow = lane >> 3;                 // 0..7
  int sgr = lane & 7;
  int scol = ((sgr ^ srow) << 3);       // pre-swizzled source col (elements)
  f32x4 acc[4][2] = {};
  const bf16* Ag = A + (long)(m0 + w * 8 + srow) * lda + scol;
  const bf16* Bg = B + (long)(n0 + w * 8 + srow) * ldb + scol;
  int NT = K / SBK;
  auto STAGE = [&](int t) {
    int k0 = t * SBK, b = t & 1;
    gload16(Ag + k0,            &As[b][w * 8][0]);
    gload16(Ag + k0 + 32 * lda, &As[b][w * 8 + 32][0]);
    gload16(Bg + k0,            &Bs[b][w * 8][0]);
    gload16(Bg + k0 + 32 * ldb, &Bs[b][w * 8 + 32][0]);
    gload16(Bg + k0 + 64 * ldb, &Bs[b][w * 8 + 64][0]);
    gload16(Bg + k0 + 96 * ldb, &Bs[b][w * 8 + 96][0]);
  };
  STAGE(0);
  STAGE(1);
  int c0 = (hi ^ l7) << 3, c1 = ((4 + hi) ^ l7) << 3;  // kk0/kk1 read cols
  for (int t = 0; t < NT; t++) {
    int b = t & 1;
    if (t + 1 < NT) asm volatile("s_waitcnt vmcnt(6)" ::: "memory");
    else            asm volatile("s_waitcnt vmcnt(0)" ::: "memory");
    __builtin_amdgcn_s_barrier();
    bf16x8 a0[4], a1[4], b0[2], b1[2];
#pragma unroll
    for (int i = 0; i < 4; i++) {
      a0[i] = *(const bf16x8*)&As[b][i * 16 + l15][c0];
      a1[i] = *(const bf16x8*)&As[b][i * 16 + l15][c1];
    }
#pragma unroll
    for (int j = 0; j < 2; j++) {
      b0[j] = *(const bf16x8*)&Bs[b][w * 32 + j * 16 + l15][c0];
      b1[j] = *(const bf16x8*)&Bs[b][w * 32 + j * 16 + l15][c1];
    }
    asm volatile("s_waitcnt lgkmcnt(0)" ::: "memory");
    __builtin_amdgcn_s_barrier();
    if (t + 2 < NT) STAGE(t + 2);
    __builtin_amdgcn_s_setprio(1);
#pragma unroll
    for (int i = 0; i < 4; i++)
#pragma unroll
      for (int j = 0; j < 2; j++) {
        acc[i][j] = __builtin_amdgcn_mfma_f32_16x16x32_bf16(a0[i], b0[j], acc[i][j], 0, 0, 0);
        acc[i][j] = __builtin_amdgcn_mfma_f32_16x16x32_bf16(a1[i], b1[j], acc[i][j], 0, 0, 0);
      }
    __builtin_amdgcn_s_setprio(0);
  }
#pragma unroll
  for (int j = 0; j < 2; j++) {
    int gn = n0 + w * 32 + j * 16 + l15;
    float bv = bias[gn];
#pragma unroll
    for (int i = 0; i < 4; i++)
#pragma unroll
      for (int rr = 0; rr < 4; rr++) {
        int gm = m0 + i * 16 + hi * 4 + rr;
        float v = acc[i][j][rr] + bv;
        if constexpr (EPI == 3) {
          long off = (long)gm * ldc + gn;
          ((float*)Cv)[off] = v + ((float*)Cv)[off];
        } else if constexpr (EPI == 2) {
          float u = 0.7978845608028654f * (v + 0.044715f * v * v * v);
          u = fminf(fmaxf(u, -15.f), 15.f);
          float e2 = __expf(2.f * u);
          float th = (e2 - 1.f) / (e2 + 1.f);
          ((bf16*)Cv)[(long)gm * ldc + gn] = __float2bfloat16(0.5f * v * (1.f + th));
        } else if constexpr (EPI == 5) {
          int gb = gm >> 10, gt = gm & 1023;
          int which = gn / C;
          int r = gn - which * C;
          int h = r >> 6, d = r & 63;
          long bh = (long)(gb * NH + h);
          if (which == 0)
            ((bf16*)Cv)[(bh * T + gt) * DH + d] = __float2bfloat16(v * 0.125f);
          else if (which == 1)
            ((bf16*)Cv2)[(bh * T + gt) * DH + d] = __float2bfloat16(v);
          else
            ((bf16*)Cv3)[(bh * DH + d) * T + gt] = __float2bfloat16(v);
        }
      }
  }
}

extern "C" void kernel_launch(void* const* d_in, const int* in_sizes, int n_in,
                              void* d_out, int out_size, void* d_ws, size_t ws_size,
                              hipStream_t stream) {
  const int*   idx    = (const int*)d_in[0];
  const float* wte    = (const float*)d_in[1];
  const float* wpe    = (const float*)d_in[2];
  const float* ln1_w  = (const float*)d_in[3];
  const float* ln1_b  = (const float*)d_in[4];
  const float* qkv_w  = (const float*)d_in[5];
  const float* qkv_b  = (const float*)d_in[6];
  const float* proj_w = (const float*)d_in[7];
  const float* proj_b = (const float*)d_in[8];
  const float* ln2_w  = (const float*)d_in[9];
  const float* ln2_b  = (const float*)d_in[10];
  const float* fc_w   = (const float*)d_in[11];
  const float* fc_b   = (const float*)d_in[12];
  const float* fc2_w  = (const float*)d_in[13];
  const float* fc2_b  = (const float*)d_in[14];
  const float* lnf_w  = (const float*)d_in[15];
  const float* lnf_b  = (const float*)d_in[16];
  const float* head_w = (const float*)d_in[17];
  (void)in_sizes; (void)n_in; (void)out_size; (void)ws_size;

  char* base = (char*)d_ws;
  size_t off = 0;
  auto alloc = [&](size_t bytes) -> void* {
    void* p = base + off;
    off = (off + bytes + 255) & ~(size_t)255;
    return p;
  };
  bf16* wt_qkv  = (bf16*)alloc((size_t)NL * 3 * C * C * 2);
  bf16* wt_proj = (bf16*)alloc((size_t)NL * C * C * 2);
  bf16* wt_fc   = (bf16*)alloc((size_t)NL * 4 * C * C * 2);
  bf16* wt_fc2  = (bf16*)alloc((size_t)NL * 4 * C * C * 2);
  bf16* wt_head = (bf16*)alloc((size_t)V * C * 2);
  float* x      = (float*)alloc((size_t)BTOK * C * 4);   // absorbs head OOB reads
  bf16*  xb     = (bf16*)alloc((size_t)BTOK * C * 2);
  bf16*  qb     = (bf16*)alloc((size_t)NB * NH * T * DH * 2);
  bf16*  kb     = (bf16*)alloc((size_t)NB * NH * T * DH * 2);
  bf16*  vtb    = (bf16*)alloc((size_t)NB * NH * T * DH * 2);
  bf16*  yb     = (bf16*)alloc((size_t)BTOK * C * 2);
  bf16*  mbuf   = (bf16*)alloc((size_t)BTOK * 4 * C * 2);

  k_transpose_bf16<<<dim3(12, 36, NL), 256, 0, stream>>>(qkv_w, wt_qkv, C, 3 * C);
  k_transpose_bf16<<<dim3(12, 12, NL), 256, 0, stream>>>(proj_w, wt_proj, C, C);
  k_transpose_bf16<<<dim3(12, 48, NL), 256, 0, stream>>>(fc_w, wt_fc, C, 4 * C);
  k_transpose_bf16<<<dim3(48, 12, NL), 256, 0, stream>>>(fc2_w, wt_fc2, 4 * C, C);
  k_transpose_bf16<<<dim3(12, (V + 63) / 64, 1), 256, 0, stream>>>(head_w, wt_head, C, V);

  k_embed_ln<<<BTOK, 256, 0, stream>>>(idx, wte, wpe, ln1_w, ln1_b, x, xb);

  for (int l = 0; l < NL; l++) {
    if (l > 0)
      k_layernorm<<<BTOK, 256, 0, stream>>>(x, ln1_w + l * C, ln1_b + l * C, xb);
    k_gemm_s<5><<<dim3(32, 18), 256, 0, stream>>>(xb, wt_qkv + (long)l * 3 * C * C,
        qkv_b + l * 3 * C, qb, BTOK, 3 * C, C, C, C, 0, kb, vtb);
    k_attn<<<dim3(T / 128, NB * NH, 2), 256, 0, stream>>>(qb, kb, vtb, yb);
    k_gemm_s<3><<<dim3(32, 6), 256, 0, stream>>>(yb, wt_proj + (long)l * C * C,
        proj_b + l * C, x, BTOK, C, C, C, C, C, nullptr, nullptr);
    k_layernorm<<<BTOK, 256, 0, stream>>>(x, ln2_w + l * C, ln2_b + l * C, xb);
    k_gemm_s<2><<<dim3(32, 24), 256, 0, stream>>>(xb, wt_fc + (long)l * 4 * C * C,
        fc_b + l * 4 * C, mbuf, BTOK, 4 * C, C, C, C, 4 * C, nullptr, nullptr);
    k_gemm_s<3><<<dim3(32, 6), 256, 0, stream>>>(mbuf, wt_fc2 + (long)l * 4 * C * C,
        fc2_b + l * C, x, BTOK, C, 4 * C, 4 * C, 4 * C, C, nullptr, nullptr);
  }
  k_layernorm<<<BTOK, 256, 0, stream>>>(x, lnf_w, lnf_b, xb);
  k_head<<<dim3(8, 197), 512, 0, stream>>>(xb, wt_head, (float*)d_out);
}